// Round 6
// baseline (293.572 us; speedup 1.0000x reference)
//
#include <hip/hip_runtime.h>
#include <math.h>

typedef unsigned short u16;
typedef __bf16 bf16x8 __attribute__((ext_vector_type(8)));
typedef float f32x4 __attribute__((ext_vector_type(4)));
typedef u16 u16x4 __attribute__((ext_vector_type(4)));
typedef u16 u16x8 __attribute__((ext_vector_type(8)));

#define DEV __device__ __forceinline__

// fp32 -> bf16 RNE (inputs are never NaN here)
DEV u16 f2bf(float f) {
  unsigned u = __builtin_bit_cast(unsigned, f);
  u += 0x7FFFu + ((u >> 16) & 1u);
  return (u16)(u >> 16);
}

// async global->LDS, 16B per lane; LDS dest is wave-uniform base + lane*16
DEV void gload16(const void* g, void* l) {
  __builtin_amdgcn_global_load_lds((__attribute__((address_space(1))) void*)g,
                                   (__attribute__((address_space(3))) void*)l, 16, 0, 0);
}

// ---------------- fp32 -> bf16 convert (weights) ----------------
__launch_bounds__(256)
__global__ void cvt_f32_bf16(const float* __restrict__ in, u16* __restrict__ out, int n4) {
  int i = blockIdx.x * 256 + threadIdx.x;
  if (i < n4) {
    float4 v = ((const float4*)in)[i];
    u16x4 o = { f2bf(v.x), f2bf(v.y), f2bf(v.z), f2bf(v.w) };
    ((u16x4*)out)[i] = o;
  }
}

// ---------------- LayerNorm over D=1024, one block per row ----------------
__launch_bounds__(256)
__global__ void ln_rows(const float* __restrict__ x, const float* __restrict__ gam,
                        const float* __restrict__ bet, u16* __restrict__ out) {
  int row = blockIdx.x;
  int t = threadIdx.x;
  float4 v = ((const float4*)(x + (size_t)row * 1024))[t];
  float s = v.x + v.y + v.z + v.w;
  float s2 = v.x * v.x + v.y * v.y + v.z * v.z + v.w * v.w;
  for (int off = 1; off < 64; off <<= 1) {
    s += __shfl_xor(s, off);
    s2 += __shfl_xor(s2, off);
  }
  __shared__ float red[8];
  int wv = t >> 6, ln = t & 63;
  if (ln == 0) { red[wv] = s; red[wv + 4] = s2; }
  __syncthreads();
  s = red[0] + red[1] + red[2] + red[3];
  s2 = red[4] + red[5] + red[6] + red[7];
  float mu = s * (1.f / 1024.f);
  float var = s2 * (1.f / 1024.f) - mu * mu;
  float rs = rsqrtf(var + 1e-5f);
  float4 gv = ((const float4*)gam)[t];
  float4 bv = ((const float4*)bet)[t];
  u16x4 o = { f2bf((v.x - mu) * rs * gv.x + bv.x), f2bf((v.y - mu) * rs * gv.y + bv.y),
              f2bf((v.z - mu) * rs * gv.z + bv.z), f2bf((v.w - mu) * rs * gv.w + bv.w) };
  ((u16x4*)(out + (size_t)row * 1024))[t] = o;
}

// ---------------- V transpose: Vt[h][d][s] = V[s][h*64+d] ----------------
__launch_bounds__(256)
__global__ void transpose_v(const u16* __restrict__ V, u16* __restrict__ Vt) {
  const int st = blockIdx.x, h = blockIdx.y;
  __shared__ u16 tile[64][72];
  const int t = threadIdx.x;
  const int r = t >> 3, c8 = t & 7;
#pragma unroll
  for (int i = 0; i < 2; ++i) {
    int row = i * 32 + r;
    *(u16x8*)&tile[row][c8 * 8] =
        *(const u16x8*)&V[(size_t)(st * 64 + row) * 1024 + h * 64 + c8 * 8];
  }
  __syncthreads();
#pragma unroll
  for (int i = 0; i < 2; ++i) {
    int d = i * 32 + r;
    u16x8 o;
#pragma unroll
    for (int jj = 0; jj < 8; ++jj) o[jj] = tile[c8 * 8 + jj][d];
    *(u16x8*)&Vt[(size_t)(h * 64 + d) * 2048 + st * 64 + c8 * 8] = o;
  }
}

// ---------------- generic bf16 GEMM: C[M,N] = A[M,K] @ B[N,K]^T ----------------
// BK=64: one barrier pair per 32 MFMA (vs 16 at BK=32) - halves the
// vmcnt(0)+barrier drain overhead of the 2-phase loop.
template <int BM, int BN, int WR, int WC, int EPI>
__launch_bounds__(256, 2)
__global__ void gemm_bt(const u16* __restrict__ A, const u16* __restrict__ B,
                        void* __restrict__ C, const float* __restrict__ bias,
                        const float* __restrict__ resid, int M, int N, int K) {
  constexpr int FM = BM / WR / 16;
  constexpr int FN = BN / WC / 16;
  __shared__ u16 As[BM * 64];
  __shared__ u16 Bs[BN * 64];
  const int t = threadIdx.x, lane = t & 63, w = t >> 6;
  const int wr = w / WC, wc = w % WC;
  const int g = lane >> 4, l16 = lane & 15;
  const int m0 = blockIdx.y * BM, n0 = blockIdx.x * BN;
  f32x4 acc[FM][FN] = {};
  const int nkt = K >> 6;
  for (int kt = 0; kt < nkt; ++kt) {
    const u16* Ag = A + (size_t)m0 * K + kt * 64;
    const u16* Bg = B + (size_t)n0 * K + kt * 64;
#pragma unroll
    for (int i = 0; i < BM / 32; ++i) {
      int c = i * 256 + t;
      gload16(Ag + (size_t)(c >> 3) * K + (c & 7) * 8, &As[(i * 256 + w * 64) * 8]);
    }
#pragma unroll
    for (int i = 0; i < BN / 32; ++i) {
      int c = i * 256 + t;
      gload16(Bg + (size_t)(c >> 3) * K + (c & 7) * 8, &Bs[(i * 256 + w * 64) * 8]);
    }
    __syncthreads();
#pragma unroll
    for (int kk = 0; kk < 2; ++kk) {
      bf16x8 af[FM], bfr[FN];
#pragma unroll
      for (int m = 0; m < FM; ++m)
        af[m] = *(const bf16x8*)&As[(wr * FM * 16 + m * 16 + l16) * 64 + kk * 32 + g * 8];
#pragma unroll
      for (int n = 0; n < FN; ++n)
        bfr[n] = *(const bf16x8*)&Bs[(wc * FN * 16 + n * 16 + l16) * 64 + kk * 32 + g * 8];
#pragma unroll
      for (int m = 0; m < FM; ++m)
#pragma unroll
        for (int n = 0; n < FN; ++n)
          acc[m][n] = __builtin_amdgcn_mfma_f32_16x16x32_bf16(af[m], bfr[n], acc[m][n], 0, 0, 0);
    }
    __syncthreads();
  }
#pragma unroll
  for (int m = 0; m < FM; ++m)
#pragma unroll
    for (int n = 0; n < FN; ++n)
#pragma unroll
      for (int r = 0; r < 4; ++r) {
        int row = m0 + wr * FM * 16 + m * 16 + g * 4 + r;
        int col = n0 + wc * FN * 16 + n * 16 + l16;
        size_t idx = (size_t)row * N + col;
        float v = acc[m][n][r];
        if constexpr (EPI == 0) {
          ((u16*)C)[idx] = f2bf(v);
        } else if constexpr (EPI == 1) {
          v += bias[col];
          v = 0.5f * v * (1.f + erff(v * 0.70710678118f));
          ((u16*)C)[idx] = f2bf(v);
        } else if constexpr (EPI == 2) {
          ((float*)C)[idx] = v + bias[col] + resid[idx];
        } else {
          ((float*)C)[idx] = v + resid[idx];
        }
      }
}

// ---------------- fused QKV projection (one launch, 384 blocks), BK=64 ----------------
__launch_bounds__(256, 2)
__global__ void gemm_qkv(const u16* __restrict__ A, const u16* __restrict__ B0,
                         const u16* __restrict__ B1, const u16* __restrict__ B2,
                         u16* __restrict__ C0, u16* __restrict__ C1, u16* __restrict__ C2) {
  constexpr int BM = 128, BN = 128, FM = 4, FN = 4;
  const int K = 1024, N = 1024;
  const int which = blockIdx.x >> 3;
  const u16* B = which == 0 ? B0 : which == 1 ? B1 : B2;
  u16* C = which == 0 ? C0 : which == 1 ? C1 : C2;
  __shared__ u16 As[BM * 64];
  __shared__ u16 Bs[BN * 64];
  const int t = threadIdx.x, lane = t & 63, w = t >> 6;
  const int wr = w >> 1, wc = w & 1;
  const int g = lane >> 4, l16 = lane & 15;
  const int m0 = blockIdx.y * BM, n0 = (blockIdx.x & 7) * BN;
  f32x4 acc[FM][FN] = {};
  for (int kt = 0; kt < 16; ++kt) {
    const u16* Ag = A + (size_t)m0 * K + kt * 64;
    const u16* Bg = B + (size_t)n0 * K + kt * 64;
#pragma unroll
    for (int i = 0; i < 4; ++i) {
      int c = i * 256 + t;
      gload16(Ag + (size_t)(c >> 3) * K + (c & 7) * 8, &As[(i * 256 + w * 64) * 8]);
    }
#pragma unroll
    for (int i = 0; i < 4; ++i) {
      int c = i * 256 + t;
      gload16(Bg + (size_t)(c >> 3) * K + (c & 7) * 8, &Bs[(i * 256 + w * 64) * 8]);
    }
    __syncthreads();
#pragma unroll
    for (int kk = 0; kk < 2; ++kk) {
      bf16x8 af[FM], bfr[FN];
#pragma unroll
      for (int m = 0; m < FM; ++m)
        af[m] = *(const bf16x8*)&As[(wr * 64 + m * 16 + l16) * 64 + kk * 32 + g * 8];
#pragma unroll
      for (int n = 0; n < FN; ++n)
        bfr[n] = *(const bf16x8*)&Bs[(wc * 64 + n * 16 + l16) * 64 + kk * 32 + g * 8];
#pragma unroll
      for (int m = 0; m < FM; ++m)
#pragma unroll
        for (int n = 0; n < FN; ++n)
          acc[m][n] = __builtin_amdgcn_mfma_f32_16x16x32_bf16(af[m], bfr[n], acc[m][n], 0, 0, 0);
    }
    __syncthreads();
  }
#pragma unroll
  for (int m = 0; m < FM; ++m)
#pragma unroll
    for (int n = 0; n < FN; ++n)
#pragma unroll
      for (int r = 0; r < 4; ++r) {
        int row = m0 + wr * 64 + m * 16 + g * 4 + r;
        int col = n0 + wc * 64 + n * 16 + l16;
        C[(size_t)row * N + col] = f2bf(acc[m][n][r]);
      }
}

// ---------------- flash attention, causal + ALiBi (R2 structure) ----------------
// 256 blocks x 4 waves; block handles paired q-blocks (bx, 31-bx) sequentially
// (constant 33 j-tiles/wave). Head-pinned XCD decode: h = (bid>>7)*8 + (bid&7)
// so each XCD serves 2 heads (K/Vt 1MB -> L2-resident; R4-proven).
__launch_bounds__(256, 2)
__global__ void attn_fwd(const u16* __restrict__ Q, const u16* __restrict__ Kb,
                         const u16* __restrict__ Vt, const float* __restrict__ slopes,
                         u16* __restrict__ O) {
  const int bid = blockIdx.x;
  const int bx = (bid >> 3) & 15;
  const int h = (bid >> 7) * 8 + (bid & 7);  // heads pinned to XCDs
  const int t = threadIdx.x, lane = t & 63, w = t >> 6;
  const int g = lane >> 4, l16 = lane & 15;
  const float slope = slopes[h];

  __shared__ u16 Ps[4][16][72];  // per-wave P tile, padded stride

#pragma unroll 1
  for (int pi = 0; pi < 2; ++pi) {
    const int qb = pi == 0 ? bx : 31 - bx;
    const int q0 = qb * 64 + w * 16;

    bf16x8 qf[2];
#pragma unroll
    for (int kk = 0; kk < 2; ++kk)
      qf[kk] = *(const bf16x8*)&Q[(size_t)(q0 + l16) * 1024 + h * 64 + kk * 32 + g * 8];

    f32x4 o_acc[4] = {};
    float m_run[4], l_run[4];
#pragma unroll
    for (int r = 0; r < 4; ++r) { m_run[r] = -1e30f; l_run[r] = 0.f; }

    for (int j = 0; j <= qb; ++j) {
      const int kv0 = j * 64;
      // ---- S = Q K^T (16 q-rows x 64 keys per wave) ----
      f32x4 s[4];
#pragma unroll
      for (int n = 0; n < 4; ++n) {
        bf16x8 kf0 = *(const bf16x8*)&Kb[(size_t)(kv0 + n * 16 + l16) * 1024 + h * 64 + g * 8];
        bf16x8 kf1 = *(const bf16x8*)&Kb[(size_t)(kv0 + n * 16 + l16) * 1024 + h * 64 + 32 + g * 8];
        f32x4 z = {};
        s[n] = __builtin_amdgcn_mfma_f32_16x16x32_bf16(qf[0], kf0, z, 0, 0, 0);
        s[n] = __builtin_amdgcn_mfma_f32_16x16x32_bf16(qf[1], kf1, s[n], 0, 0, 0);
      }
      // ---- scale + ALiBi + causal mask ----
      float sv[4][4];
      float mtile[4] = { -1e30f, -1e30f, -1e30f, -1e30f };
#pragma unroll
      for (int n = 0; n < 4; ++n) {
        int kj = kv0 + n * 16 + l16;
#pragma unroll
        for (int r = 0; r < 4; ++r) {
          int qi = q0 + g * 4 + r;
          float val = s[n][r] * 0.125f - slope * (float)(kj - qi);
          val = (kj <= qi) ? val : -1e30f;
          sv[n][r] = val;
          mtile[r] = fmaxf(mtile[r], val);
        }
      }
      // ---- online softmax: row stats across the 16-lane group ----
#pragma unroll
      for (int r = 0; r < 4; ++r) {
        float v = mtile[r];
        v = fmaxf(v, __shfl_xor(v, 1));
        v = fmaxf(v, __shfl_xor(v, 2));
        v = fmaxf(v, __shfl_xor(v, 4));
        v = fmaxf(v, __shfl_xor(v, 8));
        mtile[r] = v;
      }
      float sc[4];
#pragma unroll
      for (int r = 0; r < 4; ++r) {
        float mnew = fmaxf(m_run[r], mtile[r]);
        sc[r] = __expf(m_run[r] - mnew);
        m_run[r] = mnew;
      }
      float tsum[4] = { 0.f, 0.f, 0.f, 0.f };
#pragma unroll
      for (int n = 0; n < 4; ++n)
#pragma unroll
        for (int r = 0; r < 4; ++r) {
          float p = __expf(sv[n][r] - m_run[r]);
          sv[n][r] = p;
          tsum[r] += p;
        }
#pragma unroll
      for (int r = 0; r < 4; ++r) {
        float v = tsum[r];
        v += __shfl_xor(v, 1);
        v += __shfl_xor(v, 2);
        v += __shfl_xor(v, 4);
        v += __shfl_xor(v, 8);
        l_run[r] = l_run[r] * sc[r] + v;
      }
#pragma unroll
      for (int d = 0; d < 4; ++d)
#pragma unroll
        for (int r = 0; r < 4; ++r) o_acc[d][r] *= sc[r];
      // ---- P -> LDS (layout fix for MFMA A-fragment), then O += P Vt^T ----
#pragma unroll
      for (int n = 0; n < 4; ++n)
#pragma unroll
        for (int r = 0; r < 4; ++r)
          Ps[w][g * 4 + r][n * 16 + l16] = f2bf(sv[n][r]);
      bf16x8 pf[2];
#pragma unroll
      for (int kk = 0; kk < 2; ++kk)
        pf[kk] = *(const bf16x8*)&Ps[w][l16][kk * 32 + g * 8];
#pragma unroll
      for (int d = 0; d < 4; ++d) {
#pragma unroll
        for (int kk = 0; kk < 2; ++kk) {
          bf16x8 vv = *(const bf16x8*)&Vt[((size_t)h * 64 + d * 16 + l16) * 2048 +
                                          kv0 + kk * 32 + g * 8];
          o_acc[d] = __builtin_amdgcn_mfma_f32_16x16x32_bf16(pf[kk], vv, o_acc[d], 0, 0, 0);
        }
      }
    }
    // ---- normalize + store ----
#pragma unroll
    for (int d = 0; d < 4; ++d)
#pragma unroll
      for (int r = 0; r < 4; ++r) {
        int row = q0 + g * 4 + r;
        O[(size_t)row * 1024 + h * 64 + d * 16 + l16] = f2bf(o_acc[d][r] / l_run[r]);
      }
  }
}

// ---------------- launcher ----------------
extern "C" void kernel_launch(void* const* d_in, const int* in_sizes, int n_in,
                              void* d_out, int out_size, void* d_ws, size_t ws_size,
                              hipStream_t stream) {
  const float* x = (const float*)d_in[0];
  const float* slopes = (const float*)d_in[1];
  const float* wq = (const float*)d_in[2];
  const float* wk = (const float*)d_in[3];
  const float* wv = (const float*)d_in[4];
  const float* wo = (const float*)d_in[5];
  const float* ff1w = (const float*)d_in[6];
  const float* ff1b = (const float*)d_in[7];
  const float* ff2w = (const float*)d_in[8];
  const float* ff2b = (const float*)d_in[9];
  const float* ln1g = (const float*)d_in[10];
  const float* ln1b = (const float*)d_in[11];
  const float* ln2g = (const float*)d_in[12];
  const float* ln2b = (const float*)d_in[13];
  float* out = (float*)d_out;

  if (ws_size < (size_t)(56u << 20)) return;  // need 56MB scratch

  char* ws = (char*)d_ws;
  u16* hbuf = (u16*)(ws + 0);             // 4MB: h (LN1 out), later reused as attn output
  u16* Qb = (u16*)(ws + (4u << 20));      // 4MB
  u16* Kbf = (u16*)(ws + (8u << 20));     // 4MB
  u16* Vbf = (u16*)(ws + (12u << 20));    // 4MB
  u16* Vtb = (u16*)(ws + (16u << 20));    // 4MB: transposed V [16][64][2048]
  u16* ffact = Qb;                        // 16MB span 4-20MB (Q/K/V/Vt dead after attention)
  float* x2 = (float*)(ws + (20u << 20)); // 8MB
  u16* h2 = (u16*)(ws + (28u << 20));     // 4MB
  u16* wqb = (u16*)(ws + (32u << 20));
  u16* wkb = (u16*)(ws + (34u << 20));
  u16* wvb = (u16*)(ws + (36u << 20));
  u16* wob = (u16*)(ws + (38u << 20));
  u16* ff1wb = (u16*)(ws + (40u << 20));  // 8MB
  u16* ff2wb = (u16*)(ws + (48u << 20));  // 8MB
  u16* attnO = hbuf;

  auto cvt = [&](const float* src, u16* dst, int n) {
    int n4 = n >> 2;
    cvt_f32_bf16<<<(n4 + 255) / 256, 256, 0, stream>>>(src, dst, n4);
  };
  cvt(wq, wqb, 1 << 20);
  cvt(wk, wkb, 1 << 20);
  cvt(wv, wvb, 1 << 20);
  cvt(wo, wob, 1 << 20);
  cvt(ff1w, ff1wb, 1 << 22);
  cvt(ff2w, ff2wb, 1 << 22);

  ln_rows<<<2048, 256, 0, stream>>>(x, ln1g, ln1b, hbuf);
  gemm_qkv<<<dim3(24, 16), 256, 0, stream>>>(hbuf, wqb, wkb, wvb, Qb, Kbf, Vbf);
  transpose_v<<<dim3(32, 16), 256, 0, stream>>>(Vbf, Vtb);
  attn_fwd<<<dim3(256), 256, 0, stream>>>(Qb, Kbf, Vtb, slopes, attnO);
  // x2 = x + attnO @ wo^T
  gemm_bt<64, 128, 1, 4, 3><<<dim3(8, 32), 256, 0, stream>>>(
      attnO, wob, x2, nullptr, x, 2048, 1024, 1024);
  ln_rows<<<2048, 256, 0, stream>>>(x2, ln2g, ln2b, h2);
  // ffact = gelu(h2 @ ff1^T + b1)
  gemm_bt<128, 128, 2, 2, 1><<<dim3(32, 16), 256, 0, stream>>>(
      h2, ff1wb, ffact, ff1b, nullptr, 2048, 4096, 1024);
  // out = x2 + ffact @ ff2^T + b2
  gemm_bt<64, 128, 1, 4, 2><<<dim3(8, 32), 256, 0, stream>>>(
      ffact, ff2wb, out, ff2b, x2, 2048, 1024, 4096);
}

// Round 7
// 277.580 us; speedup vs baseline: 1.0576x; 1.0576x over previous
//
#include <hip/hip_runtime.h>
#include <math.h>

typedef unsigned short u16;
typedef __bf16 bf16x8 __attribute__((ext_vector_type(8)));
typedef float f32x4 __attribute__((ext_vector_type(4)));
typedef u16 u16x4 __attribute__((ext_vector_type(4)));
typedef u16 u16x8 __attribute__((ext_vector_type(8)));

#define DEV __device__ __forceinline__

// fp32 -> bf16 RNE (inputs are never NaN here)
DEV u16 f2bf(float f) {
  unsigned u = __builtin_bit_cast(unsigned, f);
  u += 0x7FFFu + ((u >> 16) & 1u);
  return (u16)(u >> 16);
}

// async global->LDS, 16B per lane; LDS dest is wave-uniform base + lane*16
DEV void gload16(const void* g, void* l) {
  __builtin_amdgcn_global_load_lds((__attribute__((address_space(1))) void*)g,
                                   (__attribute__((address_space(3))) void*)l, 16, 0, 0);
}

// ---------------- fp32 -> bf16 convert (weights) ----------------
__launch_bounds__(256)
__global__ void cvt_f32_bf16(const float* __restrict__ in, u16* __restrict__ out, int n4) {
  int i = blockIdx.x * 256 + threadIdx.x;
  if (i < n4) {
    float4 v = ((const float4*)in)[i];
    u16x4 o = { f2bf(v.x), f2bf(v.y), f2bf(v.z), f2bf(v.w) };
    ((u16x4*)out)[i] = o;
  }
}

// ---------------- LayerNorm over D=1024, one block per row ----------------
__launch_bounds__(256)
__global__ void ln_rows(const float* __restrict__ x, const float* __restrict__ gam,
                        const float* __restrict__ bet, u16* __restrict__ out) {
  int row = blockIdx.x;
  int t = threadIdx.x;
  float4 v = ((const float4*)(x + (size_t)row * 1024))[t];
  float s = v.x + v.y + v.z + v.w;
  float s2 = v.x * v.x + v.y * v.y + v.z * v.z + v.w * v.w;
  for (int off = 1; off < 64; off <<= 1) {
    s += __shfl_xor(s, off);
    s2 += __shfl_xor(s2, off);
  }
  __shared__ float red[8];
  int wv = t >> 6, ln = t & 63;
  if (ln == 0) { red[wv] = s; red[wv + 4] = s2; }
  __syncthreads();
  s = red[0] + red[1] + red[2] + red[3];
  s2 = red[4] + red[5] + red[6] + red[7];
  float mu = s * (1.f / 1024.f);
  float var = s2 * (1.f / 1024.f) - mu * mu;
  float rs = rsqrtf(var + 1e-5f);
  float4 gv = ((const float4*)gam)[t];
  float4 bv = ((const float4*)bet)[t];
  u16x4 o = { f2bf((v.x - mu) * rs * gv.x + bv.x), f2bf((v.y - mu) * rs * gv.y + bv.y),
              f2bf((v.z - mu) * rs * gv.z + bv.z), f2bf((v.w - mu) * rs * gv.w + bv.w) };
  ((u16x4*)(out + (size_t)row * 1024))[t] = o;
}

// ---------------- V transpose: Vt[h][d][s] = V[s][h*64+d] ----------------
__launch_bounds__(256)
__global__ void transpose_v(const u16* __restrict__ V, u16* __restrict__ Vt) {
  const int st = blockIdx.x, h = blockIdx.y;
  __shared__ u16 tile[64][72];
  const int t = threadIdx.x;
  const int r = t >> 3, c8 = t & 7;
#pragma unroll
  for (int i = 0; i < 2; ++i) {
    int row = i * 32 + r;
    *(u16x8*)&tile[row][c8 * 8] =
        *(const u16x8*)&V[(size_t)(st * 64 + row) * 1024 + h * 64 + c8 * 8];
  }
  __syncthreads();
#pragma unroll
  for (int i = 0; i < 2; ++i) {
    int d = i * 32 + r;
    u16x8 o;
#pragma unroll
    for (int jj = 0; jj < 8; ++jj) o[jj] = tile[c8 * 8 + jj][d];
    *(u16x8*)&Vt[(size_t)(h * 64 + d) * 2048 + st * 64 + c8 * 8] = o;
  }
}

// ---------------- pack K/Vt into per-lane fragment-contiguous layout ----------------
// Kp slot (h,j,f=kk*4+n,lane): Kbf[(j*64+n*16+l16)*1024 + h*64 + kk*32 + g*8 ..+8]
// Vp slot (h,j,f=d*2+kk, lane): Vt[(h*64+d*16+l16)*2048 + j*64 + kk*32 + g*8 ..+8]
// A wave's 8 K-frag loads + 8 V-frag loads each become contiguous 1KB (lane*16B),
// identical bytes for all 4 waves of an attn block -> minimal cache lines.
__launch_bounds__(256)
__global__ void pack_kv(const u16* __restrict__ Kbf, const u16* __restrict__ Vt,
                        u16* __restrict__ Kp, u16* __restrict__ Vp) {
  const int j = blockIdx.x, h = blockIdx.y;
  const int t = threadIdx.x;
#pragma unroll
  for (int s = t; s < 512; s += 256) {
    const int f = s >> 6, l = s & 63, g = l >> 4, l16 = l & 15;
    const size_t dst = (((size_t)(h * 32 + j) * 8 + f) * 64 + l) * 8;
    const int n = f & 3, kk = f >> 2;
    *(u16x8*)&Kp[dst] =
        *(const u16x8*)&Kbf[(size_t)(j * 64 + n * 16 + l16) * 1024 + h * 64 + kk * 32 + g * 8];
    const int d = f >> 1, k2 = f & 1;
    *(u16x8*)&Vp[dst] =
        *(const u16x8*)&Vt[(size_t)(h * 64 + d * 16 + l16) * 2048 + j * 64 + k2 * 32 + g * 8];
  }
}

// ---------------- generic bf16 GEMM: C[M,N] = A[M,K] @ B[N,K]^T (BK=32) ----------------
// EPI: 0 = store bf16; 1 = +bias, exact GELU, store bf16; 2 = +bias +resid, store f32;
//      3 = +resid, store f32
template <int BM, int BN, int WR, int WC, int EPI>
__launch_bounds__(256, 2)
__global__ void gemm_bt(const u16* __restrict__ A, const u16* __restrict__ B,
                        void* __restrict__ C, const float* __restrict__ bias,
                        const float* __restrict__ resid, int M, int N, int K) {
  constexpr int FM = BM / WR / 16;
  constexpr int FN = BN / WC / 16;
  __shared__ u16 As[BM * 32];
  __shared__ u16 Bs[BN * 32];
  const int t = threadIdx.x, lane = t & 63, w = t >> 6;
  const int wr = w / WC, wc = w % WC;
  const int g = lane >> 4, l16 = lane & 15;
  const int m0 = blockIdx.y * BM, n0 = blockIdx.x * BN;
  f32x4 acc[FM][FN] = {};
  const int nkt = K >> 5;
  for (int kt = 0; kt < nkt; ++kt) {
    const u16* Ag = A + (size_t)m0 * K + kt * 32;
    const u16* Bg = B + (size_t)n0 * K + kt * 32;
#pragma unroll
    for (int i = 0; i < BM / 64; ++i) {
      int c = i * 256 + t;
      gload16(Ag + (size_t)(c >> 2) * K + (c & 3) * 8, &As[(i * 256 + w * 64) * 8]);
    }
#pragma unroll
    for (int i = 0; i < BN / 64; ++i) {
      int c = i * 256 + t;
      gload16(Bg + (size_t)(c >> 2) * K + (c & 3) * 8, &Bs[(i * 256 + w * 64) * 8]);
    }
    __syncthreads();
    bf16x8 af[FM], bfr[FN];
#pragma unroll
    for (int m = 0; m < FM; ++m)
      af[m] = *(const bf16x8*)&As[(wr * FM * 16 + m * 16 + l16) * 32 + g * 8];
#pragma unroll
    for (int n = 0; n < FN; ++n)
      bfr[n] = *(const bf16x8*)&Bs[(wc * FN * 16 + n * 16 + l16) * 32 + g * 8];
#pragma unroll
    for (int m = 0; m < FM; ++m)
#pragma unroll
      for (int n = 0; n < FN; ++n)
        acc[m][n] = __builtin_amdgcn_mfma_f32_16x16x32_bf16(af[m], bfr[n], acc[m][n], 0, 0, 0);
    __syncthreads();
  }
#pragma unroll
  for (int m = 0; m < FM; ++m)
#pragma unroll
    for (int n = 0; n < FN; ++n)
#pragma unroll
      for (int r = 0; r < 4; ++r) {
        int row = m0 + wr * FM * 16 + m * 16 + g * 4 + r;
        int col = n0 + wc * FN * 16 + n * 16 + l16;
        size_t idx = (size_t)row * N + col;
        float v = acc[m][n][r];
        if constexpr (EPI == 0) {
          ((u16*)C)[idx] = f2bf(v);
        } else if constexpr (EPI == 1) {
          v += bias[col];
          v = 0.5f * v * (1.f + erff(v * 0.70710678118f));
          ((u16*)C)[idx] = f2bf(v);
        } else if constexpr (EPI == 2) {
          ((float*)C)[idx] = v + bias[col] + resid[idx];
        } else {
          ((float*)C)[idx] = v + resid[idx];
        }
      }
}

// ---------------- fused QKV projection (one launch, 384 blocks), BK=32 ----------------
__launch_bounds__(256, 2)
__global__ void gemm_qkv(const u16* __restrict__ A, const u16* __restrict__ B0,
                         const u16* __restrict__ B1, const u16* __restrict__ B2,
                         u16* __restrict__ C0, u16* __restrict__ C1, u16* __restrict__ C2) {
  constexpr int BM = 128, BN = 128, FM = 4, FN = 4;
  const int K = 1024, N = 1024;
  const int which = blockIdx.x >> 3;
  const u16* B = which == 0 ? B0 : which == 1 ? B1 : B2;
  u16* C = which == 0 ? C0 : which == 1 ? C1 : C2;
  __shared__ u16 As[BM * 32];
  __shared__ u16 Bs[BN * 32];
  const int t = threadIdx.x, lane = t & 63, w = t >> 6;
  const int wr = w >> 1, wc = w & 1;
  const int g = lane >> 4, l16 = lane & 15;
  const int m0 = blockIdx.y * BM, n0 = (blockIdx.x & 7) * BN;
  f32x4 acc[FM][FN] = {};
  for (int kt = 0; kt < 32; ++kt) {
    const u16* Ag = A + (size_t)m0 * K + kt * 32;
    const u16* Bg = B + (size_t)n0 * K + kt * 32;
#pragma unroll
    for (int i = 0; i < 2; ++i) {
      int c = i * 256 + t;
      gload16(Ag + (size_t)(c >> 2) * K + (c & 3) * 8, &As[(i * 256 + w * 64) * 8]);
    }
#pragma unroll
    for (int i = 0; i < 2; ++i) {
      int c = i * 256 + t;
      gload16(Bg + (size_t)(c >> 2) * K + (c & 3) * 8, &Bs[(i * 256 + w * 64) * 8]);
    }
    __syncthreads();
    bf16x8 af[FM], bfr[FN];
#pragma unroll
    for (int m = 0; m < FM; ++m)
      af[m] = *(const bf16x8*)&As[(wr * 64 + m * 16 + l16) * 32 + g * 8];
#pragma unroll
    for (int n = 0; n < FN; ++n)
      bfr[n] = *(const bf16x8*)&Bs[(wc * 64 + n * 16 + l16) * 32 + g * 8];
#pragma unroll
    for (int m = 0; m < FM; ++m)
#pragma unroll
      for (int n = 0; n < FN; ++n)
        acc[m][n] = __builtin_amdgcn_mfma_f32_16x16x32_bf16(af[m], bfr[n], acc[m][n], 0, 0, 0);
    __syncthreads();
  }
#pragma unroll
  for (int m = 0; m < FM; ++m)
#pragma unroll
    for (int n = 0; n < FN; ++n)
#pragma unroll
      for (int r = 0; r < 4; ++r) {
        int row = m0 + wr * 64 + m * 16 + g * 4 + r;
        int col = n0 + wc * 64 + n * 16 + l16;
        C[(size_t)row * N + col] = f2bf(acc[m][n][r]);
      }
}

// ---------------- flash attention, causal + ALiBi (R2 structure, packed K/V) ----------------
// grid (16 pair-blocks, 16 heads); 4 waves, each owns 16 query rows of a
// 64-row q-block; block processes paired q-blocks (bx, 31-bx) sequentially
// (constant 33 j-tiles). K/V read from packed fragment buffers: each load is
// contiguous 1KB per wave, identical bytes across the 4 waves.
__launch_bounds__(256, 2)
__global__ void attn_fwd(const u16* __restrict__ Q, const u16* __restrict__ Kp,
                         const u16* __restrict__ Vp, const float* __restrict__ slopes,
                         u16* __restrict__ O) {
  const int bx = blockIdx.x;
  const int h = blockIdx.y;
  const int t = threadIdx.x, lane = t & 63, w = t >> 6;
  const int g = lane >> 4, l16 = lane & 15;
  const float slope = slopes[h];

  __shared__ u16 Ps[4][16][72];  // per-wave P tile, padded stride

#pragma unroll 1
  for (int pi = 0; pi < 2; ++pi) {
    const int qb = pi == 0 ? bx : 31 - bx;
    const int q0 = qb * 64 + w * 16;

    bf16x8 qf[2];
#pragma unroll
    for (int kk = 0; kk < 2; ++kk)
      qf[kk] = *(const bf16x8*)&Q[(size_t)(q0 + l16) * 1024 + h * 64 + kk * 32 + g * 8];

    f32x4 o_acc[4] = {};
    float m_run[4], l_run[4];
#pragma unroll
    for (int r = 0; r < 4; ++r) { m_run[r] = -1e30f; l_run[r] = 0.f; }

    for (int j = 0; j <= qb; ++j) {
      const int kv0 = j * 64;
      const u16* kbase = Kp + ((size_t)(h * 32 + j) * 8) * 512 + lane * 8;
      const u16* vbase = Vp + ((size_t)(h * 32 + j) * 8) * 512 + lane * 8;
      // ---- S = Q K^T (16 q-rows x 64 keys per wave) ----
      f32x4 s[4];
#pragma unroll
      for (int n = 0; n < 4; ++n) {
        bf16x8 kf0 = *(const bf16x8*)&kbase[(size_t)n * 512];
        bf16x8 kf1 = *(const bf16x8*)&kbase[(size_t)(4 + n) * 512];
        f32x4 z = {};
        s[n] = __builtin_amdgcn_mfma_f32_16x16x32_bf16(qf[0], kf0, z, 0, 0, 0);
        s[n] = __builtin_amdgcn_mfma_f32_16x16x32_bf16(qf[1], kf1, s[n], 0, 0, 0);
      }
      // ---- scale + ALiBi + causal mask ----
      float sv[4][4];
      float mtile[4] = { -1e30f, -1e30f, -1e30f, -1e30f };
#pragma unroll
      for (int n = 0; n < 4; ++n) {
        int kj = kv0 + n * 16 + l16;
#pragma unroll
        for (int r = 0; r < 4; ++r) {
          int qi = q0 + g * 4 + r;
          float val = s[n][r] * 0.125f - slope * (float)(kj - qi);
          val = (kj <= qi) ? val : -1e30f;
          sv[n][r] = val;
          mtile[r] = fmaxf(mtile[r], val);
        }
      }
      // ---- online softmax: row stats across the 16-lane group ----
#pragma unroll
      for (int r = 0; r < 4; ++r) {
        float v = mtile[r];
        v = fmaxf(v, __shfl_xor(v, 1));
        v = fmaxf(v, __shfl_xor(v, 2));
        v = fmaxf(v, __shfl_xor(v, 4));
        v = fmaxf(v, __shfl_xor(v, 8));
        mtile[r] = v;
      }
      float sc[4];
#pragma unroll
      for (int r = 0; r < 4; ++r) {
        float mnew = fmaxf(m_run[r], mtile[r]);
        sc[r] = __expf(m_run[r] - mnew);
        m_run[r] = mnew;
      }
      float tsum[4] = { 0.f, 0.f, 0.f, 0.f };
#pragma unroll
      for (int n = 0; n < 4; ++n)
#pragma unroll
        for (int r = 0; r < 4; ++r) {
          float p = __expf(sv[n][r] - m_run[r]);
          sv[n][r] = p;
          tsum[r] += p;
        }
#pragma unroll
      for (int r = 0; r < 4; ++r) {
        float v = tsum[r];
        v += __shfl_xor(v, 1);
        v += __shfl_xor(v, 2);
        v += __shfl_xor(v, 4);
        v += __shfl_xor(v, 8);
        l_run[r] = l_run[r] * sc[r] + v;
      }
#pragma unroll
      for (int d = 0; d < 4; ++d)
#pragma unroll
        for (int r = 0; r < 4; ++r) o_acc[d][r] *= sc[r];
      // ---- P -> LDS (layout fix for MFMA A-fragment), then O += P V ----
#pragma unroll
      for (int n = 0; n < 4; ++n)
#pragma unroll
        for (int r = 0; r < 4; ++r)
          Ps[w][g * 4 + r][n * 16 + l16] = f2bf(sv[n][r]);
      bf16x8 pf[2];
#pragma unroll
      for (int kk = 0; kk < 2; ++kk)
        pf[kk] = *(const bf16x8*)&Ps[w][l16][kk * 32 + g * 8];
#pragma unroll
      for (int d = 0; d < 4; ++d) {
#pragma unroll
        for (int kk = 0; kk < 2; ++kk) {
          bf16x8 vv = *(const bf16x8*)&vbase[(size_t)(d * 2 + kk) * 512];
          o_acc[d] = __builtin_amdgcn_mfma_f32_16x16x32_bf16(pf[kk], vv, o_acc[d], 0, 0, 0);
        }
      }
    }
    // ---- normalize + store ----
#pragma unroll
    for (int d = 0; d < 4; ++d)
#pragma unroll
      for (int r = 0; r < 4; ++r) {
        int row = q0 + g * 4 + r;
        O[(size_t)row * 1024 + h * 64 + d * 16 + l16] = f2bf(o_acc[d][r] / l_run[r]);
      }
  }
}

// ---------------- launcher ----------------
extern "C" void kernel_launch(void* const* d_in, const int* in_sizes, int n_in,
                              void* d_out, int out_size, void* d_ws, size_t ws_size,
                              hipStream_t stream) {
  const float* x = (const float*)d_in[0];
  const float* slopes = (const float*)d_in[1];
  const float* wq = (const float*)d_in[2];
  const float* wk = (const float*)d_in[3];
  const float* wv = (const float*)d_in[4];
  const float* wo = (const float*)d_in[5];
  const float* ff1w = (const float*)d_in[6];
  const float* ff1b = (const float*)d_in[7];
  const float* ff2w = (const float*)d_in[8];
  const float* ff2b = (const float*)d_in[9];
  const float* ln1g = (const float*)d_in[10];
  const float* ln1b = (const float*)d_in[11];
  const float* ln2g = (const float*)d_in[12];
  const float* ln2b = (const float*)d_in[13];
  float* out = (float*)d_out;

  if (ws_size < (size_t)(56u << 20)) return;  // need 56MB scratch

  char* ws = (char*)d_ws;
  u16* hbuf = (u16*)(ws + 0);             // 4MB: h (LN1 out), later attn output
  u16* Qb = (u16*)(ws + (4u << 20));      // 4MB
  u16* Kbf = (u16*)(ws + (8u << 20));     // 4MB
  u16* Vbf = (u16*)(ws + (12u << 20));    // 4MB; after transpose_v reused as Vp
  u16* Vtb = (u16*)(ws + (16u << 20));    // 4MB: transposed V [16][64][2048]
  u16* ffact = Qb;                        // 16MB span 4-20MB (dead after attention)
  float* x2 = (float*)(ws + (20u << 20)); // 8MB; first 4MB doubles as Kp pre-attn
  u16* Kp = (u16*)(ws + (20u << 20));     // 4MB packed K (dead before x2 written)
  u16* Vp = Vbf;                          // 4MB packed V (Vbf dead after transpose)
  u16* h2 = (u16*)(ws + (28u << 20));     // 4MB
  u16* wqb = (u16*)(ws + (32u << 20));
  u16* wkb = (u16*)(ws + (34u << 20));
  u16* wvb = (u16*)(ws + (36u << 20));
  u16* wob = (u16*)(ws + (38u << 20));
  u16* ff1wb = (u16*)(ws + (40u << 20));  // 8MB
  u16* ff2wb = (u16*)(ws + (48u << 20));  // 8MB
  u16* attnO = hbuf;

  auto cvt = [&](const float* src, u16* dst, int n) {
    int n4 = n >> 2;
    cvt_f32_bf16<<<(n4 + 255) / 256, 256, 0, stream>>>(src, dst, n4);
  };
  cvt(wq, wqb, 1 << 20);
  cvt(wk, wkb, 1 << 20);
  cvt(wv, wvb, 1 << 20);
  cvt(wo, wob, 1 << 20);
  cvt(ff1w, ff1wb, 1 << 22);
  cvt(ff2w, ff2wb, 1 << 22);

  ln_rows<<<2048, 256, 0, stream>>>(x, ln1g, ln1b, hbuf);
  gemm_qkv<<<dim3(24, 16), 256, 0, stream>>>(hbuf, wqb, wkb, wvb, Qb, Kbf, Vbf);
  transpose_v<<<dim3(32, 16), 256, 0, stream>>>(Vbf, Vtb);
  pack_kv<<<dim3(32, 16), 256, 0, stream>>>(Kbf, Vtb, Kp, Vp);
  attn_fwd<<<dim3(16, 16), 256, 0, stream>>>(Qb, Kp, Vp, slopes, attnO);
  // x2 = x + attnO @ wo^T
  gemm_bt<64, 128, 1, 4, 3><<<dim3(8, 32), 256, 0, stream>>>(
      attnO, wob, x2, nullptr, x, 2048, 1024, 1024);
  ln_rows<<<2048, 256, 0, stream>>>(x2, ln2g, ln2b, h2);
  // ffact = gelu(h2 @ ff1^T + b1)
  gemm_bt<128, 128, 2, 2, 1><<<dim3(32, 16), 256, 0, stream>>>(
      h2, ff1wb, ffact, ff1b, nullptr, 2048, 4096, 1024);
  // out = x2 + ffact @ ff2^T + b2
  gemm_bt<64, 128, 1, 4, 2><<<dim3(8, 32), 256, 0, stream>>>(
      ffact, ff2wb, out, ff2b, x2, 2048, 1024, 4096);
}

// Round 8
// 263.185 us; speedup vs baseline: 1.1155x; 1.0547x over previous
//
#include <hip/hip_runtime.h>
#include <math.h>

typedef unsigned short u16;
typedef __bf16 bf16x8 __attribute__((ext_vector_type(8)));
typedef float f32x4 __attribute__((ext_vector_type(4)));
typedef u16 u16x4 __attribute__((ext_vector_type(4)));
typedef u16 u16x8 __attribute__((ext_vector_type(8)));

#define DEV __device__ __forceinline__

// fp32 -> bf16 RNE (inputs are never NaN here)
DEV u16 f2bf(float f) {
  unsigned u = __builtin_bit_cast(unsigned, f);
  u += 0x7FFFu + ((u >> 16) & 1u);
  return (u16)(u >> 16);
}

// async global->LDS, 16B per lane; LDS dest is wave-uniform base + lane*16
DEV void gload16(const void* g, void* l) {
  __builtin_amdgcn_global_load_lds((__attribute__((address_space(1))) void*)g,
                                   (__attribute__((address_space(3))) void*)l, 16, 0, 0);
}

// ---------------- fp32 -> bf16 convert (weights) ----------------
__launch_bounds__(256)
__global__ void cvt_f32_bf16(const float* __restrict__ in, u16* __restrict__ out, int n4) {
  int i = blockIdx.x * 256 + threadIdx.x;
  if (i < n4) {
    float4 v = ((const float4*)in)[i];
    u16x4 o = { f2bf(v.x), f2bf(v.y), f2bf(v.z), f2bf(v.w) };
    ((u16x4*)out)[i] = o;
  }
}

// ---------------- LayerNorm over D=1024, one block per row ----------------
__launch_bounds__(256)
__global__ void ln_rows(const float* __restrict__ x, const float* __restrict__ gam,
                        const float* __restrict__ bet, u16* __restrict__ out) {
  int row = blockIdx.x;
  int t = threadIdx.x;
  float4 v = ((const float4*)(x + (size_t)row * 1024))[t];
  float s = v.x + v.y + v.z + v.w;
  float s2 = v.x * v.x + v.y * v.y + v.z * v.z + v.w * v.w;
  for (int off = 1; off < 64; off <<= 1) {
    s += __shfl_xor(s, off);
    s2 += __shfl_xor(s2, off);
  }
  __shared__ float red[8];
  int wv = t >> 6, ln = t & 63;
  if (ln == 0) { red[wv] = s; red[wv + 4] = s2; }
  __syncthreads();
  s = red[0] + red[1] + red[2] + red[3];
  s2 = red[4] + red[5] + red[6] + red[7];
  float mu = s * (1.f / 1024.f);
  float var = s2 * (1.f / 1024.f) - mu * mu;
  float rs = rsqrtf(var + 1e-5f);
  float4 gv = ((const float4*)gam)[t];
  float4 bv = ((const float4*)bet)[t];
  u16x4 o = { f2bf((v.x - mu) * rs * gv.x + bv.x), f2bf((v.y - mu) * rs * gv.y + bv.y),
              f2bf((v.z - mu) * rs * gv.z + bv.z), f2bf((v.w - mu) * rs * gv.w + bv.w) };
  ((u16x4*)(out + (size_t)row * 1024))[t] = o;
}

// ---------------- V transpose: Vt[h][d][s] = V[s][h*64+d] ----------------
__launch_bounds__(256)
__global__ void transpose_v(const u16* __restrict__ V, u16* __restrict__ Vt) {
  const int st = blockIdx.x, h = blockIdx.y;
  __shared__ u16 tile[64][72];
  const int t = threadIdx.x;
  const int r = t >> 3, c8 = t & 7;
#pragma unroll
  for (int i = 0; i < 2; ++i) {
    int row = i * 32 + r;
    *(u16x8*)&tile[row][c8 * 8] =
        *(const u16x8*)&V[(size_t)(st * 64 + row) * 1024 + h * 64 + c8 * 8];
  }
  __syncthreads();
#pragma unroll
  for (int i = 0; i < 2; ++i) {
    int d = i * 32 + r;
    u16x8 o;
#pragma unroll
    for (int jj = 0; jj < 8; ++jj) o[jj] = tile[c8 * 8 + jj][d];
    *(u16x8*)&Vt[(size_t)(h * 64 + d) * 2048 + st * 64 + c8 * 8] = o;
  }
}

// ---------------- generic bf16 GEMM: C[M,N] = A[M,K] @ B[N,K]^T (BK=32) ----------------
// EPI: 0 = store bf16; 1 = +bias, exact GELU, store bf16; 2 = +bias +resid, store f32;
//      3 = +resid, store f32
template <int BM, int BN, int WR, int WC, int EPI>
__launch_bounds__(256, 2)
__global__ void gemm_bt(const u16* __restrict__ A, const u16* __restrict__ B,
                        void* __restrict__ C, const float* __restrict__ bias,
                        const float* __restrict__ resid, int M, int N, int K) {
  constexpr int FM = BM / WR / 16;
  constexpr int FN = BN / WC / 16;
  __shared__ u16 As[BM * 32];
  __shared__ u16 Bs[BN * 32];
  const int t = threadIdx.x, lane = t & 63, w = t >> 6;
  const int wr = w / WC, wc = w % WC;
  const int g = lane >> 4, l16 = lane & 15;
  const int m0 = blockIdx.y * BM, n0 = blockIdx.x * BN;
  f32x4 acc[FM][FN] = {};
  const int nkt = K >> 5;
  for (int kt = 0; kt < nkt; ++kt) {
    const u16* Ag = A + (size_t)m0 * K + kt * 32;
    const u16* Bg = B + (size_t)n0 * K + kt * 32;
#pragma unroll
    for (int i = 0; i < BM / 64; ++i) {
      int c = i * 256 + t;
      gload16(Ag + (size_t)(c >> 2) * K + (c & 3) * 8, &As[(i * 256 + w * 64) * 8]);
    }
#pragma unroll
    for (int i = 0; i < BN / 64; ++i) {
      int c = i * 256 + t;
      gload16(Bg + (size_t)(c >> 2) * K + (c & 3) * 8, &Bs[(i * 256 + w * 64) * 8]);
    }
    __syncthreads();
    bf16x8 af[FM], bfr[FN];
#pragma unroll
    for (int m = 0; m < FM; ++m)
      af[m] = *(const bf16x8*)&As[(wr * FM * 16 + m * 16 + l16) * 32 + g * 8];
#pragma unroll
    for (int n = 0; n < FN; ++n)
      bfr[n] = *(const bf16x8*)&Bs[(wc * FN * 16 + n * 16 + l16) * 32 + g * 8];
#pragma unroll
    for (int m = 0; m < FM; ++m)
#pragma unroll
      for (int n = 0; n < FN; ++n)
        acc[m][n] = __builtin_amdgcn_mfma_f32_16x16x32_bf16(af[m], bfr[n], acc[m][n], 0, 0, 0);
    __syncthreads();
  }
#pragma unroll
  for (int m = 0; m < FM; ++m)
#pragma unroll
    for (int n = 0; n < FN; ++n)
#pragma unroll
      for (int r = 0; r < 4; ++r) {
        int row = m0 + wr * FM * 16 + m * 16 + g * 4 + r;
        int col = n0 + wc * FN * 16 + n * 16 + l16;
        size_t idx = (size_t)row * N + col;
        float v = acc[m][n][r];
        if constexpr (EPI == 0) {
          ((u16*)C)[idx] = f2bf(v);
        } else if constexpr (EPI == 1) {
          v += bias[col];
          v = 0.5f * v * (1.f + erff(v * 0.70710678118f));
          ((u16*)C)[idx] = f2bf(v);
        } else if constexpr (EPI == 2) {
          ((float*)C)[idx] = v + bias[col] + resid[idx];
        } else {
          ((float*)C)[idx] = v + resid[idx];
        }
      }
}

// ---------------- fused QKV projection (one launch, 384 blocks), BK=32 ----------------
__launch_bounds__(256, 2)
__global__ void gemm_qkv(const u16* __restrict__ A, const u16* __restrict__ B0,
                         const u16* __restrict__ B1, const u16* __restrict__ B2,
                         u16* __restrict__ C0, u16* __restrict__ C1, u16* __restrict__ C2) {
  constexpr int BM = 128, BN = 128, FM = 4, FN = 4;
  const int K = 1024, N = 1024;
  const int which = blockIdx.x >> 3;
  const u16* B = which == 0 ? B0 : which == 1 ? B1 : B2;
  u16* C = which == 0 ? C0 : which == 1 ? C1 : C2;
  __shared__ u16 As[BM * 32];
  __shared__ u16 Bs[BN * 32];
  const int t = threadIdx.x, lane = t & 63, w = t >> 6;
  const int wr = w >> 1, wc = w & 1;
  const int g = lane >> 4, l16 = lane & 15;
  const int m0 = blockIdx.y * BM, n0 = (blockIdx.x & 7) * BN;
  f32x4 acc[FM][FN] = {};
  for (int kt = 0; kt < 32; ++kt) {
    const u16* Ag = A + (size_t)m0 * K + kt * 32;
    const u16* Bg = B + (size_t)n0 * K + kt * 32;
#pragma unroll
    for (int i = 0; i < 2; ++i) {
      int c = i * 256 + t;
      gload16(Ag + (size_t)(c >> 2) * K + (c & 3) * 8, &As[(i * 256 + w * 64) * 8]);
    }
#pragma unroll
    for (int i = 0; i < 2; ++i) {
      int c = i * 256 + t;
      gload16(Bg + (size_t)(c >> 2) * K + (c & 3) * 8, &Bs[(i * 256 + w * 64) * 8]);
    }
    __syncthreads();
    bf16x8 af[FM], bfr[FN];
#pragma unroll
    for (int m = 0; m < FM; ++m)
      af[m] = *(const bf16x8*)&As[(wr * 64 + m * 16 + l16) * 32 + g * 8];
#pragma unroll
    for (int n = 0; n < FN; ++n)
      bfr[n] = *(const bf16x8*)&Bs[(wc * 64 + n * 16 + l16) * 32 + g * 8];
#pragma unroll
    for (int m = 0; m < FM; ++m)
#pragma unroll
      for (int n = 0; n < FN; ++n)
        acc[m][n] = __builtin_amdgcn_mfma_f32_16x16x32_bf16(af[m], bfr[n], acc[m][n], 0, 0, 0);
    __syncthreads();
  }
#pragma unroll
  for (int m = 0; m < FM; ++m)
#pragma unroll
    for (int n = 0; n < FN; ++n)
#pragma unroll
      for (int r = 0; r < 4; ++r) {
        int row = m0 + wr * 64 + m * 16 + g * 4 + r;
        int col = n0 + wc * 64 + n * 16 + l16;
        C[(size_t)row * N + col] = f2bf(acc[m][n][r]);
      }
}

// ---------------- flash attention, causal + ALiBi (swapped-QK in-register softmax) ----
// R2 grid/structure (proven 67.6us): (16 pair-blocks, 16 heads), 4 waves x 16
// q-rows, paired q-blocks (bx, 31-bx), direct K/Vt loads (same bytes as R2).
// NEW: compute S^T = mfma(K, Q) so each lane holds 16 keys of ONE query
// (col=l16=query). Softmax: 15 in-reg fmax + 2 shfl (vs 32 shfl), scalar m/l,
// P roundtrip 4x b64 writes + 2x b128 reads. PV: O^T = mfma(Vt-frag, P-frag).
__launch_bounds__(256, 2)
__global__ void attn_fwd(const u16* __restrict__ Q, const u16* __restrict__ Kb,
                         const u16* __restrict__ Vt, const float* __restrict__ slopes,
                         u16* __restrict__ O) {
  const int bx = blockIdx.x;
  const int h = blockIdx.y;
  const int t = threadIdx.x, lane = t & 63, w = t >> 6;
  const int g = lane >> 4, l16 = lane & 15;
  const float slope = slopes[h];

  __shared__ u16 Ps[4][16][72];  // per-wave P tile: [query][key], padded stride

#pragma unroll 1
  for (int pi = 0; pi < 2; ++pi) {
    const int qb = pi == 0 ? bx : 31 - bx;
    const int q0 = qb * 64 + w * 16;
    const int qi = q0 + l16;  // this lane's query row

    bf16x8 qf[2];
#pragma unroll
    for (int kk = 0; kk < 2; ++kk)
      qf[kk] = *(const bf16x8*)&Q[(size_t)qi * 1024 + h * 64 + kk * 32 + g * 8];

    f32x4 o_acc[4] = {};           // O^T: o_acc[dblk][r] = O[d=dblk*16+g*4+r][qi]
    float m_run = -1e30f, l_run = 0.f;

    for (int j = 0; j <= qb; ++j) {
      const int kv0 = j * 64;
      // ---- S^T = K Q^T (64 keys x 16 queries per wave) ----
      f32x4 s[4];
      __builtin_amdgcn_s_setprio(1);
#pragma unroll
      for (int n = 0; n < 4; ++n) {
        bf16x8 kf0 = *(const bf16x8*)&Kb[(size_t)(kv0 + n * 16 + l16) * 1024 + h * 64 + g * 8];
        bf16x8 kf1 = *(const bf16x8*)&Kb[(size_t)(kv0 + n * 16 + l16) * 1024 + h * 64 + 32 + g * 8];
        f32x4 z = {};
        s[n] = __builtin_amdgcn_mfma_f32_16x16x32_bf16(kf0, qf[0], z, 0, 0, 0);
        s[n] = __builtin_amdgcn_mfma_f32_16x16x32_bf16(kf1, qf[1], s[n], 0, 0, 0);
      }
      __builtin_amdgcn_s_setprio(0);
      // ---- scale + ALiBi + causal; in-register row max (this lane = one query) ----
      float mx = -1e30f;
#pragma unroll
      for (int n = 0; n < 4; ++n)
#pragma unroll
        for (int r = 0; r < 4; ++r) {
          int kj = kv0 + n * 16 + g * 4 + r;
          float val = s[n][r] * 0.125f - slope * (float)(kj - qi);
          val = (kj <= qi) ? val : -1e30f;
          s[n][r] = val;
          mx = fmaxf(mx, val);
        }
      mx = fmaxf(mx, __shfl_xor(mx, 16));
      mx = fmaxf(mx, __shfl_xor(mx, 32));
      float mnew = fmaxf(m_run, mx);
      float sc = __expf(m_run - mnew);
      m_run = mnew;
      float ts = 0.f;
#pragma unroll
      for (int n = 0; n < 4; ++n)
#pragma unroll
        for (int r = 0; r < 4; ++r) {
          float p = __expf(s[n][r] - mnew);
          s[n][r] = p;
          ts += p;
        }
      ts += __shfl_xor(ts, 16);
      ts += __shfl_xor(ts, 32);
      l_run = l_run * sc + ts;
#pragma unroll
      for (int d = 0; d < 4; ++d)
#pragma unroll
        for (int r = 0; r < 4; ++r) o_acc[d][r] *= sc;
      // ---- P -> LDS [query][key] (4x b64 per lane), read back as B-frag ----
#pragma unroll
      for (int n = 0; n < 4; ++n) {
        u16x4 o = { f2bf(s[n][0]), f2bf(s[n][1]), f2bf(s[n][2]), f2bf(s[n][3]) };
        *(u16x4*)&Ps[w][l16][n * 16 + g * 4] = o;
      }
      bf16x8 pf[2];
#pragma unroll
      for (int kk = 0; kk < 2; ++kk)
        pf[kk] = *(const bf16x8*)&Ps[w][l16][kk * 32 + g * 8];
      // ---- O^T += V^T P^T : mfma(A=Vt-frag, B=P-frag) ----
      __builtin_amdgcn_s_setprio(1);
#pragma unroll
      for (int d = 0; d < 4; ++d) {
#pragma unroll
        for (int kk = 0; kk < 2; ++kk) {
          bf16x8 vv = *(const bf16x8*)&Vt[((size_t)h * 64 + d * 16 + l16) * 2048 +
                                          kv0 + kk * 32 + g * 8];
          o_acc[d] = __builtin_amdgcn_mfma_f32_16x16x32_bf16(vv, pf[kk], o_acc[d], 0, 0, 0);
        }
      }
      __builtin_amdgcn_s_setprio(0);
    }
    // ---- normalize + store: lane holds 16 d-values of query qi ----
    float inv = 1.f / l_run;
#pragma unroll
    for (int d = 0; d < 4; ++d) {
      u16x4 o = { f2bf(o_acc[d][0] * inv), f2bf(o_acc[d][1] * inv),
                  f2bf(o_acc[d][2] * inv), f2bf(o_acc[d][3] * inv) };
      *(u16x4*)&O[(size_t)qi * 1024 + h * 64 + d * 16 + g * 4] = o;
    }
  }
}

// ---------------- launcher ----------------
extern "C" void kernel_launch(void* const* d_in, const int* in_sizes, int n_in,
                              void* d_out, int out_size, void* d_ws, size_t ws_size,
                              hipStream_t stream) {
  const float* x = (const float*)d_in[0];
  const float* slopes = (const float*)d_in[1];
  const float* wq = (const float*)d_in[2];
  const float* wk = (const float*)d_in[3];
  const float* wv = (const float*)d_in[4];
  const float* wo = (const float*)d_in[5];
  const float* ff1w = (const float*)d_in[6];
  const float* ff1b = (const float*)d_in[7];
  const float* ff2w = (const float*)d_in[8];
  const float* ff2b = (const float*)d_in[9];
  const float* ln1g = (const float*)d_in[10];
  const float* ln1b = (const float*)d_in[11];
  const float* ln2g = (const float*)d_in[12];
  const float* ln2b = (const float*)d_in[13];
  float* out = (float*)d_out;

  if (ws_size < (size_t)(56u << 20)) return;  // need 56MB scratch

  char* ws = (char*)d_ws;
  u16* hbuf = (u16*)(ws + 0);             // 4MB: h (LN1 out), later attn output
  u16* Qb = (u16*)(ws + (4u << 20));      // 4MB
  u16* Kbf = (u16*)(ws + (8u << 20));     // 4MB
  u16* Vbf = (u16*)(ws + (12u << 20));    // 4MB
  u16* Vtb = (u16*)(ws + (16u << 20));    // 4MB: transposed V [16][64][2048]
  u16* ffact = Qb;                        // 16MB span 4-20MB (dead after attention)
  float* x2 = (float*)(ws + (20u << 20)); // 8MB
  u16* h2 = (u16*)(ws + (28u << 20));     // 4MB
  u16* wqb = (u16*)(ws + (32u << 20));
  u16* wkb = (u16*)(ws + (34u << 20));
  u16* wvb = (u16*)(ws + (36u << 20));
  u16* wob = (u16*)(ws + (38u << 20));
  u16* ff1wb = (u16*)(ws + (40u << 20));  // 8MB
  u16* ff2wb = (u16*)(ws + (48u << 20));  // 8MB
  u16* attnO = hbuf;

  auto cvt = [&](const float* src, u16* dst, int n) {
    int n4 = n >> 2;
    cvt_f32_bf16<<<(n4 + 255) / 256, 256, 0, stream>>>(src, dst, n4);
  };
  cvt(wq, wqb, 1 << 20);
  cvt(wk, wkb, 1 << 20);
  cvt(wv, wvb, 1 << 20);
  cvt(wo, wob, 1 << 20);
  cvt(ff1w, ff1wb, 1 << 22);
  cvt(ff2w, ff2wb, 1 << 22);

  ln_rows<<<2048, 256, 0, stream>>>(x, ln1g, ln1b, hbuf);
  gemm_qkv<<<dim3(24, 16), 256, 0, stream>>>(hbuf, wqb, wkb, wvb, Qb, Kbf, Vbf);
  transpose_v<<<dim3(32, 16), 256, 0, stream>>>(Vbf, Vtb);
  attn_fwd<<<dim3(16, 16), 256, 0, stream>>>(Qb, Kbf, Vtb, slopes, attnO);
  // x2 = x + attnO @ wo^T
  gemm_bt<64, 128, 1, 4, 3><<<dim3(8, 32), 256, 0, stream>>>(
      attnO, wob, x2, nullptr, x, 2048, 1024, 1024);
  ln_rows<<<2048, 256, 0, stream>>>(x2, ln2g, ln2b, h2);
  // ffact = gelu(h2 @ ff1^T + b1)
  gemm_bt<128, 128, 2, 2, 1><<<dim3(32, 16), 256, 0, stream>>>(
      h2, ff1wb, ffact, ff1b, nullptr, 2048, 4096, 1024);
  // out = x2 + ffact @ ff2^T + b2
  gemm_bt<64, 128, 1, 4, 2><<<dim3(8, 32), 256, 0, stream>>>(
      ffact, ff2wb, out, ff2b, x2, 2048, 1024, 4096);
}

// Round 9
// 228.487 us; speedup vs baseline: 1.2849x; 1.1519x over previous
//
#include <hip/hip_runtime.h>
#include <math.h>

typedef unsigned short u16;
typedef __bf16 bf16x8 __attribute__((ext_vector_type(8)));
typedef float f32x4 __attribute__((ext_vector_type(4)));
typedef u16 u16x4 __attribute__((ext_vector_type(4)));
typedef u16 u16x8 __attribute__((ext_vector_type(8)));

#define DEV __device__ __forceinline__

// fp32 -> bf16 RNE (inputs are never NaN here)
DEV u16 f2bf(float f) {
  unsigned u = __builtin_bit_cast(unsigned, f);
  u += 0x7FFFu + ((u >> 16) & 1u);
  return (u16)(u >> 16);
}

// async global->LDS, 16B per lane; LDS dest is wave-uniform base + lane*16
DEV void gload16(const void* g, void* l) {
  __builtin_amdgcn_global_load_lds((__attribute__((address_space(1))) void*)g,
                                   (__attribute__((address_space(3))) void*)l, 16, 0, 0);
}

// ---------------- fused fp32 -> bf16 convert (all 6 weights, one launch) ----------------
__launch_bounds__(256)
__global__ void cvt_all(const float* __restrict__ wq, const float* __restrict__ wk,
                        const float* __restrict__ wv, const float* __restrict__ wo,
                        const float* __restrict__ f1, const float* __restrict__ f2,
                        u16* __restrict__ dq, u16* __restrict__ dk, u16* __restrict__ dv,
                        u16* __restrict__ dwo, u16* __restrict__ df1, u16* __restrict__ df2) {
  int i = blockIdx.x * 256 + threadIdx.x;  // float4 index; total 3145728
  const float* src;
  u16* dst;
  int local;
  if (i < (1 << 18)) { src = wq; dst = dq; local = i; }
  else if (i < (2 << 18)) { src = wk; dst = dk; local = i - (1 << 18); }
  else if (i < (3 << 18)) { src = wv; dst = dv; local = i - (2 << 18); }
  else if (i < (4 << 18)) { src = wo; dst = dwo; local = i - (3 << 18); }
  else if (i < (4 << 18) + (1 << 20)) { src = f1; dst = df1; local = i - (4 << 18); }
  else { src = f2; dst = df2; local = i - ((4 << 18) + (1 << 20)); }
  float4 v = ((const float4*)src)[local];
  u16x4 o = { f2bf(v.x), f2bf(v.y), f2bf(v.z), f2bf(v.w) };
  ((u16x4*)dst)[local] = o;
}

// ---------------- LayerNorm over D=1024, one block per row ----------------
__launch_bounds__(256)
__global__ void ln_rows(const float* __restrict__ x, const float* __restrict__ gam,
                        const float* __restrict__ bet, u16* __restrict__ out) {
  int row = blockIdx.x;
  int t = threadIdx.x;
  float4 v = ((const float4*)(x + (size_t)row * 1024))[t];
  float s = v.x + v.y + v.z + v.w;
  float s2 = v.x * v.x + v.y * v.y + v.z * v.z + v.w * v.w;
  for (int off = 1; off < 64; off <<= 1) {
    s += __shfl_xor(s, off);
    s2 += __shfl_xor(s2, off);
  }
  __shared__ float red[8];
  int wv = t >> 6, ln = t & 63;
  if (ln == 0) { red[wv] = s; red[wv + 4] = s2; }
  __syncthreads();
  s = red[0] + red[1] + red[2] + red[3];
  s2 = red[4] + red[5] + red[6] + red[7];
  float mu = s * (1.f / 1024.f);
  float var = s2 * (1.f / 1024.f) - mu * mu;
  float rs = rsqrtf(var + 1e-5f);
  float4 gv = ((const float4*)gam)[t];
  float4 bv = ((const float4*)bet)[t];
  u16x4 o = { f2bf((v.x - mu) * rs * gv.x + bv.x), f2bf((v.y - mu) * rs * gv.y + bv.y),
              f2bf((v.z - mu) * rs * gv.z + bv.z), f2bf((v.w - mu) * rs * gv.w + bv.w) };
  ((u16x4*)(out + (size_t)row * 1024))[t] = o;
}

// ---------------- V transpose: Vt[h][d][s] = V[s][h*64+d] ----------------
__launch_bounds__(256)
__global__ void transpose_v(const u16* __restrict__ V, u16* __restrict__ Vt) {
  const int st = blockIdx.x, h = blockIdx.y;
  __shared__ u16 tile[64][72];
  const int t = threadIdx.x;
  const int r = t >> 3, c8 = t & 7;
#pragma unroll
  for (int i = 0; i < 2; ++i) {
    int row = i * 32 + r;
    *(u16x8*)&tile[row][c8 * 8] =
        *(const u16x8*)&V[(size_t)(st * 64 + row) * 1024 + h * 64 + c8 * 8];
  }
  __syncthreads();
#pragma unroll
  for (int i = 0; i < 2; ++i) {
    int d = i * 32 + r;
    u16x8 o;
#pragma unroll
    for (int jj = 0; jj < 8; ++jj) o[jj] = tile[c8 * 8 + jj][d];
    *(u16x8*)&Vt[(size_t)(h * 64 + d) * 2048 + st * 64 + c8 * 8] = o;
  }
}

// ---------------- generic bf16 GEMM: C[M,N] = A[M,K] @ B[N,K]^T (BK=32, R2-proven) ----
template <int BM, int BN, int WR, int WC, int EPI>
__launch_bounds__(256, 2)
__global__ void gemm_bt(const u16* __restrict__ A, const u16* __restrict__ B,
                        void* __restrict__ C, const float* __restrict__ bias,
                        const float* __restrict__ resid, int M, int N, int K) {
  constexpr int FM = BM / WR / 16;
  constexpr int FN = BN / WC / 16;
  __shared__ u16 As[BM * 32];
  __shared__ u16 Bs[BN * 32];
  const int t = threadIdx.x, lane = t & 63, w = t >> 6;
  const int wr = w / WC, wc = w % WC;
  const int g = lane >> 4, l16 = lane & 15;
  const int m0 = blockIdx.y * BM, n0 = blockIdx.x * BN;
  f32x4 acc[FM][FN] = {};
  const int nkt = K >> 5;
  for (int kt = 0; kt < nkt; ++kt) {
    const u16* Ag = A + (size_t)m0 * K + kt * 32;
    const u16* Bg = B + (size_t)n0 * K + kt * 32;
#pragma unroll
    for (int i = 0; i < BM / 64; ++i) {
      int c = i * 256 + t;
      gload16(Ag + (size_t)(c >> 2) * K + (c & 3) * 8, &As[(i * 256 + w * 64) * 8]);
    }
#pragma unroll
    for (int i = 0; i < BN / 64; ++i) {
      int c = i * 256 + t;
      gload16(Bg + (size_t)(c >> 2) * K + (c & 3) * 8, &Bs[(i * 256 + w * 64) * 8]);
    }
    __syncthreads();
    bf16x8 af[FM], bfr[FN];
#pragma unroll
    for (int m = 0; m < FM; ++m)
      af[m] = *(const bf16x8*)&As[(wr * FM * 16 + m * 16 + l16) * 32 + g * 8];
#pragma unroll
    for (int n = 0; n < FN; ++n)
      bfr[n] = *(const bf16x8*)&Bs[(wc * FN * 16 + n * 16 + l16) * 32 + g * 8];
#pragma unroll
    for (int m = 0; m < FM; ++m)
#pragma unroll
      for (int n = 0; n < FN; ++n)
        acc[m][n] = __builtin_amdgcn_mfma_f32_16x16x32_bf16(af[m], bfr[n], acc[m][n], 0, 0, 0);
    __syncthreads();
  }
#pragma unroll
  for (int m = 0; m < FM; ++m)
#pragma unroll
    for (int n = 0; n < FN; ++n)
#pragma unroll
      for (int r = 0; r < 4; ++r) {
        int row = m0 + wr * FM * 16 + m * 16 + g * 4 + r;
        int col = n0 + wc * FN * 16 + n * 16 + l16;
        size_t idx = (size_t)row * N + col;
        float v = acc[m][n][r];
        if constexpr (EPI == 0) {
          ((u16*)C)[idx] = f2bf(v);
        } else if constexpr (EPI == 1) {
          v += bias[col];
          v = 0.5f * v * (1.f + erff(v * 0.70710678118f));
          ((u16*)C)[idx] = f2bf(v);
        } else if constexpr (EPI == 2) {
          ((float*)C)[idx] = v + bias[col] + resid[idx];
        } else {
          ((float*)C)[idx] = v + resid[idx];
        }
      }
}

// ---------------- fused QKV projection (one launch, 384 blocks), BK=32 ----------------
__launch_bounds__(256, 2)
__global__ void gemm_qkv(const u16* __restrict__ A, const u16* __restrict__ B0,
                         const u16* __restrict__ B1, const u16* __restrict__ B2,
                         u16* __restrict__ C0, u16* __restrict__ C1, u16* __restrict__ C2) {
  constexpr int BM = 128, BN = 128, FM = 4, FN = 4;
  const int K = 1024, N = 1024;
  const int which = blockIdx.x >> 3;
  const u16* B = which == 0 ? B0 : which == 1 ? B1 : B2;
  u16* C = which == 0 ? C0 : which == 1 ? C1 : C2;
  __shared__ u16 As[BM * 32];
  __shared__ u16 Bs[BN * 32];
  const int t = threadIdx.x, lane = t & 63, w = t >> 6;
  const int wr = w >> 1, wc = w & 1;
  const int g = lane >> 4, l16 = lane & 15;
  const int m0 = blockIdx.y * BM, n0 = (blockIdx.x & 7) * BN;
  f32x4 acc[FM][FN] = {};
  for (int kt = 0; kt < 32; ++kt) {
    const u16* Ag = A + (size_t)m0 * K + kt * 32;
    const u16* Bg = B + (size_t)n0 * K + kt * 32;
#pragma unroll
    for (int i = 0; i < 2; ++i) {
      int c = i * 256 + t;
      gload16(Ag + (size_t)(c >> 2) * K + (c & 3) * 8, &As[(i * 256 + w * 64) * 8]);
    }
#pragma unroll
    for (int i = 0; i < 2; ++i) {
      int c = i * 256 + t;
      gload16(Bg + (size_t)(c >> 2) * K + (c & 3) * 8, &Bs[(i * 256 + w * 64) * 8]);
    }
    __syncthreads();
    bf16x8 af[FM], bfr[FN];
#pragma unroll
    for (int m = 0; m < FM; ++m)
      af[m] = *(const bf16x8*)&As[(wr * 64 + m * 16 + l16) * 32 + g * 8];
#pragma unroll
    for (int n = 0; n < FN; ++n)
      bfr[n] = *(const bf16x8*)&Bs[(wc * 64 + n * 16 + l16) * 32 + g * 8];
#pragma unroll
    for (int m = 0; m < FM; ++m)
#pragma unroll
      for (int n = 0; n < FN; ++n)
        acc[m][n] = __builtin_amdgcn_mfma_f32_16x16x32_bf16(af[m], bfr[n], acc[m][n], 0, 0, 0);
    __syncthreads();
  }
#pragma unroll
  for (int m = 0; m < FM; ++m)
#pragma unroll
    for (int n = 0; n < FN; ++n)
#pragma unroll
      for (int r = 0; r < 4; ++r) {
        int row = m0 + wr * 64 + m * 16 + g * 4 + r;
        int col = n0 + wc * 64 + n * 16 + l16;
        C[(size_t)row * N + col] = f2bf(acc[m][n][r]);
      }
}

// ---------------- flash attention, causal + ALiBi (R2 structure + LDS-staged K/V) ----
// R2 grid (16 pair-blocks, 16 heads), 4 waves x 16 q-rows, paired q-blocks
// (bx, 31-bx). NEW: per j-tile the block cooperatively stages K(64x64) and
// Vt(64x64) into double-buffered LDS via global_load_lds (prefetch j+1 during
// compute of j). XOR swizzle c8^(row&7) applied on BOTH the global source and
// the ds_read (LDS linear) per T2/m173; K/V frag reads land <=2-way conflicts.
__launch_bounds__(256, 2)
__global__ void attn_fwd(const u16* __restrict__ Q, const u16* __restrict__ Kb,
                         const u16* __restrict__ Vt, const float* __restrict__ slopes,
                         u16* __restrict__ O) {
  const int bx = blockIdx.x;
  const int h = blockIdx.y;
  const int t = threadIdx.x, lane = t & 63, w = t >> 6;
  const int g = lane >> 4, l16 = lane & 15;
  const float slope = slopes[h];

  __shared__ u16 Ks[2][4096];    // [buf][row*64 + col], 64x64 bf16, linear
  __shared__ u16 Vs[2][4096];    // [buf][drow*64 + kvcol]
  __shared__ u16 Ps[4][16][72];  // per-wave P roundtrip (R2 layout)

  // staging geometry: issue i in {0,1}: slot = i*256 + w*64 + lane
  // row = slot>>3, c8 = lane&7, swizzled source column c8s = c8 ^ (row&7)
  const int r0 = w * 8 + (lane >> 3), r1 = 32 + r0;
  const int c8 = lane & 7;
  const int c0s = c8 ^ (r0 & 7), c1s = c8 ^ (r1 & 7);
  const int sw = l16 & 7;  // read-side swizzle key

#pragma unroll 1
  for (int pi = 0; pi < 2; ++pi) {
    const int qb = pi == 0 ? bx : 31 - bx;
    const int q0 = qb * 64 + w * 16;

    bf16x8 qf[2];
#pragma unroll
    for (int kk = 0; kk < 2; ++kk)
      qf[kk] = *(const bf16x8*)&Q[(size_t)(q0 + l16) * 1024 + h * 64 + kk * 32 + g * 8];

    f32x4 o_acc[4] = {};
    float m_run[4], l_run[4];
#pragma unroll
    for (int r = 0; r < 4; ++r) { m_run[r] = -1e30f; l_run[r] = 0.f; }

    // stage tile 0 (barrier first: LDS may still be in use from previous pi)
    __syncthreads();
    gload16(Kb + (size_t)(0 + r0) * 1024 + h * 64 + c0s * 8, &Ks[0][(w * 64) * 8]);
    gload16(Kb + (size_t)(0 + r1) * 1024 + h * 64 + c1s * 8, &Ks[0][(256 + w * 64) * 8]);
    gload16(Vt + (size_t)(h * 64 + r0) * 2048 + 0 + c0s * 8, &Vs[0][(w * 64) * 8]);
    gload16(Vt + (size_t)(h * 64 + r1) * 2048 + 0 + c1s * 8, &Vs[0][(256 + w * 64) * 8]);
    __syncthreads();

    int cur = 0;
    for (int j = 0; j <= qb; ++j) {
      const int kv0 = j * 64;
      // ---- prefetch tile j+1 into the other buffer ----
      if (j < qb) {
        const int nv0 = kv0 + 64;
        gload16(Kb + (size_t)(nv0 + r0) * 1024 + h * 64 + c0s * 8, &Ks[cur ^ 1][(w * 64) * 8]);
        gload16(Kb + (size_t)(nv0 + r1) * 1024 + h * 64 + c1s * 8, &Ks[cur ^ 1][(256 + w * 64) * 8]);
        gload16(Vt + (size_t)(h * 64 + r0) * 2048 + nv0 + c0s * 8, &Vs[cur ^ 1][(w * 64) * 8]);
        gload16(Vt + (size_t)(h * 64 + r1) * 2048 + nv0 + c1s * 8, &Vs[cur ^ 1][(256 + w * 64) * 8]);
      }
      // ---- S = Q K^T from LDS (swizzled reads) ----
      f32x4 s[4];
#pragma unroll
      for (int n = 0; n < 4; ++n) {
        bf16x8 kf0 = *(const bf16x8*)&Ks[cur][(n * 16 + l16) * 64 + ((g ^ sw) * 8)];
        bf16x8 kf1 = *(const bf16x8*)&Ks[cur][(n * 16 + l16) * 64 + (((4 + g) ^ sw) * 8)];
        f32x4 z = {};
        s[n] = __builtin_amdgcn_mfma_f32_16x16x32_bf16(qf[0], kf0, z, 0, 0, 0);
        s[n] = __builtin_amdgcn_mfma_f32_16x16x32_bf16(qf[1], kf1, s[n], 0, 0, 0);
      }
      // ---- scale + ALiBi + causal mask ----
      float sv[4][4];
      float mtile[4] = { -1e30f, -1e30f, -1e30f, -1e30f };
#pragma unroll
      for (int n = 0; n < 4; ++n) {
        int kj = kv0 + n * 16 + l16;
#pragma unroll
        for (int r = 0; r < 4; ++r) {
          int qi = q0 + g * 4 + r;
          float val = s[n][r] * 0.125f - slope * (float)(kj - qi);
          val = (kj <= qi) ? val : -1e30f;
          sv[n][r] = val;
          mtile[r] = fmaxf(mtile[r], val);
        }
      }
      // ---- online softmax (16-lane row groups) ----
#pragma unroll
      for (int r = 0; r < 4; ++r) {
        float v = mtile[r];
        v = fmaxf(v, __shfl_xor(v, 1));
        v = fmaxf(v, __shfl_xor(v, 2));
        v = fmaxf(v, __shfl_xor(v, 4));
        v = fmaxf(v, __shfl_xor(v, 8));
        mtile[r] = v;
      }
      float sc[4];
#pragma unroll
      for (int r = 0; r < 4; ++r) {
        float mnew = fmaxf(m_run[r], mtile[r]);
        sc[r] = __expf(m_run[r] - mnew);
        m_run[r] = mnew;
      }
      float tsum[4] = { 0.f, 0.f, 0.f, 0.f };
#pragma unroll
      for (int n = 0; n < 4; ++n)
#pragma unroll
        for (int r = 0; r < 4; ++r) {
          float p = __expf(sv[n][r] - m_run[r]);
          sv[n][r] = p;
          tsum[r] += p;
        }
#pragma unroll
      for (int r = 0; r < 4; ++r) {
        float v = tsum[r];
        v += __shfl_xor(v, 1);
        v += __shfl_xor(v, 2);
        v += __shfl_xor(v, 4);
        v += __shfl_xor(v, 8);
        l_run[r] = l_run[r] * sc[r] + v;
      }
#pragma unroll
      for (int d = 0; d < 4; ++d)
#pragma unroll
        for (int r = 0; r < 4; ++r) o_acc[d][r] *= sc[r];
      // ---- P -> LDS (A-fragment layout, R2), then O += P Vt^T from LDS ----
#pragma unroll
      for (int n = 0; n < 4; ++n)
#pragma unroll
        for (int r = 0; r < 4; ++r)
          Ps[w][g * 4 + r][n * 16 + l16] = f2bf(sv[n][r]);
      bf16x8 pf[2];
#pragma unroll
      for (int kk = 0; kk < 2; ++kk)
        pf[kk] = *(const bf16x8*)&Ps[w][l16][kk * 32 + g * 8];
#pragma unroll
      for (int d = 0; d < 4; ++d) {
#pragma unroll
        for (int kk = 0; kk < 2; ++kk) {
          bf16x8 vv = *(const bf16x8*)&Vs[cur][(d * 16 + l16) * 64 + (((kk * 4 + g) ^ sw) * 8)];
          o_acc[d] = __builtin_amdgcn_mfma_f32_16x16x32_bf16(pf[kk], vv, o_acc[d], 0, 0, 0);
        }
      }
      // ---- tile end: drain prefetch (compiler emits vmcnt/lgkm before barrier) ----
      __syncthreads();
      cur ^= 1;
    }
    // ---- normalize + store ----
#pragma unroll
    for (int d = 0; d < 4; ++d)
#pragma unroll
      for (int r = 0; r < 4; ++r) {
        int row = q0 + g * 4 + r;
        O[(size_t)row * 1024 + h * 64 + d * 16 + l16] = f2bf(o_acc[d][r] / l_run[r]);
      }
  }
}

// ---------------- launcher ----------------
extern "C" void kernel_launch(void* const* d_in, const int* in_sizes, int n_in,
                              void* d_out, int out_size, void* d_ws, size_t ws_size,
                              hipStream_t stream) {
  const float* x = (const float*)d_in[0];
  const float* slopes = (const float*)d_in[1];
  const float* wq = (const float*)d_in[2];
  const float* wk = (const float*)d_in[3];
  const float* wv = (const float*)d_in[4];
  const float* wo = (const float*)d_in[5];
  const float* ff1w = (const float*)d_in[6];
  const float* ff1b = (const float*)d_in[7];
  const float* ff2w = (const float*)d_in[8];
  const float* ff2b = (const float*)d_in[9];
  const float* ln1g = (const float*)d_in[10];
  const float* ln1b = (const float*)d_in[11];
  const float* ln2g = (const float*)d_in[12];
  const float* ln2b = (const float*)d_in[13];
  float* out = (float*)d_out;

  if (ws_size < (size_t)(56u << 20)) return;  // need 56MB scratch

  char* ws = (char*)d_ws;
  u16* hbuf = (u16*)(ws + 0);             // 4MB: h (LN1 out), later attn output
  u16* Qb = (u16*)(ws + (4u << 20));      // 4MB
  u16* Kbf = (u16*)(ws + (8u << 20));     // 4MB
  u16* Vbf = (u16*)(ws + (12u << 20));    // 4MB
  u16* Vtb = (u16*)(ws + (16u << 20));    // 4MB: transposed V [16][64][2048]
  u16* ffact = Qb;                        // 16MB span 4-20MB (dead after attention)
  float* x2 = (float*)(ws + (20u << 20)); // 8MB
  u16* h2 = (u16*)(ws + (28u << 20));     // 4MB
  u16* wqb = (u16*)(ws + (32u << 20));
  u16* wkb = (u16*)(ws + (34u << 20));
  u16* wvb = (u16*)(ws + (36u << 20));
  u16* wob = (u16*)(ws + (38u << 20));
  u16* ff1wb = (u16*)(ws + (40u << 20));  // 8MB
  u16* ff2wb = (u16*)(ws + (48u << 20));  // 8MB
  u16* attnO = hbuf;

  // one fused weight-convert launch (3145728 float4 elements total)
  cvt_all<<<12288, 256, 0, stream>>>(wq, wk, wv, wo, ff1w, ff2w,
                                     wqb, wkb, wvb, wob, ff1wb, ff2wb);

  ln_rows<<<2048, 256, 0, stream>>>(x, ln1g, ln1b, hbuf);
  gemm_qkv<<<dim3(24, 16), 256, 0, stream>>>(hbuf, wqb, wkb, wvb, Qb, Kbf, Vbf);
  transpose_v<<<dim3(32, 16), 256, 0, stream>>>(Vbf, Vtb);
  attn_fwd<<<dim3(16, 16), 256, 0, stream>>>(Qb, Kbf, Vtb, slopes, attnO);
  // x2 = x + attnO @ wo^T
  gemm_bt<64, 128, 1, 4, 3><<<dim3(8, 32), 256, 0, stream>>>(
      attnO, wob, x2, nullptr, x, 2048, 1024, 1024);
  ln_rows<<<2048, 256, 0, stream>>>(x2, ln2g, ln2b, h2);
  // ffact = gelu(h2 @ ff1^T + b1)
  gemm_bt<128, 128, 2, 2, 1><<<dim3(32, 16), 256, 0, stream>>>(
      h2, ff1wb, ffact, ff1b, nullptr, 2048, 4096, 1024);
  // out = x2 + ffact @ ff2^T + b2
  gemm_bt<64, 128, 1, 4, 2><<<dim3(8, 32), 256, 0, stream>>>(
      ffact, ff2wb, out, ff2b, x2, 2048, 1024, 4096);
}

// Round 10
// 206.664 us; speedup vs baseline: 1.4205x; 1.1056x over previous
//
#include <hip/hip_runtime.h>
#include <math.h>

typedef unsigned short u16;
typedef __bf16 bf16x8 __attribute__((ext_vector_type(8)));
typedef float f32x4 __attribute__((ext_vector_type(4)));
typedef u16 u16x4 __attribute__((ext_vector_type(4)));
typedef u16 u16x8 __attribute__((ext_vector_type(8)));

#define DEV __device__ __forceinline__

// fp32 -> bf16 RNE (inputs are never NaN here)
DEV u16 f2bf(float f) {
  unsigned u = __builtin_bit_cast(unsigned, f);
  u += 0x7FFFu + ((u >> 16) & 1u);
  return (u16)(u >> 16);
}
DEV float bf2f(u16 b) {
  unsigned u = ((unsigned)b) << 16;
  return __builtin_bit_cast(float, u);
}

// async global->LDS, 16B per lane; LDS dest is wave-uniform base + lane*16
DEV void gload16(const void* g, void* l) {
  __builtin_amdgcn_global_load_lds((__attribute__((address_space(1))) void*)g,
                                   (__attribute__((address_space(3))) void*)l, 16, 0, 0);
}

// ---------------- fused fp32 -> bf16 convert (all 6 weights, one launch) ----------------
__launch_bounds__(256)
__global__ void cvt_all(const float* __restrict__ wq, const float* __restrict__ wk,
                        const float* __restrict__ wv, const float* __restrict__ wo,
                        const float* __restrict__ f1, const float* __restrict__ f2,
                        u16* __restrict__ dq, u16* __restrict__ dk, u16* __restrict__ dv,
                        u16* __restrict__ dwo, u16* __restrict__ df1, u16* __restrict__ df2) {
  int i = blockIdx.x * 256 + threadIdx.x;  // float4 index; total 3145728
  const float* src;
  u16* dst;
  int local;
  if (i < (1 << 18)) { src = wq; dst = dq; local = i; }
  else if (i < (2 << 18)) { src = wk; dst = dk; local = i - (1 << 18); }
  else if (i < (3 << 18)) { src = wv; dst = dv; local = i - (2 << 18); }
  else if (i < (4 << 18)) { src = wo; dst = dwo; local = i - (3 << 18); }
  else if (i < (4 << 18) + (1 << 20)) { src = f1; dst = df1; local = i - (4 << 18); }
  else { src = f2; dst = df2; local = i - ((4 << 18) + (1 << 20)); }
  float4 v = ((const float4*)src)[local];
  u16x4 o = { f2bf(v.x), f2bf(v.y), f2bf(v.z), f2bf(v.w) };
  ((u16x4*)dst)[local] = o;
}

// ---------------- LayerNorm over D=1024, one block per row ----------------
__launch_bounds__(256)
__global__ void ln_rows(const float* __restrict__ x, const float* __restrict__ gam,
                        const float* __restrict__ bet, u16* __restrict__ out) {
  int row = blockIdx.x;
  int t = threadIdx.x;
  float4 v = ((const float4*)(x + (size_t)row * 1024))[t];
  float s = v.x + v.y + v.z + v.w;
  float s2 = v.x * v.x + v.y * v.y + v.z * v.z + v.w * v.w;
  for (int off = 1; off < 64; off <<= 1) {
    s += __shfl_xor(s, off);
    s2 += __shfl_xor(s2, off);
  }
  __shared__ float red[8];
  int wv = t >> 6, ln = t & 63;
  if (ln == 0) { red[wv] = s; red[wv + 4] = s2; }
  __syncthreads();
  s = red[0] + red[1] + red[2] + red[3];
  s2 = red[4] + red[5] + red[6] + red[7];
  float mu = s * (1.f / 1024.f);
  float var = s2 * (1.f / 1024.f) - mu * mu;
  float rs = rsqrtf(var + 1e-5f);
  float4 gv = ((const float4*)gam)[t];
  float4 bv = ((const float4*)bet)[t];
  u16x4 o = { f2bf((v.x - mu) * rs * gv.x + bv.x), f2bf((v.y - mu) * rs * gv.y + bv.y),
              f2bf((v.z - mu) * rs * gv.z + bv.z), f2bf((v.w - mu) * rs * gv.w + bv.w) };
  ((u16x4*)(out + (size_t)row * 1024))[t] = o;
}

// ---------------- fused: x2 = x + P0 + P1 (wo split-K partials); h2 = LN(x2) ----------
__launch_bounds__(256)
__global__ void ln2_add(const float* __restrict__ x, const float* __restrict__ P0,
                        const float* __restrict__ P1, const float* __restrict__ gam,
                        const float* __restrict__ bet, float* __restrict__ x2,
                        u16* __restrict__ out) {
  int row = blockIdx.x;
  int t = threadIdx.x;
  size_t base = (size_t)row * 256 + t;
  float4 xv = ((const float4*)x)[base];
  float4 p0 = ((const float4*)P0)[base];
  float4 p1 = ((const float4*)P1)[base];
  float4 v = { xv.x + p0.x + p1.x, xv.y + p0.y + p1.y,
               xv.z + p0.z + p1.z, xv.w + p0.w + p1.w };
  ((float4*)x2)[base] = v;
  float s = v.x + v.y + v.z + v.w;
  float s2 = v.x * v.x + v.y * v.y + v.z * v.z + v.w * v.w;
  for (int off = 1; off < 64; off <<= 1) {
    s += __shfl_xor(s, off);
    s2 += __shfl_xor(s2, off);
  }
  __shared__ float red[8];
  int wv = t >> 6, ln = t & 63;
  if (ln == 0) { red[wv] = s; red[wv + 4] = s2; }
  __syncthreads();
  s = red[0] + red[1] + red[2] + red[3];
  s2 = red[4] + red[5] + red[6] + red[7];
  float mu = s * (1.f / 1024.f);
  float var = s2 * (1.f / 1024.f) - mu * mu;
  float rs = rsqrtf(var + 1e-5f);
  float4 gv = ((const float4*)gam)[t];
  float4 bv = ((const float4*)bet)[t];
  u16x4 o = { f2bf((v.x - mu) * rs * gv.x + bv.x), f2bf((v.y - mu) * rs * gv.y + bv.y),
              f2bf((v.z - mu) * rs * gv.z + bv.z), f2bf((v.w - mu) * rs * gv.w + bv.w) };
  ((u16x4*)(out + (size_t)row * 1024))[t] = o;
}

// ---------------- final: out = x2 + b2 + Q0 + Q1 (ff2 split-K bf16 partials) --------
__launch_bounds__(256)
__global__ void final_add(const float* __restrict__ x2, const float* __restrict__ b2,
                          const u16* __restrict__ Q0, const u16* __restrict__ Q1,
                          float* __restrict__ out) {
  int row = blockIdx.x;
  int t = threadIdx.x;
  size_t base = (size_t)row * 256 + t;
  float4 xv = ((const float4*)x2)[base];
  float4 bv = ((const float4*)b2)[t];
  u16x4 q0 = ((const u16x4*)Q0)[base];
  u16x4 q1 = ((const u16x4*)Q1)[base];
  float4 o = { xv.x + bv.x + bf2f(q0[0]) + bf2f(q1[0]),
               xv.y + bv.y + bf2f(q0[1]) + bf2f(q1[1]),
               xv.z + bv.z + bf2f(q0[2]) + bf2f(q1[2]),
               xv.w + bv.w + bf2f(q0[3]) + bf2f(q1[3]) };
  ((float4*)out)[base] = o;
}

// ---------------- V transpose: Vt[h][d][s] = V[s][h*64+d] ----------------
__launch_bounds__(256)
__global__ void transpose_v(const u16* __restrict__ V, u16* __restrict__ Vt) {
  const int st = blockIdx.x, h = blockIdx.y;
  __shared__ u16 tile[64][72];
  const int t = threadIdx.x;
  const int r = t >> 3, c8 = t & 7;
#pragma unroll
  for (int i = 0; i < 2; ++i) {
    int row = i * 32 + r;
    *(u16x8*)&tile[row][c8 * 8] =
        *(const u16x8*)&V[(size_t)(st * 64 + row) * 1024 + h * 64 + c8 * 8];
  }
  __syncthreads();
#pragma unroll
  for (int i = 0; i < 2; ++i) {
    int d = i * 32 + r;
    u16x8 o;
#pragma unroll
    for (int jj = 0; jj < 8; ++jj) o[jj] = tile[c8 * 8 + jj][d];
    *(u16x8*)&Vt[(size_t)(h * 64 + d) * 2048 + st * 64 + c8 * 8] = o;
  }
}

// ---------------- generic bf16 GEMM: C[M,N] = A[M,K] @ B[N,K]^T (BK=32) ----------------
// EPI: 0 = store bf16 raw (at zoff*blockIdx.z); 1 = +bias exact-GELU bf16;
//      2 = +bias +resid f32; 3 = +resid f32; 4 = store f32 raw (at zoff*blockIdx.z)
// SPLITK: blockIdx.z selects K-slice of size K/SPLITK.
template <int BM, int BN, int WR, int WC, int EPI, int SPLITK>
__launch_bounds__(256, 2)
__global__ void gemm_bt(const u16* __restrict__ A, const u16* __restrict__ B,
                        void* __restrict__ C, const float* __restrict__ bias,
                        const float* __restrict__ resid, int M, int N, int K,
                        size_t zoff) {
  constexpr int FM = BM / WR / 16;
  constexpr int FN = BN / WC / 16;
  __shared__ u16 As[BM * 32];
  __shared__ u16 Bs[BN * 32];
  const int t = threadIdx.x, lane = t & 63, w = t >> 6;
  const int wr = w / WC, wc = w % WC;
  const int g = lane >> 4, l16 = lane & 15;
  const int m0 = blockIdx.y * BM, n0 = blockIdx.x * BN;
  const int ks = K / SPLITK;
  const int k0 = (SPLITK > 1) ? blockIdx.z * ks : 0;
  const size_t cbase = (SPLITK > 1) ? (size_t)blockIdx.z * zoff : 0;
  f32x4 acc[FM][FN] = {};
  const int nkt = ks >> 5;
  for (int kt = 0; kt < nkt; ++kt) {
    const u16* Ag = A + (size_t)m0 * K + k0 + kt * 32;
    const u16* Bg = B + (size_t)n0 * K + k0 + kt * 32;
#pragma unroll
    for (int i = 0; i < BM / 64; ++i) {
      int c = i * 256 + t;
      gload16(Ag + (size_t)(c >> 2) * K + (c & 3) * 8, &As[(i * 256 + w * 64) * 8]);
    }
#pragma unroll
    for (int i = 0; i < BN / 64; ++i) {
      int c = i * 256 + t;
      gload16(Bg + (size_t)(c >> 2) * K + (c & 3) * 8, &Bs[(i * 256 + w * 64) * 8]);
    }
    __syncthreads();
    bf16x8 af[FM], bfr[FN];
#pragma unroll
    for (int m = 0; m < FM; ++m)
      af[m] = *(const bf16x8*)&As[(wr * FM * 16 + m * 16 + l16) * 32 + g * 8];
#pragma unroll
    for (int n = 0; n < FN; ++n)
      bfr[n] = *(const bf16x8*)&Bs[(wc * FN * 16 + n * 16 + l16) * 32 + g * 8];
#pragma unroll
    for (int m = 0; m < FM; ++m)
#pragma unroll
      for (int n = 0; n < FN; ++n)
        acc[m][n] = __builtin_amdgcn_mfma_f32_16x16x32_bf16(af[m], bfr[n], acc[m][n], 0, 0, 0);
    __syncthreads();
  }
#pragma unroll
  for (int m = 0; m < FM; ++m)
#pragma unroll
    for (int n = 0; n < FN; ++n)
#pragma unroll
      for (int r = 0; r < 4; ++r) {
        int row = m0 + wr * FM * 16 + m * 16 + g * 4 + r;
        int col = n0 + wc * FN * 16 + n * 16 + l16;
        size_t idx = (size_t)row * N + col;
        float v = acc[m][n][r];
        if constexpr (EPI == 0) {
          ((u16*)C)[cbase + idx] = f2bf(v);
        } else if constexpr (EPI == 1) {
          v += bias[col];
          v = 0.5f * v * (1.f + erff(v * 0.70710678118f));
          ((u16*)C)[idx] = f2bf(v);
        } else if constexpr (EPI == 2) {
          ((float*)C)[idx] = v + bias[col] + resid[idx];
        } else if constexpr (EPI == 3) {
          ((float*)C)[idx] = v + resid[idx];
        } else {
          ((float*)C)[cbase + idx] = v;
        }
      }
}

// ---------------- fused QKV projection, 64x128 tiles (768 blocks = 3/CU) ----------------
__launch_bounds__(256, 2)
__global__ void gemm_qkv64(const u16* __restrict__ A, const u16* __restrict__ B0,
                           const u16* __restrict__ B1, const u16* __restrict__ B2,
                           u16* __restrict__ C0, u16* __restrict__ C1, u16* __restrict__ C2) {
  constexpr int FM = 4, FN = 2;
  const int K = 1024, N = 1024;
  const int which = blockIdx.x >> 3;
  const u16* B = which == 0 ? B0 : which == 1 ? B1 : B2;
  u16* C = which == 0 ? C0 : which == 1 ? C1 : C2;
  __shared__ u16 As[64 * 32];
  __shared__ u16 Bs[128 * 32];
  const int t = threadIdx.x, lane = t & 63, w = t >> 6;
  const int wc = w;  // WR=1, WC=4
  const int g = lane >> 4, l16 = lane & 15;
  const int m0 = blockIdx.y * 64, n0 = (blockIdx.x & 7) * 128;
  f32x4 acc[FM][FN] = {};
  for (int kt = 0; kt < 32; ++kt) {
    const u16* Ag = A + (size_t)m0 * K + kt * 32;
    const u16* Bg = B + (size_t)n0 * K + kt * 32;
    {
      int c = t;
      gload16(Ag + (size_t)(c >> 2) * K + (c & 3) * 8, &As[(w * 64) * 8]);
    }
#pragma unroll
    for (int i = 0; i < 2; ++i) {
      int c = i * 256 + t;
      gload16(Bg + (size_t)(c >> 2) * K + (c & 3) * 8, &Bs[(i * 256 + w * 64) * 8]);
    }
    __syncthreads();
    bf16x8 af[FM], bfr[FN];
#pragma unroll
    for (int m = 0; m < FM; ++m)
      af[m] = *(const bf16x8*)&As[(m * 16 + l16) * 32 + g * 8];
#pragma unroll
    for (int n = 0; n < FN; ++n)
      bfr[n] = *(const bf16x8*)&Bs[(wc * FN * 16 + n * 16 + l16) * 32 + g * 8];
#pragma unroll
    for (int m = 0; m < FM; ++m)
#pragma unroll
      for (int n = 0; n < FN; ++n)
        acc[m][n] = __builtin_amdgcn_mfma_f32_16x16x32_bf16(af[m], bfr[n], acc[m][n], 0, 0, 0);
    __syncthreads();
  }
#pragma unroll
  for (int m = 0; m < FM; ++m)
#pragma unroll
    for (int n = 0; n < FN; ++n)
#pragma unroll
      for (int r = 0; r < 4; ++r) {
        int row = m0 + m * 16 + g * 4 + r;
        int col = n0 + wc * FN * 16 + n * 16 + l16;
        C[(size_t)row * N + col] = f2bf(acc[m][n][r]);
      }
}

// ---------------- flash attention, causal + ALiBi (R9 winner: LDS-staged K/V) ----------
__launch_bounds__(256, 2)
__global__ void attn_fwd(const u16* __restrict__ Q, const u16* __restrict__ Kb,
                         const u16* __restrict__ Vt, const float* __restrict__ slopes,
                         u16* __restrict__ O) {
  const int bx = blockIdx.x;
  const int h = blockIdx.y;
  const int t = threadIdx.x, lane = t & 63, w = t >> 6;
  const int g = lane >> 4, l16 = lane & 15;
  const float slope = slopes[h];

  __shared__ u16 Ks[2][4096];
  __shared__ u16 Vs[2][4096];
  __shared__ u16 Ps[4][16][72];

  const int r0 = w * 8 + (lane >> 3), r1 = 32 + r0;
  const int c8 = lane & 7;
  const int c0s = c8 ^ (r0 & 7), c1s = c8 ^ (r1 & 7);
  const int sw = l16 & 7;

#pragma unroll 1
  for (int pi = 0; pi < 2; ++pi) {
    const int qb = pi == 0 ? bx : 31 - bx;
    const int q0 = qb * 64 + w * 16;

    bf16x8 qf[2];
#pragma unroll
    for (int kk = 0; kk < 2; ++kk)
      qf[kk] = *(const bf16x8*)&Q[(size_t)(q0 + l16) * 1024 + h * 64 + kk * 32 + g * 8];

    f32x4 o_acc[4] = {};
    float m_run[4], l_run[4];
#pragma unroll
    for (int r = 0; r < 4; ++r) { m_run[r] = -1e30f; l_run[r] = 0.f; }

    __syncthreads();
    gload16(Kb + (size_t)(0 + r0) * 1024 + h * 64 + c0s * 8, &Ks[0][(w * 64) * 8]);
    gload16(Kb + (size_t)(0 + r1) * 1024 + h * 64 + c1s * 8, &Ks[0][(256 + w * 64) * 8]);
    gload16(Vt + (size_t)(h * 64 + r0) * 2048 + 0 + c0s * 8, &Vs[0][(w * 64) * 8]);
    gload16(Vt + (size_t)(h * 64 + r1) * 2048 + 0 + c1s * 8, &Vs[0][(256 + w * 64) * 8]);
    __syncthreads();

    int cur = 0;
    for (int j = 0; j <= qb; ++j) {
      const int kv0 = j * 64;
      if (j < qb) {
        const int nv0 = kv0 + 64;
        gload16(Kb + (size_t)(nv0 + r0) * 1024 + h * 64 + c0s * 8, &Ks[cur ^ 1][(w * 64) * 8]);
        gload16(Kb + (size_t)(nv0 + r1) * 1024 + h * 64 + c1s * 8, &Ks[cur ^ 1][(256 + w * 64) * 8]);
        gload16(Vt + (size_t)(h * 64 + r0) * 2048 + nv0 + c0s * 8, &Vs[cur ^ 1][(w * 64) * 8]);
        gload16(Vt + (size_t)(h * 64 + r1) * 2048 + nv0 + c1s * 8, &Vs[cur ^ 1][(256 + w * 64) * 8]);
      }
      f32x4 s[4];
#pragma unroll
      for (int n = 0; n < 4; ++n) {
        bf16x8 kf0 = *(const bf16x8*)&Ks[cur][(n * 16 + l16) * 64 + ((g ^ sw) * 8)];
        bf16x8 kf1 = *(const bf16x8*)&Ks[cur][(n * 16 + l16) * 64 + (((4 + g) ^ sw) * 8)];
        f32x4 z = {};
        s[n] = __builtin_amdgcn_mfma_f32_16x16x32_bf16(qf[0], kf0, z, 0, 0, 0);
        s[n] = __builtin_amdgcn_mfma_f32_16x16x32_bf16(qf[1], kf1, s[n], 0, 0, 0);
      }
      float sv[4][4];
      float mtile[4] = { -1e30f, -1e30f, -1e30f, -1e30f };
#pragma unroll
      for (int n = 0; n < 4; ++n) {
        int kj = kv0 + n * 16 + l16;
#pragma unroll
        for (int r = 0; r < 4; ++r) {
          int qi = q0 + g * 4 + r;
          float val = s[n][r] * 0.125f - slope * (float)(kj - qi);
          val = (kj <= qi) ? val : -1e30f;
          sv[n][r] = val;
          mtile[r] = fmaxf(mtile[r], val);
        }
      }
#pragma unroll
      for (int r = 0; r < 4; ++r) {
        float v = mtile[r];
        v = fmaxf(v, __shfl_xor(v, 1));
        v = fmaxf(v, __shfl_xor(v, 2));
        v = fmaxf(v, __shfl_xor(v, 4));
        v = fmaxf(v, __shfl_xor(v, 8));
        mtile[r] = v;
      }
      float sc[4];
#pragma unroll
      for (int r = 0; r < 4; ++r) {
        float mnew = fmaxf(m_run[r], mtile[r]);
        sc[r] = __expf(m_run[r] - mnew);
        m_run[r] = mnew;
      }
      float tsum[4] = { 0.f, 0.f, 0.f, 0.f };
#pragma unroll
      for (int n = 0; n < 4; ++n)
#pragma unroll
        for (int r = 0; r < 4; ++r) {
          float p = __expf(sv[n][r] - m_run[r]);
          sv[n][r] = p;
          tsum[r] += p;
        }
#pragma unroll
      for (int r = 0; r < 4; ++r) {
        float v = tsum[r];
        v += __shfl_xor(v, 1);
        v += __shfl_xor(v, 2);
        v += __shfl_xor(v, 4);
        v += __shfl_xor(v, 8);
        l_run[r] = l_run[r] * sc[r] + v;
      }
#pragma unroll
      for (int d = 0; d < 4; ++d)
#pragma unroll
        for (int r = 0; r < 4; ++r) o_acc[d][r] *= sc[r];
#pragma unroll
      for (int n = 0; n < 4; ++n)
#pragma unroll
        for (int r = 0; r < 4; ++r)
          Ps[w][g * 4 + r][n * 16 + l16] = f2bf(sv[n][r]);
      bf16x8 pf[2];
#pragma unroll
      for (int kk = 0; kk < 2; ++kk)
        pf[kk] = *(const bf16x8*)&Ps[w][l16][kk * 32 + g * 8];
#pragma unroll
      for (int d = 0; d < 4; ++d) {
#pragma unroll
        for (int kk = 0; kk < 2; ++kk) {
          bf16x8 vv = *(const bf16x8*)&Vs[cur][(d * 16 + l16) * 64 + (((kk * 4 + g) ^ sw) * 8)];
          o_acc[d] = __builtin_amdgcn_mfma_f32_16x16x32_bf16(pf[kk], vv, o_acc[d], 0, 0, 0);
        }
      }
      __syncthreads();
      cur ^= 1;
    }
#pragma unroll
    for (int d = 0; d < 4; ++d)
#pragma unroll
      for (int r = 0; r < 4; ++r) {
        int row = q0 + g * 4 + r;
        O[(size_t)row * 1024 + h * 64 + d * 16 + l16] = f2bf(o_acc[d][r] / l_run[r]);
      }
  }
}

// ---------------- launcher ----------------
extern "C" void kernel_launch(void* const* d_in, const int* in_sizes, int n_in,
                              void* d_out, int out_size, void* d_ws, size_t ws_size,
                              hipStream_t stream) {
  const float* x = (const float*)d_in[0];
  const float* slopes = (const float*)d_in[1];
  const float* wq = (const float*)d_in[2];
  const float* wk = (const float*)d_in[3];
  const float* wv = (const float*)d_in[4];
  const float* wo = (const float*)d_in[5];
  const float* ff1w = (const float*)d_in[6];
  const float* ff1b = (const float*)d_in[7];
  const float* ff2w = (const float*)d_in[8];
  const float* ff2b = (const float*)d_in[9];
  const float* ln1g = (const float*)d_in[10];
  const float* ln1b = (const float*)d_in[11];
  const float* ln2g = (const float*)d_in[12];
  const float* ln2b = (const float*)d_in[13];
  float* out = (float*)d_out;

  if (ws_size < (size_t)(56u << 20)) return;  // need 56MB scratch

  char* ws = (char*)d_ws;
  u16* hbuf = (u16*)(ws + 0);             // 4MB: h (LN1 out) -> attnO -> ff2 partial Q0
  u16* Qb = (u16*)(ws + (4u << 20));      // 4MB
  u16* Kbf = (u16*)(ws + (8u << 20));     // 4MB
  u16* Vbf = (u16*)(ws + (12u << 20));    // 4MB
  u16* Vtb = (u16*)(ws + (16u << 20));    // 4MB: transposed V [16][64][2048]
  float* P0 = (float*)(ws + (4u << 20));  // 8MB wo partial z=0 (Qb/Kbf dead after attn)
  float* P1 = (float*)(ws + (12u << 20)); // 8MB wo partial z=1 (Vbf/Vtb dead after attn)
  u16* ffact = Qb;                        // 16MB span 4-20MB (P0/P1 dead after ln2_add)
  float* x2 = (float*)(ws + (20u << 20)); // 8MB
  u16* h2 = (u16*)(ws + (28u << 20));     // 4MB; dead after ff1 -> ff2 partial Q1
  u16* Q1p = h2;
  u16* wqb = (u16*)(ws + (32u << 20));
  u16* wkb = (u16*)(ws + (34u << 20));
  u16* wvb = (u16*)(ws + (36u << 20));
  u16* wob = (u16*)(ws + (38u << 20));
  u16* ff1wb = (u16*)(ws + (40u << 20));  // 8MB
  u16* ff2wb = (u16*)(ws + (48u << 20));  // 8MB
  u16* attnO = hbuf;
  u16* Q0p = hbuf;
  // Q1 partial offset in u16 elements from Q0p base: (28MB - 0MB)/2
  const size_t q1off = (size_t)(28u << 20) / 2;

  cvt_all<<<12288, 256, 0, stream>>>(wq, wk, wv, wo, ff1w, ff2w,
                                     wqb, wkb, wvb, wob, ff1wb, ff2wb);

  ln_rows<<<2048, 256, 0, stream>>>(x, ln1g, ln1b, hbuf);
  gemm_qkv64<<<dim3(24, 32), 256, 0, stream>>>(hbuf, wqb, wkb, wvb, Qb, Kbf, Vbf);
  transpose_v<<<dim3(32, 16), 256, 0, stream>>>(Vbf, Vtb);
  attn_fwd<<<dim3(16, 16), 256, 0, stream>>>(Qb, Kbf, Vtb, slopes, attnO);
  // wo projection, split-K=2 -> fp32 partials P0/P1 (contiguous, zoff = M*N)
  gemm_bt<64, 128, 1, 4, 4, 2><<<dim3(8, 32, 2), 256, 0, stream>>>(
      attnO, wob, P0, nullptr, nullptr, 2048, 1024, 1024, (size_t)2048 * 1024);
  // x2 = x + P0 + P1; h2 = LN2(x2)
  ln2_add<<<2048, 256, 0, stream>>>(x, P0, P1, ln2g, ln2b, x2, h2);
  // ffact = gelu(h2 @ ff1^T + b1)
  gemm_bt<128, 128, 2, 2, 1, 1><<<dim3(32, 16), 256, 0, stream>>>(
      h2, ff1wb, ffact, ff1b, nullptr, 2048, 4096, 1024, 0);
  // ff2, split-K=2 -> bf16 partials Q0p (hbuf) and Q1p (h2 region)
  gemm_bt<64, 128, 1, 4, 0, 2><<<dim3(8, 32, 2), 256, 0, stream>>>(
      ffact, ff2wb, Q0p, nullptr, nullptr, 2048, 1024, 4096, q1off);
  // out = x2 + b2 + Q0 + Q1
  final_add<<<2048, 256, 0, stream>>>(x2, ff2b, Q0p, Q1p, out);
}

// Round 11
// 192.214 us; speedup vs baseline: 1.5273x; 1.0752x over previous
//
#include <hip/hip_runtime.h>
#include <math.h>

typedef unsigned short u16;
typedef __bf16 bf16x8 __attribute__((ext_vector_type(8)));
typedef float f32x4 __attribute__((ext_vector_type(4)));
typedef u16 u16x4 __attribute__((ext_vector_type(4)));
typedef u16 u16x8 __attribute__((ext_vector_type(8)));

#define DEV __device__ __forceinline__

DEV u16 f2bf(float f) {
  unsigned u = __builtin_bit_cast(unsigned, f);
  u += 0x7FFFu + ((u >> 16) & 1u);
  return (u16)(u >> 16);
}
DEV float bf2f(u16 b) {
  unsigned u = ((unsigned)b) << 16;
  return __builtin_bit_cast(float, u);
}

DEV void gload16(const void* g, void* l) {
  __builtin_amdgcn_global_load_lds((__attribute__((address_space(1))) void*)g,
                                   (__attribute__((address_space(3))) void*)l, 16, 0, 0);
}

// ---------------- fused fp32 -> bf16 convert (all 6 weights, one launch) ----------------
__launch_bounds__(256)
__global__ void cvt_all(const float* __restrict__ wq, const float* __restrict__ wk,
                        const float* __restrict__ wv, const float* __restrict__ wo,
                        const float* __restrict__ f1, const float* __restrict__ f2,
                        u16* __restrict__ dq, u16* __restrict__ dk, u16* __restrict__ dv,
                        u16* __restrict__ dwo, u16* __restrict__ df1, u16* __restrict__ df2) {
  int i = blockIdx.x * 256 + threadIdx.x;
  const float* src;
  u16* dst;
  int local;
  if (i < (1 << 18)) { src = wq; dst = dq; local = i; }
  else if (i < (2 << 18)) { src = wk; dst = dk; local = i - (1 << 18); }
  else if (i < (3 << 18)) { src = wv; dst = dv; local = i - (2 << 18); }
  else if (i < (4 << 18)) { src = wo; dst = dwo; local = i - (3 << 18); }
  else if (i < (4 << 18) + (1 << 20)) { src = f1; dst = df1; local = i - (4 << 18); }
  else { src = f2; dst = df2; local = i - ((4 << 18) + (1 << 20)); }
  float4 v = ((const float4*)src)[local];
  u16x4 o = { f2bf(v.x), f2bf(v.y), f2bf(v.z), f2bf(v.w) };
  ((u16x4*)dst)[local] = o;
}

// ---------------- LayerNorm over D=1024, one block per row ----------------
__launch_bounds__(256)
__global__ void ln_rows(const float* __restrict__ x, const float* __restrict__ gam,
                        const float* __restrict__ bet, u16* __restrict__ out) {
  int row = blockIdx.x;
  int t = threadIdx.x;
  float4 v = ((const float4*)(x + (size_t)row * 1024))[t];
  float s = v.x + v.y + v.z + v.w;
  float s2 = v.x * v.x + v.y * v.y + v.z * v.z + v.w * v.w;
  for (int off = 1; off < 64; off <<= 1) {
    s += __shfl_xor(s, off);
    s2 += __shfl_xor(s2, off);
  }
  __shared__ float red[8];
  int wv = t >> 6, ln = t & 63;
  if (ln == 0) { red[wv] = s; red[wv + 4] = s2; }
  __syncthreads();
  s = red[0] + red[1] + red[2] + red[3];
  s2 = red[4] + red[5] + red[6] + red[7];
  float mu = s * (1.f / 1024.f);
  float var = s2 * (1.f / 1024.f) - mu * mu;
  float rs = rsqrtf(var + 1e-5f);
  float4 gv = ((const float4*)gam)[t];
  float4 bv = ((const float4*)bet)[t];
  u16x4 o = { f2bf((v.x - mu) * rs * gv.x + bv.x), f2bf((v.y - mu) * rs * gv.y + bv.y),
              f2bf((v.z - mu) * rs * gv.z + bv.z), f2bf((v.w - mu) * rs * gv.w + bv.w) };
  ((u16x4*)(out + (size_t)row * 1024))[t] = o;
}

// ---------------- fused: x2 = x + P0 + P1; h2 = LN(x2) ----------
__launch_bounds__(256)
__global__ void ln2_add(const float* __restrict__ x, const float* __restrict__ P0,
                        const float* __restrict__ P1, const float* __restrict__ gam,
                        const float* __restrict__ bet, float* __restrict__ x2,
                        u16* __restrict__ out) {
  int row = blockIdx.x;
  int t = threadIdx.x;
  size_t base = (size_t)row * 256 + t;
  float4 xv = ((const float4*)x)[base];
  float4 p0 = ((const float4*)P0)[base];
  float4 p1 = ((const float4*)P1)[base];
  float4 v = { xv.x + p0.x + p1.x, xv.y + p0.y + p1.y,
               xv.z + p0.z + p1.z, xv.w + p0.w + p1.w };
  ((float4*)x2)[base] = v;
  float s = v.x + v.y + v.z + v.w;
  float s2 = v.x * v.x + v.y * v.y + v.z * v.z + v.w * v.w;
  for (int off = 1; off < 64; off <<= 1) {
    s += __shfl_xor(s, off);
    s2 += __shfl_xor(s2, off);
  }
  __shared__ float red[8];
  int wv = t >> 6, ln = t & 63;
  if (ln == 0) { red[wv] = s; red[wv + 4] = s2; }
  __syncthreads();
  s = red[0] + red[1] + red[2] + red[3];
  s2 = red[4] + red[5] + red[6] + red[7];
  float mu = s * (1.f / 1024.f);
  float var = s2 * (1.f / 1024.f) - mu * mu;
  float rs = rsqrtf(var + 1e-5f);
  float4 gv = ((const float4*)gam)[t];
  float4 bv = ((const float4*)bet)[t];
  u16x4 o = { f2bf((v.x - mu) * rs * gv.x + bv.x), f2bf((v.y - mu) * rs * gv.y + bv.y),
              f2bf((v.z - mu) * rs * gv.z + bv.z), f2bf((v.w - mu) * rs * gv.w + bv.w) };
  ((u16x4*)(out + (size_t)row * 1024))[t] = o;
}

// ---------------- final: out = x2 + b2 + Q0 + Q1 ----------------
__launch_bounds__(256)
__global__ void final_add(const float* __restrict__ x2, const float* __restrict__ b2,
                          const u16* __restrict__ Q0, const u16* __restrict__ Q1,
                          float* __restrict__ out) {
  int row = blockIdx.x;
  int t = threadIdx.x;
  size_t base = (size_t)row * 256 + t;
  float4 xv = ((const float4*)x2)[base];
  float4 bv = ((const float4*)b2)[t];
  u16x4 q0 = ((const u16x4*)Q0)[base];
  u16x4 q1 = ((const u16x4*)Q1)[base];
  float4 o = { xv.x + bv.x + bf2f(q0[0]) + bf2f(q1[0]),
               xv.y + bv.y + bf2f(q0[1]) + bf2f(q1[1]),
               xv.z + bv.z + bf2f(q0[2]) + bf2f(q1[2]),
               xv.w + bv.w + bf2f(q0[3]) + bf2f(q1[3]) };
  ((float4*)out)[base] = o;
}

// ---------------- V transpose ----------------
__launch_bounds__(256)
__global__ void transpose_v(const u16* __restrict__ V, u16* __restrict__ Vt) {
  const int st = blockIdx.x, h = blockIdx.y;
  __shared__ u16 tile[64][72];
  const int t = threadIdx.x;
  const int r = t >> 3, c8 = t & 7;
#pragma unroll
  for (int i = 0; i < 2; ++i) {
    int row = i * 32 + r;
    *(u16x8*)&tile[row][c8 * 8] =
        *(const u16x8*)&V[(size_t)(st * 64 + row) * 1024 + h * 64 + c8 * 8];
  }
  __syncthreads();
#pragma unroll
  for (int i = 0; i < 2; ++i) {
    int d = i * 32 + r;
    u16x8 o;
#pragma unroll
    for (int jj = 0; jj < 8; ++jj) o[jj] = tile[c8 * 8 + jj][d];
    *(u16x8*)&Vt[(size_t)(h * 64 + d) * 2048 + st * 64 + c8 * 8] = o;
  }
}

// ---------------- generic bf16 GEMM (R10-proven) ----------------
template <int BM, int BN, int WR, int WC, int EPI, int SPLITK>
__launch_bounds__(256, 2)
__global__ void gemm_bt(const u16* __restrict__ A, const u16* __restrict__ B,
                        void* __restrict__ C, const float* __restrict__ bias,
                        const float* __restrict__ resid, int M, int N, int K,
                        size_t zoff) {
  constexpr int FM = BM / WR / 16;
  constexpr int FN = BN / WC / 16;
  __shared__ u16 As[BM * 32];
  __shared__ u16 Bs[BN * 32];
  const int t = threadIdx.x, lane = t & 63, w = t >> 6;
  const int wr = w / WC, wc = w % WC;
  const int g = lane >> 4, l16 = lane & 15;
  const int m0 = blockIdx.y * BM, n0 = blockIdx.x * BN;
  const int ks = K / SPLITK;
  const int k0 = (SPLITK > 1) ? blockIdx.z * ks : 0;
  const size_t cbase = (SPLITK > 1) ? (size_t)blockIdx.z * zoff : 0;
  f32x4 acc[FM][FN] = {};
  const int nkt = ks >> 5;
  for (int kt = 0; kt < nkt; ++kt) {
    const u16* Ag = A + (size_t)m0 * K + k0 + kt * 32;
    const u16* Bg = B + (size_t)n0 * K + k0 + kt * 32;
#pragma unroll
    for (int i = 0; i < BM / 64; ++i) {
      int c = i * 256 + t;
      gload16(Ag + (size_t)(c >> 2) * K + (c & 3) * 8, &As[(i * 256 + w * 64) * 8]);
    }
#pragma unroll
    for (int i = 0; i < BN / 64; ++i) {
      int c = i * 256 + t;
      gload16(Bg + (size_t)(c >> 2) * K + (c & 3) * 8, &Bs[(i * 256 + w * 64) * 8]);
    }
    __syncthreads();
    bf16x8 af[FM], bfr[FN];
#pragma unroll
    for (int m = 0; m < FM; ++m)
      af[m] = *(const bf16x8*)&As[(wr * FM * 16 + m * 16 + l16) * 32 + g * 8];
#pragma unroll
    for (int n = 0; n < FN; ++n)
      bfr[n] = *(const bf16x8*)&Bs[(wc * FN * 16 + n * 16 + l16) * 32 + g * 8];
#pragma unroll
    for (int m = 0; m < FM; ++m)
#pragma unroll
      for (int n = 0; n < FN; ++n)
        acc[m][n] = __builtin_amdgcn_mfma_f32_16x16x32_bf16(af[m], bfr[n], acc[m][n], 0, 0, 0);
    __syncthreads();
  }
#pragma unroll
  for (int m = 0; m < FM; ++m)
#pragma unroll
    for (int n = 0; n < FN; ++n)
#pragma unroll
      for (int r = 0; r < 4; ++r) {
        int row = m0 + wr * FM * 16 + m * 16 + g * 4 + r;
        int col = n0 + wc * FN * 16 + n * 16 + l16;
        size_t idx = (size_t)row * N + col;
        float v = acc[m][n][r];
        if constexpr (EPI == 0) {
          ((u16*)C)[cbase + idx] = f2bf(v);
        } else if constexpr (EPI == 1) {
          v += bias[col];
          v = 0.5f * v * (1.f + erff(v * 0.70710678118f));
          ((u16*)C)[idx] = f2bf(v);
        } else if constexpr (EPI == 2) {
          ((float*)C)[idx] = v + bias[col] + resid[idx];
        } else if constexpr (EPI == 3) {
          ((float*)C)[idx] = v + resid[idx];
        } else {
          ((float*)C)[cbase + idx] = v;
        }
      }
}

// ---------------- fused QKV projection, 64x128 tiles (R10-proven) ----------------
__launch_bounds__(256, 2)
__global__ void gemm_qkv64(const u16* __restrict__ A, const u16* __restrict__ B0,
                           const u16* __restrict__ B1, const u16* __restrict__ B2,
                           u16* __restrict__ C0, u16* __restrict__ C1, u16* __restrict__ C2) {
  constexpr int FM = 4, FN = 2;
  const int K = 1024, N = 1024;
  const int which = blockIdx.x >> 3;
  const u16* B = which == 0 ? B0 : which == 1 ? B1 : B2;
  u16* C = which == 0 ? C0 : which == 1 ? C1 : C2;
  __shared__ u16 As[64 * 32];
  __shared__ u16 Bs[128 * 32];
  const int t = threadIdx.x, lane = t & 63, w = t >> 6;
  const int wc = w;
  const int g = lane >> 4, l16 = lane & 15;
  const int m0 = blockIdx.y * 64, n0 = (blockIdx.x & 7) * 128;
  f32x4 acc[FM][FN] = {};
  for (int kt = 0; kt < 32; ++kt) {
    const u16* Ag = A + (size_t)m0 * K + kt * 32;
    const u16* Bg = B + (size_t)n0 * K + kt * 32;
    {
      int c = t;
      gload16(Ag + (size_t)(c >> 2) * K + (c & 3) * 8, &As[(w * 64) * 8]);
    }
#pragma unroll
    for (int i = 0; i < 2; ++i) {
      int c = i * 256 + t;
      gload16(Bg + (size_t)(c >> 2) * K + (c & 3) * 8, &Bs[(i * 256 + w * 64) * 8]);
    }
    __syncthreads();
    bf16x8 af[FM], bfr[FN];
#pragma unroll
    for (int m = 0; m < FM; ++m)
      af[m] = *(const bf16x8*)&As[(m * 16 + l16) * 32 + g * 8];
#pragma unroll
    for (int n = 0; n < FN; ++n)
      bfr[n] = *(const bf16x8*)&Bs[(wc * FN * 16 + n * 16 + l16) * 32 + g * 8];
#pragma unroll
    for (int m = 0; m < FM; ++m)
#pragma unroll
      for (int n = 0; n < FN; ++n)
        acc[m][n] = __builtin_amdgcn_mfma_f32_16x16x32_bf16(af[m], bfr[n], acc[m][n], 0, 0, 0);
    __syncthreads();
  }
#pragma unroll
  for (int m = 0; m < FM; ++m)
#pragma unroll
    for (int n = 0; n < FN; ++n)
#pragma unroll
      for (int r = 0; r < 4; ++r) {
        int row = m0 + m * 16 + g * 4 + r;
        int col = n0 + wc * FN * 16 + n * 16 + l16;
        C[(size_t)row * N + col] = f2bf(acc[m][n][r]);
      }
}

// ---------------- flash attention: 8 waves = 2 groups x 4 waves, 2 waves/SIMD ----------
// Block (bx,h): pooled 33 j-tiles of chunk pair A=qb bx (TA=bx+1<=16 tiles) and
// B=qb 31-bx. Group 0 (waves 0-3) runs pooled [0,17): all of A + head of B.
// Group 1 (waves 4-7) runs pooled [17,33): tail of B. Each group has its own
// double-buffered LDS K/V staging (R10-proven path). A stored directly by
// group 0; B merged from 2 fp32 partials in LDS. Uniform 17/16-iter lockstep.
__launch_bounds__(512, 1)
__global__ void attn_fwd(const u16* __restrict__ Q, const u16* __restrict__ Kb,
                         const u16* __restrict__ Vt, const float* __restrict__ slopes,
                         u16* __restrict__ O) {
  const int bx = blockIdx.x;
  const int h = blockIdx.y;
  const int t = threadIdx.x, lane = t & 63, w8 = t >> 6;
  const int grp = w8 >> 2, w = w8 & 3;
  const int g = lane >> 4, l16 = lane & 15;
  const float slope = slopes[h];
  const int TA = bx + 1;            // tiles in chunk A (<=16)
  const int qbB = 31 - bx;

  __shared__ u16 Ks[2][2][4096];    // [grp][buf]
  __shared__ u16 Vs[2][2][4096];
  __shared__ u16 Ps[8][16][72];
  __shared__ float Bo[2][64][68];   // chunk-B fp32 partials [slot][row][col]
  __shared__ float Bm[2][64], Bl[2][64];

  const int r0 = w * 8 + (lane >> 3), r1 = 32 + r0;
  const int c8 = lane & 7;
  const int c0s = c8 ^ (r0 & 7), c1s = c8 ^ (r1 & 7);
  const int sw = l16 & 7;

  auto stage = [&](int buf, int kv0) {
    gload16(Kb + (size_t)(kv0 + r0) * 1024 + h * 64 + c0s * 8, &Ks[grp][buf][(w * 64) * 8]);
    gload16(Kb + (size_t)(kv0 + r1) * 1024 + h * 64 + c1s * 8, &Ks[grp][buf][(256 + w * 64) * 8]);
    gload16(Vt + (size_t)(h * 64 + r0) * 2048 + kv0 + c0s * 8, &Vs[grp][buf][(w * 64) * 8]);
    gload16(Vt + (size_t)(h * 64 + r1) * 2048 + kv0 + c1s * 8, &Vs[grp][buf][(256 + w * 64) * 8]);
  };
  // pooled idx -> kv0 (chunk implied: idx<TA ? A : B)
  auto kvOf = [&](int idx) { return idx < TA ? idx * 64 : (idx - TA) * 64; };

  const int myStart = grp * 17;
  const int myEnd = grp == 0 ? 17 : 33;

  // current chunk state
  int qb = grp == 0 ? bx : qbB;
  int q0 = qb * 64 + w * 16;
  bf16x8 qf[2];
#pragma unroll
  for (int kk = 0; kk < 2; ++kk)
    qf[kk] = *(const bf16x8*)&Q[(size_t)(q0 + l16) * 1024 + h * 64 + kk * 32 + g * 8];
  f32x4 o_acc[4] = {};
  float m_run[4], l_run[4];
#pragma unroll
  for (int r = 0; r < 4; ++r) { m_run[r] = -1e30f; l_run[r] = 0.f; }

  stage(0, kvOf(myStart));
  __syncthreads();

  int cur = 0;
  for (int it = 0; it < 17; ++it) {
    const int idx = myStart + it;
    const bool active = idx < myEnd;
    // group 0 crosses A->B exactly once (TA<=16)
    if (grp == 0 && idx == TA) {
      // finalize chunk A: normalize + store direct
#pragma unroll
      for (int d = 0; d < 4; ++d)
#pragma unroll
        for (int r = 0; r < 4; ++r) {
          int row = q0 + g * 4 + r;
          O[(size_t)row * 1024 + h * 64 + d * 16 + l16] = f2bf(o_acc[d][r] / l_run[r]);
        }
      qb = qbB;
      q0 = qb * 64 + w * 16;
#pragma unroll
      for (int kk = 0; kk < 2; ++kk)
        qf[kk] = *(const bf16x8*)&Q[(size_t)(q0 + l16) * 1024 + h * 64 + kk * 32 + g * 8];
#pragma unroll
      for (int d = 0; d < 4; ++d) o_acc[d] = f32x4{};
#pragma unroll
      for (int r = 0; r < 4; ++r) { m_run[r] = -1e30f; l_run[r] = 0.f; }
    }
    if (idx + 1 < myEnd) stage(cur ^ 1, kvOf(idx + 1));
    if (active) {
      const int kv0 = kvOf(idx);
      f32x4 s[4];
      __builtin_amdgcn_s_setprio(1);
#pragma unroll
      for (int n = 0; n < 4; ++n) {
        bf16x8 kf0 = *(const bf16x8*)&Ks[grp][cur][(n * 16 + l16) * 64 + ((g ^ sw) * 8)];
        bf16x8 kf1 = *(const bf16x8*)&Ks[grp][cur][(n * 16 + l16) * 64 + (((4 + g) ^ sw) * 8)];
        f32x4 z = {};
        s[n] = __builtin_amdgcn_mfma_f32_16x16x32_bf16(qf[0], kf0, z, 0, 0, 0);
        s[n] = __builtin_amdgcn_mfma_f32_16x16x32_bf16(qf[1], kf1, s[n], 0, 0, 0);
      }
      __builtin_amdgcn_s_setprio(0);
      float sv[4][4];
      float mtile[4] = { -1e30f, -1e30f, -1e30f, -1e30f };
#pragma unroll
      for (int n = 0; n < 4; ++n) {
        int kj = kv0 + n * 16 + l16;
#pragma unroll
        for (int r = 0; r < 4; ++r) {
          int qi = q0 + g * 4 + r;
          float val = s[n][r] * 0.125f - slope * (float)(kj - qi);
          val = (kj <= qi) ? val : -1e30f;
          sv[n][r] = val;
          mtile[r] = fmaxf(mtile[r], val);
        }
      }
#pragma unroll
      for (int r = 0; r < 4; ++r) {
        float v = mtile[r];
        v = fmaxf(v, __shfl_xor(v, 1));
        v = fmaxf(v, __shfl_xor(v, 2));
        v = fmaxf(v, __shfl_xor(v, 4));
        v = fmaxf(v, __shfl_xor(v, 8));
        mtile[r] = v;
      }
      float sc[4];
#pragma unroll
      for (int r = 0; r < 4; ++r) {
        float mnew = fmaxf(m_run[r], mtile[r]);
        sc[r] = __expf(m_run[r] - mnew);
        m_run[r] = mnew;
      }
      float tsum[4] = { 0.f, 0.f, 0.f, 0.f };
#pragma unroll
      for (int n = 0; n < 4; ++n)
#pragma unroll
        for (int r = 0; r < 4; ++r) {
          float p = __expf(sv[n][r] - m_run[r]);
          sv[n][r] = p;
          tsum[r] += p;
        }
#pragma unroll
      for (int r = 0; r < 4; ++r) {
        float v = tsum[r];
        v += __shfl_xor(v, 1);
        v += __shfl_xor(v, 2);
        v += __shfl_xor(v, 4);
        v += __shfl_xor(v, 8);
        l_run[r] = l_run[r] * sc[r] + v;
      }
#pragma unroll
      for (int d = 0; d < 4; ++d)
#pragma unroll
        for (int r = 0; r < 4; ++r) o_acc[d][r] *= sc[r];
#pragma unroll
      for (int n = 0; n < 4; ++n)
#pragma unroll
        for (int r = 0; r < 4; ++r)
          Ps[w8][g * 4 + r][n * 16 + l16] = f2bf(sv[n][r]);
      bf16x8 pf[2];
#pragma unroll
      for (int kk = 0; kk < 2; ++kk)
        pf[kk] = *(const bf16x8*)&Ps[w8][l16][kk * 32 + g * 8];
      __builtin_amdgcn_s_setprio(1);
#pragma unroll
      for (int d = 0; d < 4; ++d) {
#pragma unroll
        for (int kk = 0; kk < 2; ++kk) {
          bf16x8 vv = *(const bf16x8*)&Vs[grp][cur][(d * 16 + l16) * 64 + (((kk * 4 + g) ^ sw) * 8)];
          o_acc[d] = __builtin_amdgcn_mfma_f32_16x16x32_bf16(pf[kk], vv, o_acc[d], 0, 0, 0);
        }
      }
      __builtin_amdgcn_s_setprio(0);
    }
    __syncthreads();
    cur ^= 1;
  }
  // final state of both groups = chunk-B partial (grp0 always crossed: TA<=16)
#pragma unroll
  for (int d = 0; d < 4; ++d)
#pragma unroll
    for (int r = 0; r < 4; ++r)
      Bo[grp][w * 16 + g * 4 + r][d * 16 + l16] = o_acc[d][r];
  if (l16 == 0) {
#pragma unroll
    for (int r = 0; r < 4; ++r) {
      Bm[grp][w * 16 + g * 4 + r] = m_run[r];
      Bl[grp][w * 16 + g * 4 + r] = l_run[r];
    }
  }
  __syncthreads();
  if (grp == 0) {
#pragma unroll
    for (int rr = 0; rr < 4; ++rr) {
      const int row = w * 16 + g * 4 + rr;
      float m0 = Bm[0][row], m1 = Bm[1][row];
      float mm = fmaxf(m0, m1);
      float w0 = __expf(m0 - mm), w1 = __expf(m1 - mm);
      float ll = Bl[0][row] * w0 + Bl[1][row] * w1;
      float inv = 1.f / ll;
#pragma unroll
      for (int d = 0; d < 4; ++d) {
        int col = d * 16 + l16;
        float o = Bo[0][row][col] * w0 + Bo[1][row][col] * w1;
        O[(size_t)(qbB * 64 + row) * 1024 + h * 64 + col] = f2bf(o * inv);
      }
    }
  }
}

// ---------------- launcher ----------------
extern "C" void kernel_launch(void* const* d_in, const int* in_sizes, int n_in,
                              void* d_out, int out_size, void* d_ws, size_t ws_size,
                              hipStream_t stream) {
  const float* x = (const float*)d_in[0];
  const float* slopes = (const float*)d_in[1];
  const float* wq = (const float*)d_in[2];
  const float* wk = (const float*)d_in[3];
  const float* wv = (const float*)d_in[4];
  const float* wo = (const float*)d_in[5];
  const float* ff1w = (const float*)d_in[6];
  const float* ff1b = (const float*)d_in[7];
  const float* ff2w = (const float*)d_in[8];
  const float* ff2b = (const float*)d_in[9];
  const float* ln1g = (const float*)d_in[10];
  const float* ln1b = (const float*)d_in[11];
  const float* ln2g = (const float*)d_in[12];
  const float* ln2b = (const float*)d_in[13];
  float* out = (float*)d_out;

  if (ws_size < (size_t)(56u << 20)) return;  // need 56MB scratch

  char* ws = (char*)d_ws;
  u16* hbuf = (u16*)(ws + 0);
  u16* Qb = (u16*)(ws + (4u << 20));
  u16* Kbf = (u16*)(ws + (8u << 20));
  u16* Vbf = (u16*)(ws + (12u << 20));
  u16* Vtb = (u16*)(ws + (16u << 20));
  float* P0 = (float*)(ws + (4u << 20));
  float* P1 = (float*)(ws + (12u << 20));
  u16* ffact = Qb;
  float* x2 = (float*)(ws + (20u << 20));
  u16* h2 = (u16*)(ws + (28u << 20));
  u16* Q1p = h2;
  u16* wqb = (u16*)(ws + (32u << 20));
  u16* wkb = (u16*)(ws + (34u << 20));
  u16* wvb = (u16*)(ws + (36u << 20));
  u16* wob = (u16*)(ws + (38u << 20));
  u16* ff1wb = (u16*)(ws + (40u << 20));
  u16* ff2wb = (u16*)(ws + (48u << 20));
  u16* attnO = hbuf;
  u16* Q0p = hbuf;
  const size_t q1off = (size_t)(28u << 20) / 2;

  cvt_all<<<12288, 256, 0, stream>>>(wq, wk, wv, wo, ff1w, ff2w,
                                     wqb, wkb, wvb, wob, ff1wb, ff2wb);

  ln_rows<<<2048, 256, 0, stream>>>(x, ln1g, ln1b, hbuf);
  gemm_qkv64<<<dim3(24, 32), 256, 0, stream>>>(hbuf, wqb, wkb, wvb, Qb, Kbf, Vbf);
  transpose_v<<<dim3(32, 16), 256, 0, stream>>>(Vbf, Vtb);
  attn_fwd<<<dim3(16, 16), 512, 0, stream>>>(Qb, Kbf, Vtb, slopes, attnO);
  gemm_bt<64, 128, 1, 4, 4, 2><<<dim3(8, 32, 2), 256, 0, stream>>>(
      attnO, wob, P0, nullptr, nullptr, 2048, 1024, 1024, (size_t)2048 * 1024);
  ln2_add<<<2048, 256, 0, stream>>>(x, P0, P1, ln2g, ln2b, x2, h2);
  gemm_bt<128, 128, 2, 2, 1, 1><<<dim3(32, 16), 256, 0, stream>>>(
      h2, ff1wb, ffact, ff1b, nullptr, 2048, 4096, 1024, 0);
  gemm_bt<64, 128, 1, 4, 0, 2><<<dim3(8, 32, 2), 256, 0, stream>>>(
      ffact, ff2wb, Q0p, nullptr, nullptr, 2048, 1024, 4096, q1off);
  final_add<<<2048, 256, 0, stream>>>(x2, ff2b, Q0p, Q1p, out);
}

// Round 12
// 191.280 us; speedup vs baseline: 1.5348x; 1.0049x over previous
//
#include <hip/hip_runtime.h>
#include <math.h>

typedef unsigned short u16;
typedef __bf16 bf16x8 __attribute__((ext_vector_type(8)));
typedef float f32x4 __attribute__((ext_vector_type(4)));
typedef u16 u16x4 __attribute__((ext_vector_type(4)));
typedef u16 u16x8 __attribute__((ext_vector_type(8)));

#define DEV __device__ __forceinline__

DEV u16 f2bf(float f) {
  unsigned u = __builtin_bit_cast(unsigned, f);
  u += 0x7FFFu + ((u >> 16) & 1u);
  return (u16)(u >> 16);
}
DEV float bf2f(u16 b) {
  unsigned u = ((unsigned)b) << 16;
  return __builtin_bit_cast(float, u);
}

DEV void gload16(const void* g, void* l) {
  __builtin_amdgcn_global_load_lds((__attribute__((address_space(1))) void*)g,
                                   (__attribute__((address_space(3))) void*)l, 16, 0, 0);
}

// ---------------- fused fp32 -> bf16 convert (all 6 weights, one launch) ----------------
__launch_bounds__(256)
__global__ void cvt_all(const float* __restrict__ wq, const float* __restrict__ wk,
                        const float* __restrict__ wv, const float* __restrict__ wo,
                        const float* __restrict__ f1, const float* __restrict__ f2,
                        u16* __restrict__ dq, u16* __restrict__ dk, u16* __restrict__ dv,
                        u16* __restrict__ dwo, u16* __restrict__ df1, u16* __restrict__ df2) {
  int i = blockIdx.x * 256 + threadIdx.x;
  const float* src;
  u16* dst;
  int local;
  if (i < (1 << 18)) { src = wq; dst = dq; local = i; }
  else if (i < (2 << 18)) { src = wk; dst = dk; local = i - (1 << 18); }
  else if (i < (3 << 18)) { src = wv; dst = dv; local = i - (2 << 18); }
  else if (i < (4 << 18)) { src = wo; dst = dwo; local = i - (3 << 18); }
  else if (i < (4 << 18) + (1 << 20)) { src = f1; dst = df1; local = i - (4 << 18); }
  else { src = f2; dst = df2; local = i - ((4 << 18) + (1 << 20)); }
  float4 v = ((const float4*)src)[local];
  u16x4 o = { f2bf(v.x), f2bf(v.y), f2bf(v.z), f2bf(v.w) };
  ((u16x4*)dst)[local] = o;
}

// ---------------- LayerNorm over D=1024, one block per row ----------------
__launch_bounds__(256)
__global__ void ln_rows(const float* __restrict__ x, const float* __restrict__ gam,
                        const float* __restrict__ bet, u16* __restrict__ out) {
  int row = blockIdx.x;
  int t = threadIdx.x;
  float4 v = ((const float4*)(x + (size_t)row * 1024))[t];
  float s = v.x + v.y + v.z + v.w;
  float s2 = v.x * v.x + v.y * v.y + v.z * v.z + v.w * v.w;
  for (int off = 1; off < 64; off <<= 1) {
    s += __shfl_xor(s, off);
    s2 += __shfl_xor(s2, off);
  }
  __shared__ float red[8];
  int wv = t >> 6, ln = t & 63;
  if (ln == 0) { red[wv] = s; red[wv + 4] = s2; }
  __syncthreads();
  s = red[0] + red[1] + red[2] + red[3];
  s2 = red[4] + red[5] + red[6] + red[7];
  float mu = s * (1.f / 1024.f);
  float var = s2 * (1.f / 1024.f) - mu * mu;
  float rs = rsqrtf(var + 1e-5f);
  float4 gv = ((const float4*)gam)[t];
  float4 bv = ((const float4*)bet)[t];
  u16x4 o = { f2bf((v.x - mu) * rs * gv.x + bv.x), f2bf((v.y - mu) * rs * gv.y + bv.y),
              f2bf((v.z - mu) * rs * gv.z + bv.z), f2bf((v.w - mu) * rs * gv.w + bv.w) };
  ((u16x4*)(out + (size_t)row * 1024))[t] = o;
}

// ---------------- fused: x2 = x + P0 + P1; h2 = LN(x2) ----------
__launch_bounds__(256)
__global__ void ln2_add(const float* __restrict__ x, const float* __restrict__ P0,
                        const float* __restrict__ P1, const float* __restrict__ gam,
                        const float* __restrict__ bet, float* __restrict__ x2,
                        u16* __restrict__ out) {
  int row = blockIdx.x;
  int t = threadIdx.x;
  size_t base = (size_t)row * 256 + t;
  float4 xv = ((const float4*)x)[base];
  float4 p0 = ((const float4*)P0)[base];
  float4 p1 = ((const float4*)P1)[base];
  float4 v = { xv.x + p0.x + p1.x, xv.y + p0.y + p1.y,
               xv.z + p0.z + p1.z, xv.w + p0.w + p1.w };
  ((float4*)x2)[base] = v;
  float s = v.x + v.y + v.z + v.w;
  float s2 = v.x * v.x + v.y * v.y + v.z * v.z + v.w * v.w;
  for (int off = 1; off < 64; off <<= 1) {
    s += __shfl_xor(s, off);
    s2 += __shfl_xor(s2, off);
  }
  __shared__ float red[8];
  int wv = t >> 6, ln = t & 63;
  if (ln == 0) { red[wv] = s; red[wv + 4] = s2; }
  __syncthreads();
  s = red[0] + red[1] + red[2] + red[3];
  s2 = red[4] + red[5] + red[6] + red[7];
  float mu = s * (1.f / 1024.f);
  float var = s2 * (1.f / 1024.f) - mu * mu;
  float rs = rsqrtf(var + 1e-5f);
  float4 gv = ((const float4*)gam)[t];
  float4 bv = ((const float4*)bet)[t];
  u16x4 o = { f2bf((v.x - mu) * rs * gv.x + bv.x), f2bf((v.y - mu) * rs * gv.y + bv.y),
              f2bf((v.z - mu) * rs * gv.z + bv.z), f2bf((v.w - mu) * rs * gv.w + bv.w) };
  ((u16x4*)(out + (size_t)row * 1024))[t] = o;
}

// ---------------- final: out = x2 + b2 + Q0 + Q1 ----------------
__launch_bounds__(256)
__global__ void final_add(const float* __restrict__ x2, const float* __restrict__ b2,
                          const u16* __restrict__ Q0, const u16* __restrict__ Q1,
                          float* __restrict__ out) {
  int row = blockIdx.x;
  int t = threadIdx.x;
  size_t base = (size_t)row * 256 + t;
  float4 xv = ((const float4*)x2)[base];
  float4 bv = ((const float4*)b2)[t];
  u16x4 q0 = ((const u16x4*)Q0)[base];
  u16x4 q1 = ((const u16x4*)Q1)[base];
  float4 o = { xv.x + bv.x + bf2f(q0[0]) + bf2f(q1[0]),
               xv.y + bv.y + bf2f(q0[1]) + bf2f(q1[1]),
               xv.z + bv.z + bf2f(q0[2]) + bf2f(q1[2]),
               xv.w + bv.w + bf2f(q0[3]) + bf2f(q1[3]) };
  ((float4*)out)[base] = o;
}

// ---------------- V transpose ----------------
__launch_bounds__(256)
__global__ void transpose_v(const u16* __restrict__ V, u16* __restrict__ Vt) {
  const int st = blockIdx.x, h = blockIdx.y;
  __shared__ u16 tile[64][72];
  const int t = threadIdx.x;
  const int r = t >> 3, c8 = t & 7;
#pragma unroll
  for (int i = 0; i < 2; ++i) {
    int row = i * 32 + r;
    *(u16x8*)&tile[row][c8 * 8] =
        *(const u16x8*)&V[(size_t)(st * 64 + row) * 1024 + h * 64 + c8 * 8];
  }
  __syncthreads();
#pragma unroll
  for (int i = 0; i < 2; ++i) {
    int d = i * 32 + r;
    u16x8 o;
#pragma unroll
    for (int jj = 0; jj < 8; ++jj) o[jj] = tile[c8 * 8 + jj][d];
    *(u16x8*)&Vt[(size_t)(h * 64 + d) * 2048 + st * 64 + c8 * 8] = o;
  }
}

// ---------------- generic bf16 GEMM + XCD-swizzle ----------------
// SWZ 0: none. SWZ 1 (gx must be 8): XCD i owns n-strip x=i (B-slice L2-resident).
// SWZ 2 (gx=32, gy=16): XCD i owns x in [4i,4i+4); consecutive blocks share A-tile.
template <int BM, int BN, int WR, int WC, int EPI, int SPLITK, int SWZ>
__launch_bounds__(256, 2)
__global__ void gemm_bt(const u16* __restrict__ A, const u16* __restrict__ B,
                        void* __restrict__ C, const float* __restrict__ bias,
                        const float* __restrict__ resid, int M, int N, int K,
                        size_t zoff) {
  constexpr int FM = BM / WR / 16;
  constexpr int FN = BN / WC / 16;
  __shared__ u16 As[BM * 32];
  __shared__ u16 Bs[BN * 32];
  int bxi = blockIdx.x, byi = blockIdx.y, bzi = blockIdx.z;
  if constexpr (SWZ == 1) {
    int bid = bxi + 8 * (byi + (int)gridDim.y * bzi);
    int xcd = bid & 7, k = bid >> 3;
    bxi = xcd;
    byi = k % (int)gridDim.y;
    bzi = k / (int)gridDim.y;
  } else if constexpr (SWZ == 2) {
    int bid = bxi + 32 * byi;
    int xcd = bid & 7, k = bid >> 3;
    bxi = xcd * 4 + (k & 3);
    byi = k >> 2;
    bzi = 0;
  }
  const int t = threadIdx.x, lane = t & 63, w = t >> 6;
  const int wr = w / WC, wc = w % WC;
  const int g = lane >> 4, l16 = lane & 15;
  const int m0 = byi * BM, n0 = bxi * BN;
  const int ks = K / SPLITK;
  const int k0 = (SPLITK > 1) ? bzi * ks : 0;
  const size_t cbase = (SPLITK > 1) ? (size_t)bzi * zoff : 0;
  f32x4 acc[FM][FN] = {};
  const int nkt = ks >> 5;
  for (int kt = 0; kt < nkt; ++kt) {
    const u16* Ag = A + (size_t)m0 * K + k0 + kt * 32;
    const u16* Bg = B + (size_t)n0 * K + k0 + kt * 32;
#pragma unroll
    for (int i = 0; i < BM / 64; ++i) {
      int c = i * 256 + t;
      gload16(Ag + (size_t)(c >> 2) * K + (c & 3) * 8, &As[(i * 256 + w * 64) * 8]);
    }
#pragma unroll
    for (int i = 0; i < BN / 64; ++i) {
      int c = i * 256 + t;
      gload16(Bg + (size_t)(c >> 2) * K + (c & 3) * 8, &Bs[(i * 256 + w * 64) * 8]);
    }
    __syncthreads();
    bf16x8 af[FM], bfr[FN];
#pragma unroll
    for (int m = 0; m < FM; ++m)
      af[m] = *(const bf16x8*)&As[(wr * FM * 16 + m * 16 + l16) * 32 + g * 8];
#pragma unroll
    for (int n = 0; n < FN; ++n)
      bfr[n] = *(const bf16x8*)&Bs[(wc * FN * 16 + n * 16 + l16) * 32 + g * 8];
#pragma unroll
    for (int m = 0; m < FM; ++m)
#pragma unroll
      for (int n = 0; n < FN; ++n)
        acc[m][n] = __builtin_amdgcn_mfma_f32_16x16x32_bf16(af[m], bfr[n], acc[m][n], 0, 0, 0);
    __syncthreads();
  }
#pragma unroll
  for (int m = 0; m < FM; ++m)
#pragma unroll
    for (int n = 0; n < FN; ++n)
#pragma unroll
      for (int r = 0; r < 4; ++r) {
        int row = m0 + wr * FM * 16 + m * 16 + g * 4 + r;
        int col = n0 + wc * FN * 16 + n * 16 + l16;
        size_t idx = (size_t)row * N + col;
        float v = acc[m][n][r];
        if constexpr (EPI == 0) {
          ((u16*)C)[cbase + idx] = f2bf(v);
        } else if constexpr (EPI == 1) {
          v += bias[col];
          v = 0.5f * v * (1.f + erff(v * 0.70710678118f));
          ((u16*)C)[idx] = f2bf(v);
        } else if constexpr (EPI == 2) {
          ((float*)C)[idx] = v + bias[col] + resid[idx];
        } else if constexpr (EPI == 3) {
          ((float*)C)[idx] = v + resid[idx];
        } else {
          ((float*)C)[cbase + idx] = v;
        }
      }
}

// ---------------- fused QKV projection, 64x128 tiles + XCD swizzle ----------------
__launch_bounds__(256, 2)
__global__ void gemm_qkv64(const u16* __restrict__ A, const u16* __restrict__ B0,
                           const u16* __restrict__ B1, const u16* __restrict__ B2,
                           u16* __restrict__ C0, u16* __restrict__ C1, u16* __restrict__ C2) {
  constexpr int FM = 4, FN = 2;
  const int K = 1024, N = 1024;
  // XCD swizzle: 768 blocks; XCD i owns x-strips {3i,3i+1,3i+2} (B 768KB L2-resident)
  int bid = blockIdx.x + 24 * blockIdx.y;
  int xcd = bid & 7, kk0 = bid >> 3;
  const int bxs = xcd * 3 + kk0 % 3;
  const int bys = kk0 / 3;
  const int which = bxs >> 3;
  const u16* B = which == 0 ? B0 : which == 1 ? B1 : B2;
  u16* C = which == 0 ? C0 : which == 1 ? C1 : C2;
  __shared__ u16 As[64 * 32];
  __shared__ u16 Bs[128 * 32];
  const int t = threadIdx.x, lane = t & 63, w = t >> 6;
  const int wc = w;
  const int g = lane >> 4, l16 = lane & 15;
  const int m0 = bys * 64, n0 = (bxs & 7) * 128;
  f32x4 acc[FM][FN] = {};
  for (int kt = 0; kt < 32; ++kt) {
    const u16* Ag = A + (size_t)m0 * K + kt * 32;
    const u16* Bg = B + (size_t)n0 * K + kt * 32;
    {
      int c = t;
      gload16(Ag + (size_t)(c >> 2) * K + (c & 3) * 8, &As[(w * 64) * 8]);
    }
#pragma unroll
    for (int i = 0; i < 2; ++i) {
      int c = i * 256 + t;
      gload16(Bg + (size_t)(c >> 2) * K + (c & 3) * 8, &Bs[(i * 256 + w * 64) * 8]);
    }
    __syncthreads();
    bf16x8 af[FM], bfr[FN];
#pragma unroll
    for (int m = 0; m < FM; ++m)
      af[m] = *(const bf16x8*)&As[(m * 16 + l16) * 32 + g * 8];
#pragma unroll
    for (int n = 0; n < FN; ++n)
      bfr[n] = *(const bf16x8*)&Bs[(wc * FN * 16 + n * 16 + l16) * 32 + g * 8];
#pragma unroll
    for (int m = 0; m < FM; ++m)
#pragma unroll
      for (int n = 0; n < FN; ++n)
        acc[m][n] = __builtin_amdgcn_mfma_f32_16x16x32_bf16(af[m], bfr[n], acc[m][n], 0, 0, 0);
    __syncthreads();
  }
#pragma unroll
  for (int m = 0; m < FM; ++m)
#pragma unroll
    for (int n = 0; n < FN; ++n)
#pragma unroll
      for (int r = 0; r < 4; ++r) {
        int row = m0 + m * 16 + g * 4 + r;
        int col = n0 + wc * FN * 16 + n * 16 + l16;
        C[(size_t)row * N + col] = f2bf(acc[m][n][r]);
      }
}

// ---------------- flash attention: 8 waves = 2 groups x 4 waves (R11 champion) --------
// + ALiBi row-shift fold (softmax-invariant): score = fma(s, 0.125, -slope*kj);
// + causal mask only on each chunk's last tile (idx==TA-1 or idx==32).
__launch_bounds__(512, 1)
__global__ void attn_fwd(const u16* __restrict__ Q, const u16* __restrict__ Kb,
                         const u16* __restrict__ Vt, const float* __restrict__ slopes,
                         u16* __restrict__ O) {
  const int bx = blockIdx.x;
  const int h = blockIdx.y;
  const int t = threadIdx.x, lane = t & 63, w8 = t >> 6;
  const int grp = w8 >> 2, w = w8 & 3;
  const int g = lane >> 4, l16 = lane & 15;
  const float slope = slopes[h];
  const int TA = bx + 1;
  const int qbB = 31 - bx;

  __shared__ u16 Ks[2][2][4096];
  __shared__ u16 Vs[2][2][4096];
  __shared__ u16 Ps[8][16][72];
  __shared__ float Bo[2][64][68];
  __shared__ float Bm[2][64], Bl[2][64];

  const int r0 = w * 8 + (lane >> 3), r1 = 32 + r0;
  const int c8 = lane & 7;
  const int c0s = c8 ^ (r0 & 7), c1s = c8 ^ (r1 & 7);
  const int sw = l16 & 7;

  auto stage = [&](int buf, int kv0) {
    gload16(Kb + (size_t)(kv0 + r0) * 1024 + h * 64 + c0s * 8, &Ks[grp][buf][(w * 64) * 8]);
    gload16(Kb + (size_t)(kv0 + r1) * 1024 + h * 64 + c1s * 8, &Ks[grp][buf][(256 + w * 64) * 8]);
    gload16(Vt + (size_t)(h * 64 + r0) * 2048 + kv0 + c0s * 8, &Vs[grp][buf][(w * 64) * 8]);
    gload16(Vt + (size_t)(h * 64 + r1) * 2048 + kv0 + c1s * 8, &Vs[grp][buf][(256 + w * 64) * 8]);
  };
  auto kvOf = [&](int idx) { return idx < TA ? idx * 64 : (idx - TA) * 64; };

  const int myStart = grp * 17;
  const int myEnd = grp == 0 ? 17 : 33;

  int qb = grp == 0 ? bx : qbB;
  int q0 = qb * 64 + w * 16;
  bf16x8 qf[2];
#pragma unroll
  for (int kk = 0; kk < 2; ++kk)
    qf[kk] = *(const bf16x8*)&Q[(size_t)(q0 + l16) * 1024 + h * 64 + kk * 32 + g * 8];
  f32x4 o_acc[4] = {};
  float m_run[4], l_run[4];
#pragma unroll
  for (int r = 0; r < 4; ++r) { m_run[r] = -1e30f; l_run[r] = 0.f; }

  stage(0, kvOf(myStart));
  __syncthreads();

  int cur = 0;
  for (int it = 0; it < 17; ++it) {
    const int idx = myStart + it;
    const bool active = idx < myEnd;
    if (grp == 0 && idx == TA) {
#pragma unroll
      for (int d = 0; d < 4; ++d)
#pragma unroll
        for (int r = 0; r < 4; ++r) {
          int row = q0 + g * 4 + r;
          O[(size_t)row * 1024 + h * 64 + d * 16 + l16] = f2bf(o_acc[d][r] / l_run[r]);
        }
      qb = qbB;
      q0 = qb * 64 + w * 16;
#pragma unroll
      for (int kk = 0; kk < 2; ++kk)
        qf[kk] = *(const bf16x8*)&Q[(size_t)(q0 + l16) * 1024 + h * 64 + kk * 32 + g * 8];
#pragma unroll
      for (int d = 0; d < 4; ++d) o_acc[d] = f32x4{};
#pragma unroll
      for (int r = 0; r < 4; ++r) { m_run[r] = -1e30f; l_run[r] = 0.f; }
    }
    if (idx + 1 < myEnd) stage(cur ^ 1, kvOf(idx + 1));
    if (active) {
      const int kv0 = kvOf(idx);
      const bool lastT = (idx == TA - 1) || (idx == 32);
      f32x4 s[4];
      __builtin_amdgcn_s_setprio(1);
#pragma unroll
      for (int n = 0; n < 4; ++n) {
        bf16x8 kf0 = *(const bf16x8*)&Ks[grp][cur][(n * 16 + l16) * 64 + ((g ^ sw) * 8)];
        bf16x8 kf1 = *(const bf16x8*)&Ks[grp][cur][(n * 16 + l16) * 64 + (((4 + g) ^ sw) * 8)];
        f32x4 z = {};
        s[n] = __builtin_amdgcn_mfma_f32_16x16x32_bf16(qf[0], kf0, z, 0, 0, 0);
        s[n] = __builtin_amdgcn_mfma_f32_16x16x32_bf16(qf[1], kf1, s[n], 0, 0, 0);
      }
      __builtin_amdgcn_s_setprio(0);
      // ALiBi: +slope*qi row-shift dropped (softmax-invariant); only -slope*kj kept.
      float sv[4][4];
      float mtile[4] = { -1e30f, -1e30f, -1e30f, -1e30f };
      const float aB = -slope * (float)(kv0 + l16);
#pragma unroll
      for (int n = 0; n < 4; ++n) {
        const float aN = aB - slope * (float)(n * 16);
        const int kj = kv0 + n * 16 + l16;
#pragma unroll
        for (int r = 0; r < 4; ++r) {
          float val = fmaf(s[n][r], 0.125f, aN);
          if (lastT) {
            int qi = q0 + g * 4 + r;
            val = (kj <= qi) ? val : -1e30f;
          }
          sv[n][r] = val;
          mtile[r] = fmaxf(mtile[r], val);
        }
      }
#pragma unroll
      for (int r = 0; r < 4; ++r) {
        float v = mtile[r];
        v = fmaxf(v, __shfl_xor(v, 1));
        v = fmaxf(v, __shfl_xor(v, 2));
        v = fmaxf(v, __shfl_xor(v, 4));
        v = fmaxf(v, __shfl_xor(v, 8));
        mtile[r] = v;
      }
      float sc[4];
#pragma unroll
      for (int r = 0; r < 4; ++r) {
        float mnew = fmaxf(m_run[r], mtile[r]);
        sc[r] = __expf(m_run[r] - mnew);
        m_run[r] = mnew;
      }
      float tsum[4] = { 0.f, 0.f, 0.f, 0.f };
#pragma unroll
      for (int n = 0; n < 4; ++n)
#pragma unroll
        for (int r = 0; r < 4; ++r) {
          float p = __expf(sv[n][r] - m_run[r]);
          sv[n][r] = p;
          tsum[r] += p;
        }
#pragma unroll
      for (int r = 0; r < 4; ++r) {
        float v = tsum[r];
        v += __shfl_xor(v, 1);
        v += __shfl_xor(v, 2);
        v += __shfl_xor(v, 4);
        v += __shfl_xor(v, 8);
        l_run[r] = l_run[r] * sc[r] + v;
      }
#pragma unroll
      for (int d = 0; d < 4; ++d)
#pragma unroll
        for (int r = 0; r < 4; ++r) o_acc[d][r] *= sc[r];
#pragma unroll
      for (int n = 0; n < 4; ++n)
#pragma unroll
        for (int r = 0; r < 4; ++r)
          Ps[w8][g * 4 + r][n * 16 + l16] = f2bf(sv[n][r]);
      bf16x8 pf[2];
#pragma unroll
      for (int kk = 0; kk < 2; ++kk)
        pf[kk] = *(const bf16x8*)&Ps[w8][l16][kk * 32 + g * 8];
      __builtin_amdgcn_s_setprio(1);
#pragma unroll
      for (int d = 0; d < 4; ++d) {
#pragma unroll
        for (int kk = 0; kk < 2; ++kk) {
          bf16x8 vv = *(const bf16x8*)&Vs[grp][cur][(d * 16 + l16) * 64 + (((kk * 4 + g) ^ sw) * 8)];
          o_acc[d] = __builtin_amdgcn_mfma_f32_16x16x32_bf16(pf[kk], vv, o_acc[d], 0, 0, 0);
        }
      }
      __builtin_amdgcn_s_setprio(0);
    }
    __syncthreads();
    cur ^= 1;
  }
#pragma unroll
  for (int d = 0; d < 4; ++d)
#pragma unroll
    for (int r = 0; r < 4; ++r)
      Bo[grp][w * 16 + g * 4 + r][d * 16 + l16] = o_acc[d][r];
  if (l16 == 0) {
#pragma unroll
    for (int r = 0; r < 4; ++r) {
      Bm[grp][w * 16 + g * 4 + r] = m_run[r];
      Bl[grp][w * 16 + g * 4 + r] = l_run[r];
    }
  }
  __syncthreads();
  if (grp == 0) {
#pragma unroll
    for (int rr = 0; rr < 4; ++rr) {
      const int row = w * 16 + g * 4 + rr;
      float m0 = Bm[0][row], m1 = Bm[1][row];
      float mm = fmaxf(m0, m1);
      float w0 = __expf(m0 - mm), w1 = __expf(m1 - mm);
      float ll = Bl[0][row] * w0 + Bl[1][row] * w1;
      float inv = 1.f / ll;
#pragma unroll
      for (int d = 0; d < 4; ++d) {
        int col = d * 16 + l16;
        float o = Bo[0][row][col] * w0 + Bo[1][row][col] * w1;
        O[(size_t)(qbB * 64 + row) * 1024 + h * 64 + col] = f2bf(o * inv);
      }
    }
  }
}

// ---------------- launcher ----------------
extern "C" void kernel_launch(void* const* d_in, const int* in_sizes, int n_in,
                              void* d_out, int out_size, void* d_ws, size_t ws_size,
                              hipStream_t stream) {
  const float* x = (const float*)d_in[0];
  const float* slopes = (const float*)d_in[1];
  const float* wq = (const float*)d_in[2];
  const float* wk = (const float*)d_in[3];
  const float* wv = (const float*)d_in[4];
  const float* wo = (const float*)d_in[5];
  const float* ff1w = (const float*)d_in[6];
  const float* ff1b = (const float*)d_in[7];
  const float* ff2w = (const float*)d_in[8];
  const float* ff2b = (const float*)d_in[9];
  const float* ln1g = (const float*)d_in[10];
  const float* ln1b = (const float*)d_in[11];
  const float* ln2g = (const float*)d_in[12];
  const float* ln2b = (const float*)d_in[13];
  float* out = (float*)d_out;

  if (ws_size < (size_t)(56u << 20)) return;  // need 56MB scratch

  char* ws = (char*)d_ws;
  u16* hbuf = (u16*)(ws + 0);
  u16* Qb = (u16*)(ws + (4u << 20));
  u16* Kbf = (u16*)(ws + (8u << 20));
  u16* Vbf = (u16*)(ws + (12u << 20));
  u16* Vtb = (u16*)(ws + (16u << 20));
  float* P0 = (float*)(ws + (4u << 20));
  float* P1 = (float*)(ws + (12u << 20));
  u16* ffact = Qb;
  float* x2 = (float*)(ws + (20u << 20));
  u16* h2 = (u16*)(ws + (28u << 20));
  u16* Q1p = h2;
  u16* wqb = (u16*)(ws + (32u << 20));
  u16* wkb = (u16*)(ws + (34u << 20));
  u16* wvb = (u16*)(ws + (36u << 20));
  u16* wob = (u16*)(ws + (38u << 20));
  u16* ff1wb = (u16*)(ws + (40u << 20));
  u16* ff2wb = (u16*)(ws + (48u << 20));
  u16* attnO = hbuf;
  u16* Q0p = hbuf;
  const size_t q1off = (size_t)(28u << 20) / 2;

  cvt_all<<<12288, 256, 0, stream>>>(wq, wk, wv, wo, ff1w, ff2w,
                                     wqb, wkb, wvb, wob, ff1wb, ff2wb);

  ln_rows<<<2048, 256, 0, stream>>>(x, ln1g, ln1b, hbuf);
  gemm_qkv64<<<dim3(24, 32), 256, 0, stream>>>(hbuf, wqb, wkb, wvb, Qb, Kbf, Vbf);
  transpose_v<<<dim3(32, 16), 256, 0, stream>>>(Vbf, Vtb);
  attn_fwd<<<dim3(16, 16), 512, 0, stream>>>(Qb, Kbf, Vtb, slopes, attnO);
  gemm_bt<64, 128, 1, 4, 4, 2, 1><<<dim3(8, 32, 2), 256, 0, stream>>>(
      attnO, wob, P0, nullptr, nullptr, 2048, 1024, 1024, (size_t)2048 * 1024);
  ln2_add<<<2048, 256, 0, stream>>>(x, P0, P1, ln2g, ln2b, x2, h2);
  gemm_bt<128, 128, 2, 2, 1, 1, 2><<<dim3(32, 16), 256, 0, stream>>>(
      h2, ff1wb, ffact, ff1b, nullptr, 2048, 4096, 1024, 0);
  gemm_bt<64, 128, 1, 4, 0, 2, 1><<<dim3(8, 32, 2), 256, 0, stream>>>(
      ffact, ff2wb, Q0p, nullptr, nullptr, 2048, 1024, 4096, q1off);
  final_add<<<2048, 256, 0, stream>>>(x2, ff2b, Q0p, Q1p, out);
}

// Round 13
// 189.918 us; speedup vs baseline: 1.5458x; 1.0072x over previous
//
#include <hip/hip_runtime.h>
#include <math.h>

typedef unsigned short u16;
typedef __bf16 bf16x8 __attribute__((ext_vector_type(8)));
typedef float f32x4 __attribute__((ext_vector_type(4)));
typedef u16 u16x4 __attribute__((ext_vector_type(4)));
typedef u16 u16x8 __attribute__((ext_vector_type(8)));

#define DEV __device__ __forceinline__

DEV u16 f2bf(float f) {
  unsigned u = __builtin_bit_cast(unsigned, f);
  u += 0x7FFFu + ((u >> 16) & 1u);
  return (u16)(u >> 16);
}
DEV float bf2f(u16 b) {
  unsigned u = ((unsigned)b) << 16;
  return __builtin_bit_cast(float, u);
}

DEV void gload16(const void* g, void* l) {
  __builtin_amdgcn_global_load_lds((__attribute__((address_space(1))) void*)g,
                                   (__attribute__((address_space(3))) void*)l, 16, 0, 0);
}

// ---------------- fused prep: LN1 (blocks 0..2047) + weight cvt (blocks 2048+) --------
__launch_bounds__(256)
__global__ void prep(const float* __restrict__ x, const float* __restrict__ gam,
                     const float* __restrict__ bet, u16* __restrict__ hout,
                     const float* __restrict__ wq, const float* __restrict__ wk,
                     const float* __restrict__ wv, const float* __restrict__ wo,
                     const float* __restrict__ f1, const float* __restrict__ f2,
                     u16* __restrict__ dq, u16* __restrict__ dk, u16* __restrict__ dv,
                     u16* __restrict__ dwo, u16* __restrict__ df1, u16* __restrict__ df2) {
  int t = threadIdx.x;
  if (blockIdx.x < 2048) {
    int row = blockIdx.x;
    float4 v = ((const float4*)(x + (size_t)row * 1024))[t];
    float s = v.x + v.y + v.z + v.w;
    float s2 = v.x * v.x + v.y * v.y + v.z * v.z + v.w * v.w;
    for (int off = 1; off < 64; off <<= 1) {
      s += __shfl_xor(s, off);
      s2 += __shfl_xor(s2, off);
    }
    __shared__ float red[8];
    int wv0 = t >> 6, ln = t & 63;
    if (ln == 0) { red[wv0] = s; red[wv0 + 4] = s2; }
    __syncthreads();
    s = red[0] + red[1] + red[2] + red[3];
    s2 = red[4] + red[5] + red[6] + red[7];
    float mu = s * (1.f / 1024.f);
    float var = s2 * (1.f / 1024.f) - mu * mu;
    float rs = rsqrtf(var + 1e-5f);
    float4 gv = ((const float4*)gam)[t];
    float4 bv = ((const float4*)bet)[t];
    u16x4 o = { f2bf((v.x - mu) * rs * gv.x + bv.x), f2bf((v.y - mu) * rs * gv.y + bv.y),
                f2bf((v.z - mu) * rs * gv.z + bv.z), f2bf((v.w - mu) * rs * gv.w + bv.w) };
    ((u16x4*)(hout + (size_t)row * 1024))[t] = o;
  } else {
    int i = (blockIdx.x - 2048) * 256 + t;
    const float* src;
    u16* dst;
    int local;
    if (i < (1 << 18)) { src = wq; dst = dq; local = i; }
    else if (i < (2 << 18)) { src = wk; dst = dk; local = i - (1 << 18); }
    else if (i < (3 << 18)) { src = wv; dst = dv; local = i - (2 << 18); }
    else if (i < (4 << 18)) { src = wo; dst = dwo; local = i - (3 << 18); }
    else if (i < (4 << 18) + (1 << 20)) { src = f1; dst = df1; local = i - (4 << 18); }
    else { src = f2; dst = df2; local = i - ((4 << 18) + (1 << 20)); }
    float4 v = ((const float4*)src)[local];
    u16x4 o = { f2bf(v.x), f2bf(v.y), f2bf(v.z), f2bf(v.w) };
    ((u16x4*)dst)[local] = o;
  }
}

// ---------------- fused: x2 = x + P0 + P1; h2 = LN(x2) ----------
__launch_bounds__(256)
__global__ void ln2_add(const float* __restrict__ x, const float* __restrict__ P0,
                        const float* __restrict__ P1, const float* __restrict__ gam,
                        const float* __restrict__ bet, float* __restrict__ x2,
                        u16* __restrict__ out) {
  int row = blockIdx.x;
  int t = threadIdx.x;
  size_t base = (size_t)row * 256 + t;
  float4 xv = ((const float4*)x)[base];
  float4 p0 = ((const float4*)P0)[base];
  float4 p1 = ((const float4*)P1)[base];
  float4 v = { xv.x + p0.x + p1.x, xv.y + p0.y + p1.y,
               xv.z + p0.z + p1.z, xv.w + p0.w + p1.w };
  ((float4*)x2)[base] = v;
  float s = v.x + v.y + v.z + v.w;
  float s2 = v.x * v.x + v.y * v.y + v.z * v.z + v.w * v.w;
  for (int off = 1; off < 64; off <<= 1) {
    s += __shfl_xor(s, off);
    s2 += __shfl_xor(s2, off);
  }
  __shared__ float red[8];
  int wv = t >> 6, ln = t & 63;
  if (ln == 0) { red[wv] = s; red[wv + 4] = s2; }
  __syncthreads();
  s = red[0] + red[1] + red[2] + red[3];
  s2 = red[4] + red[5] + red[6] + red[7];
  float mu = s * (1.f / 1024.f);
  float var = s2 * (1.f / 1024.f) - mu * mu;
  float rs = rsqrtf(var + 1e-5f);
  float4 gv = ((const float4*)gam)[t];
  float4 bv = ((const float4*)bet)[t];
  u16x4 o = { f2bf((v.x - mu) * rs * gv.x + bv.x), f2bf((v.y - mu) * rs * gv.y + bv.y),
              f2bf((v.z - mu) * rs * gv.z + bv.z), f2bf((v.w - mu) * rs * gv.w + bv.w) };
  ((u16x4*)(out + (size_t)row * 1024))[t] = o;
}

// ---------------- final: out = x2 + b2 + Q0 + Q1 ----------------
__launch_bounds__(256)
__global__ void final_add(const float* __restrict__ x2, const float* __restrict__ b2,
                          const u16* __restrict__ Q0, const u16* __restrict__ Q1,
                          float* __restrict__ out) {
  int row = blockIdx.x;
  int t = threadIdx.x;
  size_t base = (size_t)row * 256 + t;
  float4 xv = ((const float4*)x2)[base];
  float4 bv = ((const float4*)b2)[t];
  u16x4 q0 = ((const u16x4*)Q0)[base];
  u16x4 q1 = ((const u16x4*)Q1)[base];
  float4 o = { xv.x + bv.x + bf2f(q0[0]) + bf2f(q1[0]),
               xv.y + bv.y + bf2f(q0[1]) + bf2f(q1[1]),
               xv.z + bv.z + bf2f(q0[2]) + bf2f(q1[2]),
               xv.w + bv.w + bf2f(q0[3]) + bf2f(q1[3]) };
  ((float4*)out)[base] = o;
}

// ---------------- V transpose ----------------
__launch_bounds__(256)
__global__ void transpose_v(const u16* __restrict__ V, u16* __restrict__ Vt) {
  const int st = blockIdx.x, h = blockIdx.y;
  __shared__ u16 tile[64][72];
  const int t = threadIdx.x;
  const int r = t >> 3, c8 = t & 7;
#pragma unroll
  for (int i = 0; i < 2; ++i) {
    int row = i * 32 + r;
    *(u16x8*)&tile[row][c8 * 8] =
        *(const u16x8*)&V[(size_t)(st * 64 + row) * 1024 + h * 64 + c8 * 8];
  }
  __syncthreads();
#pragma unroll
  for (int i = 0; i < 2; ++i) {
    int d = i * 32 + r;
    u16x8 o;
#pragma unroll
    for (int jj = 0; jj < 8; ++jj) o[jj] = tile[c8 * 8 + jj][d];
    *(u16x8*)&Vt[(size_t)(h * 64 + d) * 2048 + st * 64 + c8 * 8] = o;
  }
}

// ---------------- generic bf16 GEMM + XCD-swizzle (R12) ----------------
template <int BM, int BN, int WR, int WC, int EPI, int SPLITK, int SWZ>
__launch_bounds__(256, 2)
__global__ void gemm_bt(const u16* __restrict__ A, const u16* __restrict__ B,
                        void* __restrict__ C, const float* __restrict__ bias,
                        const float* __restrict__ resid, int M, int N, int K,
                        size_t zoff) {
  constexpr int FM = BM / WR / 16;
  constexpr int FN = BN / WC / 16;
  __shared__ u16 As[BM * 32];
  __shared__ u16 Bs[BN * 32];
  int bxi = blockIdx.x, byi = blockIdx.y, bzi = blockIdx.z;
  if constexpr (SWZ == 1) {
    int bid = bxi + 8 * (byi + (int)gridDim.y * bzi);
    int xcd = bid & 7, k = bid >> 3;
    bxi = xcd;
    byi = k % (int)gridDim.y;
    bzi = k / (int)gridDim.y;
  } else if constexpr (SWZ == 2) {
    int bid = bxi + 32 * byi;
    int xcd = bid & 7, k = bid >> 3;
    bxi = xcd * 4 + (k & 3);
    byi = k >> 2;
    bzi = 0;
  }
  const int t = threadIdx.x, lane = t & 63, w = t >> 6;
  const int wr = w / WC, wc = w % WC;
  const int g = lane >> 4, l16 = lane & 15;
  const int m0 = byi * BM, n0 = bxi * BN;
  const int ks = K / SPLITK;
  const int k0 = (SPLITK > 1) ? bzi * ks : 0;
  const size_t cbase = (SPLITK > 1) ? (size_t)bzi * zoff : 0;
  f32x4 acc[FM][FN] = {};
  const int nkt = ks >> 5;
  for (int kt = 0; kt < nkt; ++kt) {
    const u16* Ag = A + (size_t)m0 * K + k0 + kt * 32;
    const u16* Bg = B + (size_t)n0 * K + k0 + kt * 32;
#pragma unroll
    for (int i = 0; i < BM / 64; ++i) {
      int c = i * 256 + t;
      gload16(Ag + (size_t)(c >> 2) * K + (c & 3) * 8, &As[(i * 256 + w * 64) * 8]);
    }
#pragma unroll
    for (int i = 0; i < BN / 64; ++i) {
      int c = i * 256 + t;
      gload16(Bg + (size_t)(c >> 2) * K + (c & 3) * 8, &Bs[(i * 256 + w * 64) * 8]);
    }
    __syncthreads();
    bf16x8 af[FM], bfr[FN];
#pragma unroll
    for (int m = 0; m < FM; ++m)
      af[m] = *(const bf16x8*)&As[(wr * FM * 16 + m * 16 + l16) * 32 + g * 8];
#pragma unroll
    for (int n = 0; n < FN; ++n)
      bfr[n] = *(const bf16x8*)&Bs[(wc * FN * 16 + n * 16 + l16) * 32 + g * 8];
#pragma unroll
    for (int m = 0; m < FM; ++m)
#pragma unroll
      for (int n = 0; n < FN; ++n)
        acc[m][n] = __builtin_amdgcn_mfma_f32_16x16x32_bf16(af[m], bfr[n], acc[m][n], 0, 0, 0);
    __syncthreads();
  }
#pragma unroll
  for (int m = 0; m < FM; ++m)
#pragma unroll
    for (int n = 0; n < FN; ++n)
#pragma unroll
      for (int r = 0; r < 4; ++r) {
        int row = m0 + wr * FM * 16 + m * 16 + g * 4 + r;
        int col = n0 + wc * FN * 16 + n * 16 + l16;
        size_t idx = (size_t)row * N + col;
        float v = acc[m][n][r];
        if constexpr (EPI == 0) {
          ((u16*)C)[cbase + idx] = f2bf(v);
        } else if constexpr (EPI == 1) {
          v += bias[col];
          v = 0.5f * v * (1.f + erff(v * 0.70710678118f));
          ((u16*)C)[idx] = f2bf(v);
        } else if constexpr (EPI == 2) {
          ((float*)C)[idx] = v + bias[col] + resid[idx];
        } else if constexpr (EPI == 3) {
          ((float*)C)[idx] = v + resid[idx];
        } else {
          ((float*)C)[cbase + idx] = v;
        }
      }
}

// ---------------- fused QKV projection, 64x128 tiles + XCD swizzle (R12) --------------
__launch_bounds__(256, 2)
__global__ void gemm_qkv64(const u16* __restrict__ A, const u16* __restrict__ B0,
                           const u16* __restrict__ B1, const u16* __restrict__ B2,
                           u16* __restrict__ C0, u16* __restrict__ C1, u16* __restrict__ C2) {
  constexpr int FM = 4, FN = 2;
  const int K = 1024, N = 1024;
  int bid = blockIdx.x + 24 * blockIdx.y;
  int xcd = bid & 7, kk0 = bid >> 3;
  const int bxs = xcd * 3 + kk0 % 3;
  const int bys = kk0 / 3;
  const int which = bxs >> 3;
  const u16* B = which == 0 ? B0 : which == 1 ? B1 : B2;
  u16* C = which == 0 ? C0 : which == 1 ? C1 : C2;
  __shared__ u16 As[64 * 32];
  __shared__ u16 Bs[128 * 32];
  const int t = threadIdx.x, lane = t & 63, w = t >> 6;
  const int wc = w;
  const int g = lane >> 4, l16 = lane & 15;
  const int m0 = bys * 64, n0 = (bxs & 7) * 128;
  f32x4 acc[FM][FN] = {};
  for (int kt = 0; kt < 32; ++kt) {
    const u16* Ag = A + (size_t)m0 * K + kt * 32;
    const u16* Bg = B + (size_t)n0 * K + kt * 32;
    {
      int c = t;
      gload16(Ag + (size_t)(c >> 2) * K + (c & 3) * 8, &As[(w * 64) * 8]);
    }
#pragma unroll
    for (int i = 0; i < 2; ++i) {
      int c = i * 256 + t;
      gload16(Bg + (size_t)(c >> 2) * K + (c & 3) * 8, &Bs[(i * 256 + w * 64) * 8]);
    }
    __syncthreads();
    bf16x8 af[FM], bfr[FN];
#pragma unroll
    for (int m = 0; m < FM; ++m)
      af[m] = *(const bf16x8*)&As[(m * 16 + l16) * 32 + g * 8];
#pragma unroll
    for (int n = 0; n < FN; ++n)
      bfr[n] = *(const bf16x8*)&Bs[(wc * FN * 16 + n * 16 + l16) * 32 + g * 8];
#pragma unroll
    for (int m = 0; m < FM; ++m)
#pragma unroll
      for (int n = 0; n < FN; ++n)
        acc[m][n] = __builtin_amdgcn_mfma_f32_16x16x32_bf16(af[m], bfr[n], acc[m][n], 0, 0, 0);
    __syncthreads();
  }
#pragma unroll
  for (int m = 0; m < FM; ++m)
#pragma unroll
    for (int n = 0; n < FN; ++n)
#pragma unroll
      for (int r = 0; r < 4; ++r) {
        int row = m0 + m * 16 + g * 4 + r;
        int col = n0 + wc * FN * 16 + n * 16 + l16;
        C[(size_t)row * N + col] = f2bf(acc[m][n][r]);
      }
}

// ---------------- flash attention: 512 blocks x 4 waves (2 blocks/CU, 4 waves/SIMD) ---
// Block (p,h,z): pooled half [17z, myEnd) of pair chunks A=p (TA=p+1 tiles),
// B=31-p. Chunk A wholly in z=0 -> stored direct. Chunk-B partials (fp32 O +
// m/l) to scratch; merge_b combines. Tile body/staging/swizzles = R12-proven.
__launch_bounds__(256, 4)
__global__ void attn_fwd(const u16* __restrict__ Q, const u16* __restrict__ Kb,
                         const u16* __restrict__ Vt, const float* __restrict__ slopes,
                         u16* __restrict__ O, float* __restrict__ BoG,
                         float* __restrict__ BmlG) {
  const int p = blockIdx.x;
  const int h = blockIdx.y;
  const int z = blockIdx.z;
  const int t = threadIdx.x, lane = t & 63, w = t >> 6;
  const int g = lane >> 4, l16 = lane & 15;
  const float slope = slopes[h];
  const int TA = p + 1;
  const int qbB = 31 - p;

  __shared__ u16 Ks[2][4096];
  __shared__ u16 Vs[2][4096];
  __shared__ u16 Ps[4][16][72];

  const int r0 = w * 8 + (lane >> 3), r1 = 32 + r0;
  const int c8 = lane & 7;
  const int c0s = c8 ^ (r0 & 7), c1s = c8 ^ (r1 & 7);
  const int sw = l16 & 7;

  auto stage = [&](int buf, int kv0) {
    gload16(Kb + (size_t)(kv0 + r0) * 1024 + h * 64 + c0s * 8, &Ks[buf][(w * 64) * 8]);
    gload16(Kb + (size_t)(kv0 + r1) * 1024 + h * 64 + c1s * 8, &Ks[buf][(256 + w * 64) * 8]);
    gload16(Vt + (size_t)(h * 64 + r0) * 2048 + kv0 + c0s * 8, &Vs[buf][(w * 64) * 8]);
    gload16(Vt + (size_t)(h * 64 + r1) * 2048 + kv0 + c1s * 8, &Vs[buf][(256 + w * 64) * 8]);
  };
  auto kvOf = [&](int idx) { return idx < TA ? idx * 64 : (idx - TA) * 64; };

  const int myStart = z * 17;
  const int myEnd = z ? 33 : 17;

  int qb = (z == 0) ? p : qbB;  // z=1 starts in chunk B (17 >= TA always)
  int q0 = qb * 64 + w * 16;
  bf16x8 qf[2];
#pragma unroll
  for (int kk = 0; kk < 2; ++kk)
    qf[kk] = *(const bf16x8*)&Q[(size_t)(q0 + l16) * 1024 + h * 64 + kk * 32 + g * 8];
  f32x4 o_acc[4] = {};
  float m_run[4], l_run[4];
#pragma unroll
  for (int r = 0; r < 4; ++r) { m_run[r] = -1e30f; l_run[r] = 0.f; }

  stage(0, kvOf(myStart));
  __syncthreads();

  int cur = 0;
  for (int it = 0; it < 17; ++it) {
    const int idx = myStart + it;
    const bool active = idx < myEnd;
    if (z == 0 && idx == TA) {
      // finalize chunk A (always completes inside z=0: TA <= 16)
#pragma unroll
      for (int d = 0; d < 4; ++d)
#pragma unroll
        for (int r = 0; r < 4; ++r) {
          int row = q0 + g * 4 + r;
          O[(size_t)row * 1024 + h * 64 + d * 16 + l16] = f2bf(o_acc[d][r] / l_run[r]);
        }
      qb = qbB;
      q0 = qb * 64 + w * 16;
#pragma unroll
      for (int kk = 0; kk < 2; ++kk)
        qf[kk] = *(const bf16x8*)&Q[(size_t)(q0 + l16) * 1024 + h * 64 + kk * 32 + g * 8];
#pragma unroll
      for (int d = 0; d < 4; ++d) o_acc[d] = f32x4{};
#pragma unroll
      for (int r = 0; r < 4; ++r) { m_run[r] = -1e30f; l_run[r] = 0.f; }
    }
    if (idx + 1 < myEnd) stage(cur ^ 1, kvOf(idx + 1));
    if (active) {
      const int kv0 = kvOf(idx);
      const bool lastT = (idx == TA - 1) || (idx == 32);
      f32x4 s[4];
      __builtin_amdgcn_s_setprio(1);
#pragma unroll
      for (int n = 0; n < 4; ++n) {
        bf16x8 kf0 = *(const bf16x8*)&Ks[cur][(n * 16 + l16) * 64 + ((g ^ sw) * 8)];
        bf16x8 kf1 = *(const bf16x8*)&Ks[cur][(n * 16 + l16) * 64 + (((4 + g) ^ sw) * 8)];
        f32x4 z4 = {};
        s[n] = __builtin_amdgcn_mfma_f32_16x16x32_bf16(qf[0], kf0, z4, 0, 0, 0);
        s[n] = __builtin_amdgcn_mfma_f32_16x16x32_bf16(qf[1], kf1, s[n], 0, 0, 0);
      }
      __builtin_amdgcn_s_setprio(0);
      float sv[4][4];
      float mtile[4] = { -1e30f, -1e30f, -1e30f, -1e30f };
      const float aB = -slope * (float)(kv0 + l16);
#pragma unroll
      for (int n = 0; n < 4; ++n) {
        const float aN = aB - slope * (float)(n * 16);
        const int kj = kv0 + n * 16 + l16;
#pragma unroll
        for (int r = 0; r < 4; ++r) {
          float val = fmaf(s[n][r], 0.125f, aN);
          if (lastT) {
            int qi = q0 + g * 4 + r;
            val = (kj <= qi) ? val : -1e30f;
          }
          sv[n][r] = val;
          mtile[r] = fmaxf(mtile[r], val);
        }
      }
#pragma unroll
      for (int r = 0; r < 4; ++r) {
        float v = mtile[r];
        v = fmaxf(v, __shfl_xor(v, 1));
        v = fmaxf(v, __shfl_xor(v, 2));
        v = fmaxf(v, __shfl_xor(v, 4));
        v = fmaxf(v, __shfl_xor(v, 8));
        mtile[r] = v;
      }
      float sc[4];
#pragma unroll
      for (int r = 0; r < 4; ++r) {
        float mnew = fmaxf(m_run[r], mtile[r]);
        sc[r] = __expf(m_run[r] - mnew);
        m_run[r] = mnew;
      }
      float tsum[4] = { 0.f, 0.f, 0.f, 0.f };
#pragma unroll
      for (int n = 0; n < 4; ++n)
#pragma unroll
        for (int r = 0; r < 4; ++r) {
          float pp = __expf(sv[n][r] - m_run[r]);
          sv[n][r] = pp;
          tsum[r] += pp;
        }
#pragma unroll
      for (int r = 0; r < 4; ++r) {
        float v = tsum[r];
        v += __shfl_xor(v, 1);
        v += __shfl_xor(v, 2);
        v += __shfl_xor(v, 4);
        v += __shfl_xor(v, 8);
        l_run[r] = l_run[r] * sc[r] + v;
      }
#pragma unroll
      for (int d = 0; d < 4; ++d)
#pragma unroll
        for (int r = 0; r < 4; ++r) o_acc[d][r] *= sc[r];
#pragma unroll
      for (int n = 0; n < 4; ++n)
#pragma unroll
        for (int r = 0; r < 4; ++r)
          Ps[w][g * 4 + r][n * 16 + l16] = f2bf(sv[n][r]);
      bf16x8 pf[2];
#pragma unroll
      for (int kk = 0; kk < 2; ++kk)
        pf[kk] = *(const bf16x8*)&Ps[w][l16][kk * 32 + g * 8];
      __builtin_amdgcn_s_setprio(1);
#pragma unroll
      for (int d = 0; d < 4; ++d) {
#pragma unroll
        for (int kk = 0; kk < 2; ++kk) {
          bf16x8 vv = *(const bf16x8*)&Vs[cur][(d * 16 + l16) * 64 + (((kk * 4 + g) ^ sw) * 8)];
          o_acc[d] = __builtin_amdgcn_mfma_f32_16x16x32_bf16(pf[kk], vv, o_acc[d], 0, 0, 0);
        }
      }
      __builtin_amdgcn_s_setprio(0);
    }
    __syncthreads();
    cur ^= 1;
  }
  // write chunk-B partial: Bo[(p,h,z)][row][col], Bml[(p,h,z)][{m,l}][row]
  const size_t slot = ((size_t)p * 16 + h) * 2 + z;
  float* Bo = BoG + slot * 4096;
  float* Bml = BmlG + slot * 128;
#pragma unroll
  for (int d = 0; d < 4; ++d)
#pragma unroll
    for (int r = 0; r < 4; ++r)
      Bo[(w * 16 + g * 4 + r) * 64 + d * 16 + l16] = o_acc[d][r];
  if (l16 == 0) {
#pragma unroll
    for (int r = 0; r < 4; ++r) {
      Bml[w * 16 + g * 4 + r] = m_run[r];
      Bml[64 + w * 16 + g * 4 + r] = l_run[r];
    }
  }
}

// ---------------- merge chunk-B partials -> attnO ----------------
__launch_bounds__(256)
__global__ void merge_b(const float* __restrict__ BoG, const float* __restrict__ BmlG,
                        u16* __restrict__ O) {
  const int p = blockIdx.x, h = blockIdx.y;
  const int qbB = 31 - p;
  const size_t s0 = (((size_t)p * 16 + h) * 2 + 0);
  const size_t s1 = s0 + 1;
  const float* Bo0 = BoG + s0 * 4096;
  const float* Bo1 = BoG + s1 * 4096;
  const float* Bml0 = BmlG + s0 * 128;
  const float* Bml1 = BmlG + s1 * 128;
  const int t = threadIdx.x;
#pragma unroll
  for (int i = 0; i < 4; ++i) {
    int idx = t + i * 256;          // 1024 float4 slots = 64 rows x 16
    int row = idx >> 4, c4 = idx & 15;
    float m0 = Bml0[row], m1 = Bml1[row];
    float mm = fmaxf(m0, m1);
    float w0 = __expf(m0 - mm), w1 = __expf(m1 - mm);
    float inv = 1.f / (Bml0[64 + row] * w0 + Bml1[64 + row] * w1);
    float4 a = ((const float4*)Bo0)[(size_t)row * 16 + c4];
    float4 b = ((const float4*)Bo1)[(size_t)row * 16 + c4];
    u16x4 o = { f2bf((a.x * w0 + b.x * w1) * inv), f2bf((a.y * w0 + b.y * w1) * inv),
                f2bf((a.z * w0 + b.z * w1) * inv), f2bf((a.w * w0 + b.w * w1) * inv) };
    *(u16x4*)&O[(size_t)(qbB * 64 + row) * 1024 + h * 64 + c4 * 4] = o;
  }
}

// ---------------- launcher ----------------
extern "C" void kernel_launch(void* const* d_in, const int* in_sizes, int n_in,
                              void* d_out, int out_size, void* d_ws, size_t ws_size,
                              hipStream_t stream) {
  const float* x = (const float*)d_in[0];
  const float* slopes = (const float*)d_in[1];
  const float* wq = (const float*)d_in[2];
  const float* wk = (const float*)d_in[3];
  const float* wv = (const float*)d_in[4];
  const float* wo = (const float*)d_in[5];
  const float* ff1w = (const float*)d_in[6];
  const float* ff1b = (const float*)d_in[7];
  const float* ff2w = (const float*)d_in[8];
  const float* ff2b = (const float*)d_in[9];
  const float* ln1g = (const float*)d_in[10];
  const float* ln1b = (const float*)d_in[11];
  const float* ln2g = (const float*)d_in[12];
  const float* ln2b = (const float*)d_in[13];
  float* out = (float*)d_out;

  if (ws_size < (size_t)(56u << 20)) return;  // need 56MB scratch

  char* ws = (char*)d_ws;
  u16* hbuf = (u16*)(ws + 0);              // 4MB: h -> attnO -> ff2 partial Q0
  u16* Qb = (u16*)(ws + (4u << 20));       // 4MB
  u16* Kbf = (u16*)(ws + (8u << 20));      // 4MB
  u16* Vbf = (u16*)(ws + (12u << 20));     // 4MB
  u16* Vtb = (u16*)(ws + (16u << 20));     // 4MB
  float* P0 = (float*)(ws + (4u << 20));   // 8MB wo partial z=0 (post-attn)
  float* P1 = (float*)(ws + (12u << 20));  // 8MB wo partial z=1
  u16* ffact = Qb;                         // 16MB span 4-20MB
  float* x2 = (float*)(ws + (20u << 20));  // 8MB (post-merge); during attn = Bo scratch
  float* BoG = (float*)(ws + (20u << 20)); // 8MB: 512 slots x 4096 fp32
  u16* h2 = (u16*)(ws + (28u << 20));      // 4MB (post-merge); during attn = Bml
  float* BmlG = (float*)(ws + (28u << 20)); // 256KB: 512 slots x 128 fp32
  u16* Q1p = h2;
  u16* wqb = (u16*)(ws + (32u << 20));
  u16* wkb = (u16*)(ws + (34u << 20));
  u16* wvb = (u16*)(ws + (36u << 20));
  u16* wob = (u16*)(ws + (38u << 20));
  u16* ff1wb = (u16*)(ws + (40u << 20));
  u16* ff2wb = (u16*)(ws + (48u << 20));
  u16* attnO = hbuf;
  u16* Q0p = hbuf;
  const size_t q1off = (size_t)(28u << 20) / 2;

  // fused LN1 + weight convert (independent work, one launch)
  prep<<<2048 + 12288, 256, 0, stream>>>(x, ln1g, ln1b, hbuf, wq, wk, wv, wo, ff1w, ff2w,
                                         wqb, wkb, wvb, wob, ff1wb, ff2wb);
  gemm_qkv64<<<dim3(24, 32), 256, 0, stream>>>(hbuf, wqb, wkb, wvb, Qb, Kbf, Vbf);
  transpose_v<<<dim3(32, 16), 256, 0, stream>>>(Vbf, Vtb);
  attn_fwd<<<dim3(16, 16, 2), 256, 0, stream>>>(Qb, Kbf, Vtb, slopes, attnO, BoG, BmlG);
  merge_b<<<dim3(16, 16), 256, 0, stream>>>(BoG, BmlG, attnO);
  gemm_bt<64, 128, 1, 4, 4, 2, 1><<<dim3(8, 32, 2), 256, 0, stream>>>(
      attnO, wob, P0, nullptr, nullptr, 2048, 1024, 1024, (size_t)2048 * 1024);
  ln2_add<<<2048, 256, 0, stream>>>(x, P0, P1, ln2g, ln2b, x2, h2);
  gemm_bt<128, 128, 2, 2, 1, 1, 2><<<dim3(32, 16), 256, 0, stream>>>(
      h2, ff1wb, ffact, ff1b, nullptr, 2048, 4096, 1024, 0);
  gemm_bt<64, 128, 1, 4, 0, 2, 1><<<dim3(8, 32, 2), 256, 0, stream>>>(
      ffact, ff2wb, Q0p, nullptr, nullptr, 2048, 1024, 4096, q1off);
  final_add<<<2048, 256, 0, stream>>>(x2, ff2b, Q0p, Q1p, out);
}

// Round 14
// 174.128 us; speedup vs baseline: 1.6860x; 1.0907x over previous
//
#include <hip/hip_runtime.h>
#include <math.h>

typedef unsigned short u16;
typedef __bf16 bf16x8 __attribute__((ext_vector_type(8)));
typedef float f32x4 __attribute__((ext_vector_type(4)));
typedef u16 u16x4 __attribute__((ext_vector_type(4)));
typedef u16 u16x8 __attribute__((ext_vector_type(8)));

#define DEV __device__ __forceinline__

DEV u16 f2bf(float f) {
  unsigned u = __builtin_bit_cast(unsigned, f);
  u += 0x7FFFu + ((u >> 16) & 1u);
  return (u16)(u >> 16);
}
DEV float bf2f(u16 b) {
  unsigned u = ((unsigned)b) << 16;
  return __builtin_bit_cast(float, u);
}

DEV void gload16(const void* g, void* l) {
  __builtin_amdgcn_global_load_lds((__attribute__((address_space(1))) void*)g,
                                   (__attribute__((address_space(3))) void*)l, 16, 0, 0);
}

// ---------------- fused prep: LN1 (blocks 0..2047) + weight cvt (blocks 2048+) --------
__launch_bounds__(256)
__global__ void prep(const float* __restrict__ x, const float* __restrict__ gam,
                     const float* __restrict__ bet, u16* __restrict__ hout,
                     const float* __restrict__ wq, const float* __restrict__ wk,
                     const float* __restrict__ wv, const float* __restrict__ wo,
                     const float* __restrict__ f1, const float* __restrict__ f2,
                     u16* __restrict__ dq, u16* __restrict__ dk, u16* __restrict__ dv,
                     u16* __restrict__ dwo, u16* __restrict__ df1, u16* __restrict__ df2) {
  int t = threadIdx.x;
  if (blockIdx.x < 2048) {
    int row = blockIdx.x;
    float4 v = ((const float4*)(x + (size_t)row * 1024))[t];
    float s = v.x + v.y + v.z + v.w;
    float s2 = v.x * v.x + v.y * v.y + v.z * v.z + v.w * v.w;
    for (int off = 1; off < 64; off <<= 1) {
      s += __shfl_xor(s, off);
      s2 += __shfl_xor(s2, off);
    }
    __shared__ float red[8];
    int wv0 = t >> 6, ln = t & 63;
    if (ln == 0) { red[wv0] = s; red[wv0 + 4] = s2; }
    __syncthreads();
    s = red[0] + red[1] + red[2] + red[3];
    s2 = red[4] + red[5] + red[6] + red[7];
    float mu = s * (1.f / 1024.f);
    float var = s2 * (1.f / 1024.f) - mu * mu;
    float rs = rsqrtf(var + 1e-5f);
    float4 gv = ((const float4*)gam)[t];
    float4 bv = ((const float4*)bet)[t];
    u16x4 o = { f2bf((v.x - mu) * rs * gv.x + bv.x), f2bf((v.y - mu) * rs * gv.y + bv.y),
                f2bf((v.z - mu) * rs * gv.z + bv.z), f2bf((v.w - mu) * rs * gv.w + bv.w) };
    ((u16x4*)(hout + (size_t)row * 1024))[t] = o;
  } else {
    int i = (blockIdx.x - 2048) * 256 + t;
    const float* src;
    u16* dst;
    int local;
    if (i < (1 << 18)) { src = wq; dst = dq; local = i; }
    else if (i < (2 << 18)) { src = wk; dst = dk; local = i - (1 << 18); }
    else if (i < (3 << 18)) { src = wv; dst = dv; local = i - (2 << 18); }
    else if (i < (4 << 18)) { src = wo; dst = dwo; local = i - (3 << 18); }
    else if (i < (4 << 18) + (1 << 20)) { src = f1; dst = df1; local = i - (4 << 18); }
    else { src = f2; dst = df2; local = i - ((4 << 18) + (1 << 20)); }
    float4 v = ((const float4*)src)[local];
    u16x4 o = { f2bf(v.x), f2bf(v.y), f2bf(v.z), f2bf(v.w) };
    ((u16x4*)dst)[local] = o;
  }
}

// ---------------- fused: x2 = x + P0 + P1; h2 = LN(x2) ----------
__launch_bounds__(256)
__global__ void ln2_add(const float* __restrict__ x, const float* __restrict__ P0,
                        const float* __restrict__ P1, const float* __restrict__ gam,
                        const float* __restrict__ bet, float* __restrict__ x2,
                        u16* __restrict__ out) {
  int row = blockIdx.x;
  int t = threadIdx.x;
  size_t base = (size_t)row * 256 + t;
  float4 xv = ((const float4*)x)[base];
  float4 p0 = ((const float4*)P0)[base];
  float4 p1 = ((const float4*)P1)[base];
  float4 v = { xv.x + p0.x + p1.x, xv.y + p0.y + p1.y,
               xv.z + p0.z + p1.z, xv.w + p0.w + p1.w };
  ((float4*)x2)[base] = v;
  float s = v.x + v.y + v.z + v.w;
  float s2 = v.x * v.x + v.y * v.y + v.z * v.z + v.w * v.w;
  for (int off = 1; off < 64; off <<= 1) {
    s += __shfl_xor(s, off);
    s2 += __shfl_xor(s2, off);
  }
  __shared__ float red[8];
  int wv = t >> 6, ln = t & 63;
  if (ln == 0) { red[wv] = s; red[wv + 4] = s2; }
  __syncthreads();
  s = red[0] + red[1] + red[2] + red[3];
  s2 = red[4] + red[5] + red[6] + red[7];
  float mu = s * (1.f / 1024.f);
  float var = s2 * (1.f / 1024.f) - mu * mu;
  float rs = rsqrtf(var + 1e-5f);
  float4 gv = ((const float4*)gam)[t];
  float4 bv = ((const float4*)bet)[t];
  u16x4 o = { f2bf((v.x - mu) * rs * gv.x + bv.x), f2bf((v.y - mu) * rs * gv.y + bv.y),
              f2bf((v.z - mu) * rs * gv.z + bv.z), f2bf((v.w - mu) * rs * gv.w + bv.w) };
  ((u16x4*)(out + (size_t)row * 1024))[t] = o;
}

// ---------------- final: out = x2 + b2 + sum of 4 ff2 partials ----------------
__launch_bounds__(256)
__global__ void final_add(const float* __restrict__ x2, const float* __restrict__ b2,
                          const u16* __restrict__ Qp, size_t qoff,
                          float* __restrict__ out) {
  int row = blockIdx.x;
  int t = threadIdx.x;
  size_t base = (size_t)row * 256 + t;
  float4 xv = ((const float4*)x2)[base];
  float4 bv = ((const float4*)b2)[t];
  float4 o = { xv.x + bv.x, xv.y + bv.y, xv.z + bv.z, xv.w + bv.w };
#pragma unroll
  for (int i = 0; i < 4; ++i) {
    u16x4 q = ((const u16x4*)(Qp + i * qoff))[base];
    o.x += bf2f(q[0]);
    o.y += bf2f(q[1]);
    o.z += bf2f(q[2]);
    o.w += bf2f(q[3]);
  }
  ((float4*)out)[base] = o;
}

// ---------------- V transpose ----------------
__launch_bounds__(256)
__global__ void transpose_v(const u16* __restrict__ V, u16* __restrict__ Vt) {
  const int st = blockIdx.x, h = blockIdx.y;
  __shared__ u16 tile[64][72];
  const int t = threadIdx.x;
  const int r = t >> 3, c8 = t & 7;
#pragma unroll
  for (int i = 0; i < 2; ++i) {
    int row = i * 32 + r;
    *(u16x8*)&tile[row][c8 * 8] =
        *(const u16x8*)&V[(size_t)(st * 64 + row) * 1024 + h * 64 + c8 * 8];
  }
  __syncthreads();
#pragma unroll
  for (int i = 0; i < 2; ++i) {
    int d = i * 32 + r;
    u16x8 o;
#pragma unroll
    for (int jj = 0; jj < 8; ++jj) o[jj] = tile[c8 * 8 + jj][d];
    *(u16x8*)&Vt[(size_t)(h * 64 + d) * 2048 + st * 64 + c8 * 8] = o;
  }
}

// ---------------- generic bf16 GEMM + XCD-swizzle (R12) ----------------
template <int BM, int BN, int WR, int WC, int EPI, int SPLITK, int SWZ>
__launch_bounds__(256, 2)
__global__ void gemm_bt(const u16* __restrict__ A, const u16* __restrict__ B,
                        void* __restrict__ C, const float* __restrict__ bias,
                        const float* __restrict__ resid, int M, int N, int K,
                        size_t zoff) {
  constexpr int FM = BM / WR / 16;
  constexpr int FN = BN / WC / 16;
  __shared__ u16 As[BM * 32];
  __shared__ u16 Bs[BN * 32];
  int bxi = blockIdx.x, byi = blockIdx.y, bzi = blockIdx.z;
  if constexpr (SWZ == 1) {
    int bid = bxi + 8 * (byi + (int)gridDim.y * bzi);
    int xcd = bid & 7, k = bid >> 3;
    bxi = xcd;
    byi = k % (int)gridDim.y;
    bzi = k / (int)gridDim.y;
  } else if constexpr (SWZ == 2) {
    int bid = bxi + 32 * blockIdx.y;
    int xcd = bid & 7, k = bid >> 3;
    bxi = xcd * 4 + (k & 3);
    byi = k >> 2;
    bzi = 0;
  }
  const int t = threadIdx.x, lane = t & 63, w = t >> 6;
  const int wr = w / WC, wc = w % WC;
  const int g = lane >> 4, l16 = lane & 15;
  const int m0 = byi * BM, n0 = bxi * BN;
  const int ks = K / SPLITK;
  const int k0 = (SPLITK > 1) ? bzi * ks : 0;
  const size_t cbase = (SPLITK > 1) ? (size_t)bzi * zoff : 0;
  f32x4 acc[FM][FN] = {};
  const int nkt = ks >> 5;
  for (int kt = 0; kt < nkt; ++kt) {
    const u16* Ag = A + (size_t)m0 * K + k0 + kt * 32;
    const u16* Bg = B + (size_t)n0 * K + k0 + kt * 32;
#pragma unroll
    for (int i = 0; i < BM / 64; ++i) {
      int c = i * 256 + t;
      gload16(Ag + (size_t)(c >> 2) * K + (c & 3) * 8, &As[(i * 256 + w * 64) * 8]);
    }
#pragma unroll
    for (int i = 0; i < BN / 64; ++i) {
      int c = i * 256 + t;
      gload16(Bg + (size_t)(c >> 2) * K + (c & 3) * 8, &Bs[(i * 256 + w * 64) * 8]);
    }
    __syncthreads();
    bf16x8 af[FM], bfr[FN];
#pragma unroll
    for (int m = 0; m < FM; ++m)
      af[m] = *(const bf16x8*)&As[(wr * FM * 16 + m * 16 + l16) * 32 + g * 8];
#pragma unroll
    for (int n = 0; n < FN; ++n)
      bfr[n] = *(const bf16x8*)&Bs[(wc * FN * 16 + n * 16 + l16) * 32 + g * 8];
#pragma unroll
    for (int m = 0; m < FM; ++m)
#pragma unroll
      for (int n = 0; n < FN; ++n)
        acc[m][n] = __builtin_amdgcn_mfma_f32_16x16x32_bf16(af[m], bfr[n], acc[m][n], 0, 0, 0);
    __syncthreads();
  }
#pragma unroll
  for (int m = 0; m < FM; ++m)
#pragma unroll
    for (int n = 0; n < FN; ++n)
#pragma unroll
      for (int r = 0; r < 4; ++r) {
        int row = m0 + wr * FM * 16 + m * 16 + g * 4 + r;
        int col = n0 + wc * FN * 16 + n * 16 + l16;
        size_t idx = (size_t)row * N + col;
        float v = acc[m][n][r];
        if constexpr (EPI == 0) {
          ((u16*)C)[cbase + idx] = f2bf(v);
        } else if constexpr (EPI == 1) {
          v += bias[col];
          v = 0.5f * v * (1.f + erff(v * 0.70710678118f));
          ((u16*)C)[idx] = f2bf(v);
        } else if constexpr (EPI == 2) {
          ((float*)C)[idx] = v + bias[col] + resid[idx];
        } else if constexpr (EPI == 3) {
          ((float*)C)[idx] = v + resid[idx];
        } else {
          ((float*)C)[cbase + idx] = v;
        }
      }
}

// ---------------- fused QKV projection, 64x128 tiles + XCD swizzle (R12) --------------
__launch_bounds__(256, 2)
__global__ void gemm_qkv64(const u16* __restrict__ A, const u16* __restrict__ B0,
                           const u16* __restrict__ B1, const u16* __restrict__ B2,
                           u16* __restrict__ C0, u16* __restrict__ C1, u16* __restrict__ C2) {
  constexpr int FM = 4, FN = 2;
  const int K = 1024, N = 1024;
  int bid = blockIdx.x + 24 * blockIdx.y;
  int xcd = bid & 7, kk0 = bid >> 3;
  const int bxs = xcd * 3 + kk0 % 3;
  const int bys = kk0 / 3;
  const int which = bxs >> 3;
  const u16* B = which == 0 ? B0 : which == 1 ? B1 : B2;
  u16* C = which == 0 ? C0 : which == 1 ? C1 : C2;
  __shared__ u16 As[64 * 32];
  __shared__ u16 Bs[128 * 32];
  const int t = threadIdx.x, lane = t & 63, w = t >> 6;
  const int wc = w;
  const int g = lane >> 4, l16 = lane & 15;
  const int m0 = bys * 64, n0 = (bxs & 7) * 128;
  f32x4 acc[FM][FN] = {};
  for (int kt = 0; kt < 32; ++kt) {
    const u16* Ag = A + (size_t)m0 * K + kt * 32;
    const u16* Bg = B + (size_t)n0 * K + kt * 32;
    {
      int c = t;
      gload16(Ag + (size_t)(c >> 2) * K + (c & 3) * 8, &As[(w * 64) * 8]);
    }
#pragma unroll
    for (int i = 0; i < 2; ++i) {
      int c = i * 256 + t;
      gload16(Bg + (size_t)(c >> 2) * K + (c & 3) * 8, &Bs[(i * 256 + w * 64) * 8]);
    }
    __syncthreads();
    bf16x8 af[FM], bfr[FN];
#pragma unroll
    for (int m = 0; m < FM; ++m)
      af[m] = *(const bf16x8*)&As[(m * 16 + l16) * 32 + g * 8];
#pragma unroll
    for (int n = 0; n < FN; ++n)
      bfr[n] = *(const bf16x8*)&Bs[(wc * FN * 16 + n * 16 + l16) * 32 + g * 8];
#pragma unroll
    for (int m = 0; m < FM; ++m)
#pragma unroll
      for (int n = 0; n < FN; ++n)
        acc[m][n] = __builtin_amdgcn_mfma_f32_16x16x32_bf16(af[m], bfr[n], acc[m][n], 0, 0, 0);
    __syncthreads();
  }
#pragma unroll
  for (int m = 0; m < FM; ++m)
#pragma unroll
    for (int n = 0; n < FN; ++n)
#pragma unroll
      for (int r = 0; r < 4; ++r) {
        int row = m0 + m * 16 + g * 4 + r;
        int col = n0 + wc * FN * 16 + n * 16 + l16;
        C[(size_t)row * N + col] = f2bf(acc[m][n][r]);
      }
}

// ---------------- flash attention, chain-minimal softmax ----------------
// Static max (m=0): R12's ALiBi fold bounds scores <= s*0.125 (~5) for every
// row, so exp() never overflows; softmax shift-invariance makes this exact.
// Row-sum l computed by MFMA against a ones-fragment (same bf16 P as O).
// NO cross-lane ops in the j-loop. 512 blocks x 4 waves (R13 z-split).
__launch_bounds__(256, 4)
__global__ void attn_fwd(const u16* __restrict__ Q, const u16* __restrict__ Kb,
                         const u16* __restrict__ Vt, const float* __restrict__ slopes,
                         u16* __restrict__ O, float* __restrict__ BoG,
                         float* __restrict__ BlG) {
  const int p = blockIdx.x;
  const int h = blockIdx.y;
  const int z = blockIdx.z;
  const int t = threadIdx.x, lane = t & 63, w = t >> 6;
  const int g = lane >> 4, l16 = lane & 15;
  const float slope = slopes[h];
  const int TA = p + 1;
  const int qbB = 31 - p;

  __shared__ u16 Ks[2][4096];
  __shared__ u16 Vs[2][4096];
  __shared__ u16 Ps[4][16][72];

  const int r0 = w * 8 + (lane >> 3), r1 = 32 + r0;
  const int c8 = lane & 7;
  const int c0s = c8 ^ (r0 & 7), c1s = c8 ^ (r1 & 7);
  const int sw = l16 & 7;
  const u16x8 ones_u = { 0x3F80, 0x3F80, 0x3F80, 0x3F80, 0x3F80, 0x3F80, 0x3F80, 0x3F80 };
  const bf16x8 ones = __builtin_bit_cast(bf16x8, ones_u);

  auto stage = [&](int buf, int kv0) {
    gload16(Kb + (size_t)(kv0 + r0) * 1024 + h * 64 + c0s * 8, &Ks[buf][(w * 64) * 8]);
    gload16(Kb + (size_t)(kv0 + r1) * 1024 + h * 64 + c1s * 8, &Ks[buf][(256 + w * 64) * 8]);
    gload16(Vt + (size_t)(h * 64 + r0) * 2048 + kv0 + c0s * 8, &Vs[buf][(w * 64) * 8]);
    gload16(Vt + (size_t)(h * 64 + r1) * 2048 + kv0 + c1s * 8, &Vs[buf][(256 + w * 64) * 8]);
  };
  auto kvOf = [&](int idx) { return idx < TA ? idx * 64 : (idx - TA) * 64; };

  const int myStart = z * 17;
  const int myEnd = z ? 33 : 17;

  int qb = (z == 0) ? p : qbB;
  int q0 = qb * 64 + w * 16;
  bf16x8 qf[2];
#pragma unroll
  for (int kk = 0; kk < 2; ++kk)
    qf[kk] = *(const bf16x8*)&Q[(size_t)(q0 + l16) * 1024 + h * 64 + kk * 32 + g * 8];
  f32x4 o_acc[4] = {};
  f32x4 lsum = {};

  stage(0, kvOf(myStart));
  __syncthreads();

  int cur = 0;
  for (int it = 0; it < 17; ++it) {
    const int idx = myStart + it;
    const bool active = idx < myEnd;
    if (z == 0 && idx == TA) {
      // finalize chunk A (always completes inside z=0: TA <= 16)
#pragma unroll
      for (int d = 0; d < 4; ++d)
#pragma unroll
        for (int r = 0; r < 4; ++r) {
          int row = q0 + g * 4 + r;
          O[(size_t)row * 1024 + h * 64 + d * 16 + l16] = f2bf(o_acc[d][r] / lsum[r]);
        }
      qb = qbB;
      q0 = qb * 64 + w * 16;
#pragma unroll
      for (int kk = 0; kk < 2; ++kk)
        qf[kk] = *(const bf16x8*)&Q[(size_t)(q0 + l16) * 1024 + h * 64 + kk * 32 + g * 8];
#pragma unroll
      for (int d = 0; d < 4; ++d) o_acc[d] = f32x4{};
      lsum = f32x4{};
    }
    if (idx + 1 < myEnd) stage(cur ^ 1, kvOf(idx + 1));
    if (active) {
      const int kv0 = kvOf(idx);
      const bool lastT = (idx == TA - 1) || (idx == 32);
      f32x4 s[4];
      __builtin_amdgcn_s_setprio(1);
#pragma unroll
      for (int n = 0; n < 4; ++n) {
        bf16x8 kf0 = *(const bf16x8*)&Ks[cur][(n * 16 + l16) * 64 + ((g ^ sw) * 8)];
        bf16x8 kf1 = *(const bf16x8*)&Ks[cur][(n * 16 + l16) * 64 + (((4 + g) ^ sw) * 8)];
        f32x4 z4 = {};
        s[n] = __builtin_amdgcn_mfma_f32_16x16x32_bf16(qf[0], kf0, z4, 0, 0, 0);
        s[n] = __builtin_amdgcn_mfma_f32_16x16x32_bf16(qf[1], kf1, s[n], 0, 0, 0);
      }
      __builtin_amdgcn_s_setprio(0);
      // p = exp(s*0.125 - slope*kj)  (static max; mask only on diagonal tiles)
      const float aB = -slope * (float)(kv0 + l16);
#pragma unroll
      for (int n = 0; n < 4; ++n) {
        const float aN = aB - slope * (float)(n * 16);
        const int kj = kv0 + n * 16 + l16;
        u16x4 pr;
#pragma unroll
        for (int r = 0; r < 4; ++r) {
          float val = fmaf(s[n][r], 0.125f, aN);
          if (lastT) {
            int qi = q0 + g * 4 + r;
            val = (kj <= qi) ? val : -1e30f;
          }
          pr[r] = f2bf(__expf(val));
        }
#pragma unroll
        for (int r = 0; r < 4; ++r) Ps[w][g * 4 + r][n * 16 + l16] = pr[r];
      }
      bf16x8 pf[2];
#pragma unroll
      for (int kk = 0; kk < 2; ++kk)
        pf[kk] = *(const bf16x8*)&Ps[w][l16][kk * 32 + g * 8];
      __builtin_amdgcn_s_setprio(1);
#pragma unroll
      for (int kk = 0; kk < 2; ++kk)
        lsum = __builtin_amdgcn_mfma_f32_16x16x32_bf16(pf[kk], ones, lsum, 0, 0, 0);
#pragma unroll
      for (int d = 0; d < 4; ++d) {
#pragma unroll
        for (int kk = 0; kk < 2; ++kk) {
          bf16x8 vv = *(const bf16x8*)&Vs[cur][(d * 16 + l16) * 64 + (((kk * 4 + g) ^ sw) * 8)];
          o_acc[d] = __builtin_amdgcn_mfma_f32_16x16x32_bf16(pf[kk], vv, o_acc[d], 0, 0, 0);
        }
      }
      __builtin_amdgcn_s_setprio(0);
    }
    __syncthreads();
    cur ^= 1;
  }
  // write chunk-B partial: Bo[(p,h,z)][row][col], Bl[(p,h,z)][row]
  const size_t slot = ((size_t)p * 16 + h) * 2 + z;
  float* Bo = BoG + slot * 4096;
  float* Bl = BlG + slot * 64;
#pragma unroll
  for (int d = 0; d < 4; ++d)
#pragma unroll
    for (int r = 0; r < 4; ++r)
      Bo[(w * 16 + g * 4 + r) * 64 + d * 16 + l16] = o_acc[d][r];
  if (l16 == 0) {
#pragma unroll
    for (int r = 0; r < 4; ++r) Bl[w * 16 + g * 4 + r] = lsum[r];
  }
}

// ---------------- merge chunk-B partials -> attnO (m=0: plain sums) ----------------
__launch_bounds__(256)
__global__ void merge_b(const float* __restrict__ BoG, const float* __restrict__ BlG,
                        u16* __restrict__ O) {
  const int p = blockIdx.x, h = blockIdx.y;
  const int qbB = 31 - p;
  const size_t s0 = (((size_t)p * 16 + h) * 2 + 0);
  const size_t s1 = s0 + 1;
  const float* Bo0 = BoG + s0 * 4096;
  const float* Bo1 = BoG + s1 * 4096;
  const float* Bl0 = BlG + s0 * 64;
  const float* Bl1 = BlG + s1 * 64;
  const int t = threadIdx.x;
#pragma unroll
  for (int i = 0; i < 4; ++i) {
    int idx = t + i * 256;
    int row = idx >> 4, c4 = idx & 15;
    float inv = 1.f / (Bl0[row] + Bl1[row]);
    float4 a = ((const float4*)Bo0)[(size_t)row * 16 + c4];
    float4 b = ((const float4*)Bo1)[(size_t)row * 16 + c4];
    u16x4 o = { f2bf((a.x + b.x) * inv), f2bf((a.y + b.y) * inv),
                f2bf((a.z + b.z) * inv), f2bf((a.w + b.w) * inv) };
    *(u16x4*)&O[(size_t)(qbB * 64 + row) * 1024 + h * 64 + c4 * 4] = o;
  }
}

// ---------------- launcher ----------------
extern "C" void kernel_launch(void* const* d_in, const int* in_sizes, int n_in,
                              void* d_out, int out_size, void* d_ws, size_t ws_size,
                              hipStream_t stream) {
  const float* x = (const float*)d_in[0];
  const float* slopes = (const float*)d_in[1];
  const float* wq = (const float*)d_in[2];
  const float* wk = (const float*)d_in[3];
  const float* wv = (const float*)d_in[4];
  const float* wo = (const float*)d_in[5];
  const float* ff1w = (const float*)d_in[6];
  const float* ff1b = (const float*)d_in[7];
  const float* ff2w = (const float*)d_in[8];
  const float* ff2b = (const float*)d_in[9];
  const float* ln1g = (const float*)d_in[10];
  const float* ln1b = (const float*)d_in[11];
  const float* ln2g = (const float*)d_in[12];
  const float* ln2b = (const float*)d_in[13];
  float* out = (float*)d_out;

  if (ws_size < (size_t)(56u << 20)) return;  // need 56MB scratch

  char* ws = (char*)d_ws;
  u16* hbuf = (u16*)(ws + 0);              // 4MB: h -> attnO
  u16* Qb = (u16*)(ws + (4u << 20));       // 4MB
  u16* Kbf = (u16*)(ws + (8u << 20));      // 4MB
  u16* Vbf = (u16*)(ws + (12u << 20));     // 4MB
  u16* Vtb = (u16*)(ws + (16u << 20));     // 4MB
  float* P0 = (float*)(ws + (4u << 20));   // 8MB wo partial z=0 (post-attn)
  float* P1 = (float*)(ws + (12u << 20));  // 8MB wo partial z=1
  u16* ffact = Qb;                         // 16MB span 4-20MB
  float* x2 = (float*)(ws + (20u << 20));  // 8MB (post-merge); during attn = Bo
  float* BoG = (float*)(ws + (20u << 20)); // 8MB: 512 slots x 4096 fp32
  u16* h2 = (u16*)(ws + (28u << 20));      // 4MB (post-merge); during attn = Bl
  float* BlG = (float*)(ws + (28u << 20)); // 128KB: 512 slots x 64 fp32
  u16* wqb = (u16*)(ws + (32u << 20));
  u16* wkb = (u16*)(ws + (34u << 20));
  u16* wvb = (u16*)(ws + (36u << 20));
  u16* wob = (u16*)(ws + (38u << 20));
  u16* ff1wb = (u16*)(ws + (40u << 20));
  u16* ff2wb = (u16*)(ws + (48u << 20));
  u16* attnO = hbuf;
  // ff2 split-4 partials: 16MB in the dead weight region 32..48MB
  u16* Qp = (u16*)(ws + (32u << 20));
  const size_t q4off = (size_t)(4u << 20) / 2;  // 4MB stride in u16 elems

  prep<<<2048 + 12288, 256, 0, stream>>>(x, ln1g, ln1b, hbuf, wq, wk, wv, wo, ff1w, ff2w,
                                         wqb, wkb, wvb, wob, ff1wb, ff2wb);
  gemm_qkv64<<<dim3(24, 32), 256, 0, stream>>>(hbuf, wqb, wkb, wvb, Qb, Kbf, Vbf);
  transpose_v<<<dim3(32, 16), 256, 0, stream>>>(Vbf, Vtb);
  attn_fwd<<<dim3(16, 16, 2), 256, 0, stream>>>(Qb, Kbf, Vtb, slopes, attnO, BoG, BlG);
  merge_b<<<dim3(16, 16), 256, 0, stream>>>(BoG, BlG, attnO);
  gemm_bt<64, 128, 1, 4, 4, 2, 1><<<dim3(8, 32, 2), 256, 0, stream>>>(
      attnO, wob, P0, nullptr, nullptr, 2048, 1024, 1024, (size_t)2048 * 1024);
  ln2_add<<<2048, 256, 0, stream>>>(x, P0, P1, ln2g, ln2b, x2, h2);
  gemm_bt<128, 128, 2, 2, 1, 1, 2><<<dim3(32, 16), 256, 0, stream>>>(
      h2, ff1wb, ffact, ff1b, nullptr, 2048, 4096, 1024, 0);
  gemm_bt<64, 128, 1, 4, 0, 4, 1><<<dim3(8, 32, 4), 256, 0, stream>>>(
      ffact, ff2wb, Qp, nullptr, nullptr, 2048, 1024, 4096, q4off);
  final_add<<<2048, 256, 0, stream>>>(x2, ff2b, Qp, q4off, out);
}

// Round 16
// 171.068 us; speedup vs baseline: 1.7161x; 1.0179x over previous
//
#include <hip/hip_runtime.h>
#include <math.h>

typedef unsigned short u16;
typedef __bf16 bf16x8 __attribute__((ext_vector_type(8)));
typedef float f32x4 __attribute__((ext_vector_type(4)));
typedef u16 u16x4 __attribute__((ext_vector_type(4)));
typedef u16 u16x8 __attribute__((ext_vector_type(8)));

#define DEV __device__ __forceinline__

DEV u16 f2bf(float f) {
  unsigned u = __builtin_bit_cast(unsigned, f);
  u += 0x7FFFu + ((u >> 16) & 1u);
  return (u16)(u >> 16);
}
DEV float bf2f(u16 b) {
  unsigned u = ((unsigned)b) << 16;
  return __builtin_bit_cast(float, u);
}

DEV void gload16(const void* g, void* l) {
  __builtin_amdgcn_global_load_lds((__attribute__((address_space(1))) void*)g,
                                   (__attribute__((address_space(3))) void*)l, 16, 0, 0);
}

// ---------------- fused prep: LN1 (blocks 0..2047) + weight cvt (blocks 2048+) --------
__launch_bounds__(256)
__global__ void prep(const float* __restrict__ x, const float* __restrict__ gam,
                     const float* __restrict__ bet, u16* __restrict__ hout,
                     const float* __restrict__ wq, const float* __restrict__ wk,
                     const float* __restrict__ wv, const float* __restrict__ wo,
                     const float* __restrict__ f1, const float* __restrict__ f2,
                     u16* __restrict__ dq, u16* __restrict__ dk, u16* __restrict__ dv,
                     u16* __restrict__ dwo, u16* __restrict__ df1, u16* __restrict__ df2) {
  int t = threadIdx.x;
  if (blockIdx.x < 2048) {
    int row = blockIdx.x;
    float4 v = ((const float4*)(x + (size_t)row * 1024))[t];
    float s = v.x + v.y + v.z + v.w;
    float s2 = v.x * v.x + v.y * v.y + v.z * v.z + v.w * v.w;
    for (int off = 1; off < 64; off <<= 1) {
      s += __shfl_xor(s, off);
      s2 += __shfl_xor(s2, off);
    }
    __shared__ float red[8];
    int wv0 = t >> 6, ln = t & 63;
    if (ln == 0) { red[wv0] = s; red[wv0 + 4] = s2; }
    __syncthreads();
    s = red[0] + red[1] + red[2] + red[3];
    s2 = red[4] + red[5] + red[6] + red[7];
    float mu = s * (1.f / 1024.f);
    float var = s2 * (1.f / 1024.f) - mu * mu;
    float rs = rsqrtf(var + 1e-5f);
    float4 gv = ((const float4*)gam)[t];
    float4 bv = ((const float4*)bet)[t];
    u16x4 o = { f2bf((v.x - mu) * rs * gv.x + bv.x), f2bf((v.y - mu) * rs * gv.y + bv.y),
                f2bf((v.z - mu) * rs * gv.z + bv.z), f2bf((v.w - mu) * rs * gv.w + bv.w) };
    ((u16x4*)(hout + (size_t)row * 1024))[t] = o;
  } else {
    int i = (blockIdx.x - 2048) * 256 + t;
    const float* src;
    u16* dst;
    int local;
    if (i < (1 << 18)) { src = wq; dst = dq; local = i; }
    else if (i < (2 << 18)) { src = wk; dst = dk; local = i - (1 << 18); }
    else if (i < (3 << 18)) { src = wv; dst = dv; local = i - (2 << 18); }
    else if (i < (4 << 18)) { src = wo; dst = dwo; local = i - (3 << 18); }
    else if (i < (4 << 18) + (1 << 20)) { src = f1; dst = df1; local = i - (4 << 18); }
    else { src = f2; dst = df2; local = i - ((4 << 18) + (1 << 20)); }
    float4 v = ((const float4*)src)[local];
    u16x4 o = { f2bf(v.x), f2bf(v.y), f2bf(v.z), f2bf(v.w) };
    ((u16x4*)dst)[local] = o;
  }
}

// ---------------- fused: x2 = x + sum of 4 bf16 wo-partials; h2 = LN(x2) ----------
__launch_bounds__(256)
__global__ void ln2_add(const float* __restrict__ x, const u16* __restrict__ Pw,
                        size_t poff, const float* __restrict__ gam,
                        const float* __restrict__ bet, float* __restrict__ x2,
                        u16* __restrict__ out) {
  int row = blockIdx.x;
  int t = threadIdx.x;
  size_t base = (size_t)row * 256 + t;
  float4 v = ((const float4*)x)[base];
#pragma unroll
  for (int i = 0; i < 4; ++i) {
    u16x4 q = ((const u16x4*)(Pw + i * poff))[base];
    v.x += bf2f(q[0]);
    v.y += bf2f(q[1]);
    v.z += bf2f(q[2]);
    v.w += bf2f(q[3]);
  }
  ((float4*)x2)[base] = v;
  float s = v.x + v.y + v.z + v.w;
  float s2 = v.x * v.x + v.y * v.y + v.z * v.z + v.w * v.w;
  for (int off = 1; off < 64; off <<= 1) {
    s += __shfl_xor(s, off);
    s2 += __shfl_xor(s2, off);
  }
  __shared__ float red[8];
  int wv = t >> 6, ln = t & 63;
  if (ln == 0) { red[wv] = s; red[wv + 4] = s2; }
  __syncthreads();
  s = red[0] + red[1] + red[2] + red[3];
  s2 = red[4] + red[5] + red[6] + red[7];
  float mu = s * (1.f / 1024.f);
  float var = s2 * (1.f / 1024.f) - mu * mu;
  float rs = rsqrtf(var + 1e-5f);
  float4 gv = ((const float4*)gam)[t];
  float4 bv = ((const float4*)bet)[t];
  u16x4 o = { f2bf((v.x - mu) * rs * gv.x + bv.x), f2bf((v.y - mu) * rs * gv.y + bv.y),
              f2bf((v.z - mu) * rs * gv.z + bv.z), f2bf((v.w - mu) * rs * gv.w + bv.w) };
  ((u16x4*)(out + (size_t)row * 1024))[t] = o;
}

// ---------------- final: out = x2 + b2 + sum of 4 ff2 partials ----------------
__launch_bounds__(256)
__global__ void final_add(const float* __restrict__ x2, const float* __restrict__ b2,
                          const u16* __restrict__ Qp, size_t qoff,
                          float* __restrict__ out) {
  int row = blockIdx.x;
  int t = threadIdx.x;
  size_t base = (size_t)row * 256 + t;
  float4 xv = ((const float4*)x2)[base];
  float4 bv = ((const float4*)b2)[t];
  float4 o = { xv.x + bv.x, xv.y + bv.y, xv.z + bv.z, xv.w + bv.w };
#pragma unroll
  for (int i = 0; i < 4; ++i) {
    u16x4 q = ((const u16x4*)(Qp + i * qoff))[base];
    o.x += bf2f(q[0]);
    o.y += bf2f(q[1]);
    o.z += bf2f(q[2]);
    o.w += bf2f(q[3]);
  }
  ((float4*)out)[base] = o;
}

// ---------------- V transpose ----------------
__launch_bounds__(256)
__global__ void transpose_v(const u16* __restrict__ V, u16* __restrict__ Vt) {
  const int st = blockIdx.x, h = blockIdx.y;
  __shared__ u16 tile[64][72];
  const int t = threadIdx.x;
  const int r = t >> 3, c8 = t & 7;
#pragma unroll
  for (int i = 0; i < 2; ++i) {
    int row = i * 32 + r;
    *(u16x8*)&tile[row][c8 * 8] =
        *(const u16x8*)&V[(size_t)(st * 64 + row) * 1024 + h * 64 + c8 * 8];
  }
  __syncthreads();
#pragma unroll
  for (int i = 0; i < 2; ++i) {
    int d = i * 32 + r;
    u16x8 o;
#pragma unroll
    for (int jj = 0; jj < 8; ++jj) o[jj] = tile[c8 * 8 + jj][d];
    *(u16x8*)&Vt[(size_t)(h * 64 + d) * 2048 + st * 64 + c8 * 8] = o;
  }
}

// ---------------- generic bf16 GEMM + XCD-swizzle (R12) ----------------
template <int BM, int BN, int WR, int WC, int EPI, int SPLITK, int SWZ>
__launch_bounds__(256, 2)
__global__ void gemm_bt(const u16* __restrict__ A, const u16* __restrict__ B,
                        void* __restrict__ C, const float* __restrict__ bias,
                        const float* __restrict__ resid, int M, int N, int K,
                        size_t zoff) {
  constexpr int FM = BM / WR / 16;
  constexpr int FN = BN / WC / 16;
  __shared__ u16 As[BM * 32];
  __shared__ u16 Bs[BN * 32];
  int bxi = blockIdx.x, byi = blockIdx.y, bzi = blockIdx.z;
  if constexpr (SWZ == 1) {
    int bid = bxi + 8 * (byi + (int)gridDim.y * bzi);
    int xcd = bid & 7, k = bid >> 3;
    bxi = xcd;
    byi = k % (int)gridDim.y;
    bzi = k / (int)gridDim.y;
  } else if constexpr (SWZ == 2) {
    int bid = bxi + 32 * blockIdx.y;
    int xcd = bid & 7, k = bid >> 3;
    bxi = xcd * 4 + (k & 3);
    byi = k >> 2;
    bzi = 0;
  }
  const int t = threadIdx.x, lane = t & 63, w = t >> 6;
  const int wr = w / WC, wc = w % WC;
  const int g = lane >> 4, l16 = lane & 15;
  const int m0 = byi * BM, n0 = bxi * BN;
  const int ks = K / SPLITK;
  const int k0 = (SPLITK > 1) ? bzi * ks : 0;
  const size_t cbase = (SPLITK > 1) ? (size_t)bzi * zoff : 0;
  f32x4 acc[FM][FN] = {};
  const int nkt = ks >> 5;
  for (int kt = 0; kt < nkt; ++kt) {
    const u16* Ag = A + (size_t)m0 * K + k0 + kt * 32;
    const u16* Bg = B + (size_t)n0 * K + k0 + kt * 32;
#pragma unroll
    for (int i = 0; i < BM / 64; ++i) {
      int c = i * 256 + t;
      gload16(Ag + (size_t)(c >> 2) * K + (c & 3) * 8, &As[(i * 256 + w * 64) * 8]);
    }
#pragma unroll
    for (int i = 0; i < BN / 64; ++i) {
      int c = i * 256 + t;
      gload16(Bg + (size_t)(c >> 2) * K + (c & 3) * 8, &Bs[(i * 256 + w * 64) * 8]);
    }
    __syncthreads();
    bf16x8 af[FM], bfr[FN];
#pragma unroll
    for (int m = 0; m < FM; ++m)
      af[m] = *(const bf16x8*)&As[(wr * FM * 16 + m * 16 + l16) * 32 + g * 8];
#pragma unroll
    for (int n = 0; n < FN; ++n)
      bfr[n] = *(const bf16x8*)&Bs[(wc * FN * 16 + n * 16 + l16) * 32 + g * 8];
#pragma unroll
    for (int m = 0; m < FM; ++m)
#pragma unroll
      for (int n = 0; n < FN; ++n)
        acc[m][n] = __builtin_amdgcn_mfma_f32_16x16x32_bf16(af[m], bfr[n], acc[m][n], 0, 0, 0);
    __syncthreads();
  }
#pragma unroll
  for (int m = 0; m < FM; ++m)
#pragma unroll
    for (int n = 0; n < FN; ++n)
#pragma unroll
      for (int r = 0; r < 4; ++r) {
        int row = m0 + wr * FM * 16 + m * 16 + g * 4 + r;
        int col = n0 + wc * FN * 16 + n * 16 + l16;
        size_t idx = (size_t)row * N + col;
        float v = acc[m][n][r];
        if constexpr (EPI == 0) {
          ((u16*)C)[cbase + idx] = f2bf(v);
        } else if constexpr (EPI == 1) {
          v += bias[col];
          v = 0.5f * v * (1.f + erff(v * 0.70710678118f));
          ((u16*)C)[idx] = f2bf(v);
        } else if constexpr (EPI == 2) {
          ((float*)C)[idx] = v + bias[col] + resid[idx];
        } else if constexpr (EPI == 3) {
          ((float*)C)[idx] = v + resid[idx];
        } else {
          ((float*)C)[cbase + idx] = v;
        }
      }
}

// ---------------- fused QKV projection, 64x128 tiles + XCD swizzle (R12) --------------
__launch_bounds__(256, 2)
__global__ void gemm_qkv64(const u16* __restrict__ A, const u16* __restrict__ B0,
                           const u16* __restrict__ B1, const u16* __restrict__ B2,
                           u16* __restrict__ C0, u16* __restrict__ C1, u16* __restrict__ C2) {
  constexpr int FM = 4, FN = 2;
  const int K = 1024, N = 1024;
  int bid = blockIdx.x + 24 * blockIdx.y;
  int xcd = bid & 7, kk0 = bid >> 3;
  const int bxs = xcd * 3 + kk0 % 3;
  const int bys = kk0 / 3;
  const int which = bxs >> 3;
  const u16* B = which == 0 ? B0 : which == 1 ? B1 : B2;
  u16* C = which == 0 ? C0 : which == 1 ? C1 : C2;
  __shared__ u16 As[64 * 32];
  __shared__ u16 Bs[128 * 32];
  const int t = threadIdx.x, lane = t & 63, w = t >> 6;
  const int wc = w;
  const int g = lane >> 4, l16 = lane & 15;
  const int m0 = bys * 64, n0 = (bxs & 7) * 128;
  f32x4 acc[FM][FN] = {};
  for (int kt = 0; kt < 32; ++kt) {
    const u16* Ag = A + (size_t)m0 * K + kt * 32;
    const u16* Bg = B + (size_t)n0 * K + kt * 32;
    {
      int c = t;
      gload16(Ag + (size_t)(c >> 2) * K + (c & 3) * 8, &As[(w * 64) * 8]);
    }
#pragma unroll
    for (int i = 0; i < 2; ++i) {
      int c = i * 256 + t;
      gload16(Bg + (size_t)(c >> 2) * K + (c & 3) * 8, &Bs[(i * 256 + w * 64) * 8]);
    }
    __syncthreads();
    bf16x8 af[FM], bfr[FN];
#pragma unroll
    for (int m = 0; m < FM; ++m)
      af[m] = *(const bf16x8*)&As[(m * 16 + l16) * 32 + g * 8];
#pragma unroll
    for (int n = 0; n < FN; ++n)
      bfr[n] = *(const bf16x8*)&Bs[(wc * FN * 16 + n * 16 + l16) * 32 + g * 8];
#pragma unroll
    for (int m = 0; m < FM; ++m)
#pragma unroll
      for (int n = 0; n < FN; ++n)
        acc[m][n] = __builtin_amdgcn_mfma_f32_16x16x32_bf16(af[m], bfr[n], acc[m][n], 0, 0, 0);
    __syncthreads();
  }
#pragma unroll
  for (int m = 0; m < FM; ++m)
#pragma unroll
    for (int n = 0; n < FN; ++n)
#pragma unroll
      for (int r = 0; r < 4; ++r) {
        int row = m0 + m * 16 + g * 4 + r;
        int col = n0 + wc * FN * 16 + n * 16 + l16;
        C[(size_t)row * N + col] = f2bf(acc[m][n][r]);
      }
}

// ---------------- flash attention: 768 blocks (3/CU), 11 tiles each ----------------
// Pool of 33 tiles per (p,h) split 3 ways (33 = 3*11). Static-max softmax + MFMA
// row-sum (R14). All output via partials: Bo bf16[64][64] + Bl fp32[64] per
// (p,h,z,chunk) slot. Slots 0..1023 at BoLo (20-28MB), 1024..1535 at BoHi
// (12-16MB = Vbf region, dead after transpose_v; NOT hbuf -> no overlap with
// merge_b's attnO output, which was the R15 race).
__launch_bounds__(256, 4)
__global__ void attn_fwd(const u16* __restrict__ Q, const u16* __restrict__ Kb,
                         const u16* __restrict__ Vt, const float* __restrict__ slopes,
                         u16* __restrict__ BoLo, u16* __restrict__ BoHi,
                         float* __restrict__ BlG) {
  const int p = blockIdx.x;
  const int h = blockIdx.y;
  const int z = blockIdx.z;
  const int t = threadIdx.x, lane = t & 63, w = t >> 6;
  const int g = lane >> 4, l16 = lane & 15;
  const float slope = slopes[h];
  const int TA = p + 1;
  const int qbB = 31 - p;

  __shared__ u16 Ks[2][4096];
  __shared__ u16 Vs[2][4096];
  __shared__ u16 Ps[4][16][72];

  const int r0 = w * 8 + (lane >> 3), r1 = 32 + r0;
  const int c8 = lane & 7;
  const int c0s = c8 ^ (r0 & 7), c1s = c8 ^ (r1 & 7);
  const int sw = l16 & 7;
  const u16x8 ones_u = { 0x3F80, 0x3F80, 0x3F80, 0x3F80, 0x3F80, 0x3F80, 0x3F80, 0x3F80 };
  const bf16x8 ones = __builtin_bit_cast(bf16x8, ones_u);

  auto stage = [&](int buf, int kv0) {
    gload16(Kb + (size_t)(kv0 + r0) * 1024 + h * 64 + c0s * 8, &Ks[buf][(w * 64) * 8]);
    gload16(Kb + (size_t)(kv0 + r1) * 1024 + h * 64 + c1s * 8, &Ks[buf][(256 + w * 64) * 8]);
    gload16(Vt + (size_t)(h * 64 + r0) * 2048 + kv0 + c0s * 8, &Vs[buf][(w * 64) * 8]);
    gload16(Vt + (size_t)(h * 64 + r1) * 2048 + kv0 + c1s * 8, &Vs[buf][(256 + w * 64) * 8]);
  };
  auto kvOf = [&](int idx) { return idx < TA ? idx * 64 : (idx - TA) * 64; };
  auto boPtr = [&](size_t slot) {
    return slot < 1024 ? BoLo + slot * 4096 : BoHi + (slot - 1024) * 4096;
  };

  const int myStart = z * 11;
  const int myEnd = myStart + 11;
  const size_t slotBase = (((size_t)p * 16 + h) * 3 + z) * 2;

  bool flushed[2] = { false, false };
  f32x4 o_acc[4] = {};
  f32x4 lsum = {};

  auto flush = [&](int c) {
    u16* Bo = boPtr(slotBase + c);
    float* Bl = BlG + (slotBase + c) * 64;
#pragma unroll
    for (int d = 0; d < 4; ++d)
#pragma unroll
      for (int r = 0; r < 4; ++r)
        Bo[(w * 16 + g * 4 + r) * 64 + d * 16 + l16] = f2bf(o_acc[d][r]);
    if (l16 == 0) {
#pragma unroll
      for (int r = 0; r < 4; ++r) Bl[w * 16 + g * 4 + r] = lsum[r];
    }
    flushed[c] = true;
  };

  int qb = (myStart < TA) ? p : qbB;
  int q0 = qb * 64 + w * 16;
  bf16x8 qf[2];
#pragma unroll
  for (int kk = 0; kk < 2; ++kk)
    qf[kk] = *(const bf16x8*)&Q[(size_t)(q0 + l16) * 1024 + h * 64 + kk * 32 + g * 8];

  stage(0, kvOf(myStart));
  __syncthreads();

  int cur = 0;
  for (int it = 0; it < 11; ++it) {
    const int idx = myStart + it;
    if (idx == TA && myStart < TA) {
      flush(0);
      qb = qbB;
      q0 = qb * 64 + w * 16;
#pragma unroll
      for (int kk = 0; kk < 2; ++kk)
        qf[kk] = *(const bf16x8*)&Q[(size_t)(q0 + l16) * 1024 + h * 64 + kk * 32 + g * 8];
#pragma unroll
      for (int d = 0; d < 4; ++d) o_acc[d] = f32x4{};
      lsum = f32x4{};
    }
    if (it + 1 < 11) stage(cur ^ 1, kvOf(idx + 1));
    {
      const int kv0 = kvOf(idx);
      const bool lastT = (idx == TA - 1) || (idx == 32);
      f32x4 s[4];
      __builtin_amdgcn_s_setprio(1);
#pragma unroll
      for (int n = 0; n < 4; ++n) {
        bf16x8 kf0 = *(const bf16x8*)&Ks[cur][(n * 16 + l16) * 64 + ((g ^ sw) * 8)];
        bf16x8 kf1 = *(const bf16x8*)&Ks[cur][(n * 16 + l16) * 64 + (((4 + g) ^ sw) * 8)];
        f32x4 z4 = {};
        s[n] = __builtin_amdgcn_mfma_f32_16x16x32_bf16(qf[0], kf0, z4, 0, 0, 0);
        s[n] = __builtin_amdgcn_mfma_f32_16x16x32_bf16(qf[1], kf1, s[n], 0, 0, 0);
      }
      __builtin_amdgcn_s_setprio(0);
      const float aB = -slope * (float)(kv0 + l16);
#pragma unroll
      for (int n = 0; n < 4; ++n) {
        const float aN = aB - slope * (float)(n * 16);
        const int kj = kv0 + n * 16 + l16;
        u16x4 pr;
#pragma unroll
        for (int r = 0; r < 4; ++r) {
          float val = fmaf(s[n][r], 0.125f, aN);
          if (lastT) {
            int qi = q0 + g * 4 + r;
            val = (kj <= qi) ? val : -1e30f;
          }
          pr[r] = f2bf(__expf(val));
        }
#pragma unroll
        for (int r = 0; r < 4; ++r) Ps[w][g * 4 + r][n * 16 + l16] = pr[r];
      }
      bf16x8 pf[2];
#pragma unroll
      for (int kk = 0; kk < 2; ++kk)
        pf[kk] = *(const bf16x8*)&Ps[w][l16][kk * 32 + g * 8];
      __builtin_amdgcn_s_setprio(1);
#pragma unroll
      for (int kk = 0; kk < 2; ++kk)
        lsum = __builtin_amdgcn_mfma_f32_16x16x32_bf16(pf[kk], ones, lsum, 0, 0, 0);
#pragma unroll
      for (int d = 0; d < 4; ++d) {
#pragma unroll
        for (int kk = 0; kk < 2; ++kk) {
          bf16x8 vv = *(const bf16x8*)&Vs[cur][(d * 16 + l16) * 64 + (((kk * 4 + g) ^ sw) * 8)];
          o_acc[d] = __builtin_amdgcn_mfma_f32_16x16x32_bf16(pf[kk], vv, o_acc[d], 0, 0, 0);
        }
      }
      __builtin_amdgcn_s_setprio(0);
    }
    __syncthreads();
    cur ^= 1;
  }
  flush((myEnd - 1) < TA ? 0 : 1);
#pragma unroll
  for (int c = 0; c < 2; ++c)
    if (!flushed[c]) {
      u16* Bo = boPtr(slotBase + c);
      float* Bl = BlG + (slotBase + c) * 64;
#pragma unroll
      for (int i = 0; i < 16; ++i) Bo[i * 256 + t] = 0;
      if (t < 64) Bl[t] = 0.f;
    }
}

// ---------------- merge 3 z-partials per chunk -> attnO ----------------
__launch_bounds__(256)
__global__ void merge_b(const u16* __restrict__ BoLo, const u16* __restrict__ BoHi,
                        const float* __restrict__ BlG, u16* __restrict__ O) {
  const int p = blockIdx.x, h = blockIdx.y;
  const int t = threadIdx.x;
  const int row = t >> 2, c0 = (t & 3) * 16;
  const size_t base = ((size_t)p * 16 + h) * 6;
#pragma unroll
  for (int c = 0; c < 2; ++c) {
    const int qb = c == 0 ? p : 31 - p;
    float l = 0.f;
    float acc[16];
#pragma unroll
    for (int i = 0; i < 16; ++i) acc[i] = 0.f;
#pragma unroll
    for (int z = 0; z < 3; ++z) {
      const size_t slot = base + (size_t)z * 2 + c;
      l += BlG[slot * 64 + row];
      const u16* Bo = (slot < 1024 ? BoLo + slot * 4096 : BoHi + (slot - 1024) * 4096) +
                      row * 64 + c0;
#pragma unroll
      for (int i = 0; i < 16; ++i) acc[i] += bf2f(Bo[i]);
    }
    float inv = 1.f / l;
    u16x8 o0, o1;
#pragma unroll
    for (int i = 0; i < 8; ++i) {
      o0[i] = f2bf(acc[i] * inv);
      o1[i] = f2bf(acc[8 + i] * inv);
    }
    u16* dst = O + (size_t)(qb * 64 + row) * 1024 + h * 64 + c0;
    *(u16x8*)dst = o0;
    *(u16x8*)(dst + 8) = o1;
  }
}

// ---------------- launcher ----------------
extern "C" void kernel_launch(void* const* d_in, const int* in_sizes, int n_in,
                              void* d_out, int out_size, void* d_ws, size_t ws_size,
                              hipStream_t stream) {
  const float* x = (const float*)d_in[0];
  const float* slopes = (const float*)d_in[1];
  const float* wq = (const float*)d_in[2];
  const float* wk = (const float*)d_in[3];
  const float* wv = (const float*)d_in[4];
  const float* wo = (const float*)d_in[5];
  const float* ff1w = (const float*)d_in[6];
  const float* ff1b = (const float*)d_in[7];
  const float* ff2w = (const float*)d_in[8];
  const float* ff2b = (const float*)d_in[9];
  const float* ln1g = (const float*)d_in[10];
  const float* ln1b = (const float*)d_in[11];
  const float* ln2g = (const float*)d_in[12];
  const float* ln2b = (const float*)d_in[13];
  float* out = (float*)d_out;

  if (ws_size < (size_t)(56u << 20)) return;  // need 56MB scratch

  char* ws = (char*)d_ws;
  // Region plan (time-ordered):
  //  0-4   hbuf: LN1 out (prep..qkv) -> attnO (merge..wo)            [free during attn]
  //  4-8   Qb (qkv..attn) -> Pw[0] (wo..ln2_add) -> ffact (ff1..ff2)
  //  8-12  Kbf (qkv..attn) -> Pw[1] / ffact
  //  12-16 Vbf (qkv..transpose) -> BoHi slots 1024..1535 (attn..merge) -> Pw[2]/ffact
  //  16-20 Vtb (transpose..attn) -> Pw[3] / ffact
  //  20-28 BoLo slots 0..1023 (attn..merge) -> x2 (ln2_add..final)
  //  28-32 BlG 384KB (attn..merge) -> h2 (ln2_add..ff1)
  //  32-48 weights wq..ff1 (prep..ff1) -> ff2 partials Qp (ff2..final)
  //  48-56 ff2wb (prep..ff2)
  u16* hbuf = (u16*)(ws + 0);
  u16* Qb = (u16*)(ws + (4u << 20));
  u16* Kbf = (u16*)(ws + (8u << 20));
  u16* Vbf = (u16*)(ws + (12u << 20));
  u16* Vtb = (u16*)(ws + (16u << 20));
  u16* Pw = (u16*)(ws + (4u << 20));
  u16* ffact = Qb;
  u16* BoLo = (u16*)(ws + (20u << 20));     // slots 0..1023 (8MB)
  u16* BoHi = (u16*)(ws + (12u << 20));     // slots 1024..1535 (4MB; Vbf dead after transpose)
  float* x2 = (float*)(ws + (20u << 20));
  float* BlG = (float*)(ws + (28u << 20));  // 384KB
  u16* h2 = (u16*)(ws + (28u << 20));
  u16* wqb = (u16*)(ws + (32u << 20));
  u16* wkb = (u16*)(ws + (34u << 20));
  u16* wvb = (u16*)(ws + (36u << 20));
  u16* wob = (u16*)(ws + (38u << 20));
  u16* ff1wb = (u16*)(ws + (40u << 20));
  u16* ff2wb = (u16*)(ws + (48u << 20));
  u16* attnO = hbuf;
  u16* Qp = (u16*)(ws + (32u << 20));
  const size_t q4off = (size_t)(4u << 20) / 2;
  const size_t woff = (size_t)2048 * 1024;

  prep<<<2048 + 12288, 256, 0, stream>>>(x, ln1g, ln1b, hbuf, wq, wk, wv, wo, ff1w, ff2w,
                                         wqb, wkb, wvb, wob, ff1wb, ff2wb);
  gemm_qkv64<<<dim3(24, 32), 256, 0, stream>>>(hbuf, wqb, wkb, wvb, Qb, Kbf, Vbf);
  transpose_v<<<dim3(32, 16), 256, 0, stream>>>(Vbf, Vtb);
  attn_fwd<<<dim3(16, 16, 3), 256, 0, stream>>>(Qb, Kbf, Vtb, slopes, BoLo, BoHi, BlG);
  merge_b<<<dim3(16, 16), 256, 0, stream>>>(BoLo, BoHi, BlG, attnO);
  gemm_bt<64, 128, 1, 4, 0, 4, 1><<<dim3(8, 32, 4), 256, 0, stream>>>(
      attnO, wob, Pw, nullptr, nullptr, 2048, 1024, 1024, woff);
  ln2_add<<<2048, 256, 0, stream>>>(x, Pw, woff, ln2g, ln2b, x2, h2);
  gemm_bt<128, 128, 2, 2, 1, 1, 2><<<dim3(32, 16), 256, 0, stream>>>(
      h2, ff1wb, ffact, ff1b, nullptr, 2048, 4096, 1024, 0);
  gemm_bt<64, 128, 1, 4, 0, 4, 1><<<dim3(8, 32, 4), 256, 0, stream>>>(
      ffact, ff2wb, Qp, nullptr, nullptr, 2048, 1024, 4096, q4off);
  final_add<<<2048, 256, 0, stream>>>(x2, ff2b, Qp, q4off, out);
}

// Round 17
// 168.188 us; speedup vs baseline: 1.7455x; 1.0171x over previous
//
#include <hip/hip_runtime.h>
#include <math.h>

typedef unsigned short u16;
typedef __bf16 bf16x8 __attribute__((ext_vector_type(8)));
typedef float f32x4 __attribute__((ext_vector_type(4)));
typedef u16 u16x4 __attribute__((ext_vector_type(4)));
typedef u16 u16x8 __attribute__((ext_vector_type(8)));

#define DEV __device__ __forceinline__

DEV u16 f2bf(float f) {
  unsigned u = __builtin_bit_cast(unsigned, f);
  u += 0x7FFFu + ((u >> 16) & 1u);
  return (u16)(u >> 16);
}
DEV float bf2f(u16 b) {
  unsigned u = ((unsigned)b) << 16;
  return __builtin_bit_cast(float, u);
}

DEV void gload16(const void* g, void* l) {
  __builtin_amdgcn_global_load_lds((__attribute__((address_space(1))) void*)g,
                                   (__attribute__((address_space(3))) void*)l, 16, 0, 0);
}

// ---------------- fused prep: LN1 (blocks 0..2047) + weight cvt (blocks 2048+) --------
__launch_bounds__(256)
__global__ void prep(const float* __restrict__ x, const float* __restrict__ gam,
                     const float* __restrict__ bet, u16* __restrict__ hout,
                     const float* __restrict__ wq, const float* __restrict__ wk,
                     const float* __restrict__ wv, const float* __restrict__ wo,
                     const float* __restrict__ f1, const float* __restrict__ f2,
                     u16* __restrict__ dq, u16* __restrict__ dk, u16* __restrict__ dv,
                     u16* __restrict__ dwo, u16* __restrict__ df1, u16* __restrict__ df2) {
  int t = threadIdx.x;
  if (blockIdx.x < 2048) {
    int row = blockIdx.x;
    float4 v = ((const float4*)(x + (size_t)row * 1024))[t];
    float s = v.x + v.y + v.z + v.w;
    float s2 = v.x * v.x + v.y * v.y + v.z * v.z + v.w * v.w;
    for (int off = 1; off < 64; off <<= 1) {
      s += __shfl_xor(s, off);
      s2 += __shfl_xor(s2, off);
    }
    __shared__ float red[8];
    int wv0 = t >> 6, ln = t & 63;
    if (ln == 0) { red[wv0] = s; red[wv0 + 4] = s2; }
    __syncthreads();
    s = red[0] + red[1] + red[2] + red[3];
    s2 = red[4] + red[5] + red[6] + red[7];
    float mu = s * (1.f / 1024.f);
    float var = s2 * (1.f / 1024.f) - mu * mu;
    float rs = rsqrtf(var + 1e-5f);
    float4 gv = ((const float4*)gam)[t];
    float4 bv = ((const float4*)bet)[t];
    u16x4 o = { f2bf((v.x - mu) * rs * gv.x + bv.x), f2bf((v.y - mu) * rs * gv.y + bv.y),
                f2bf((v.z - mu) * rs * gv.z + bv.z), f2bf((v.w - mu) * rs * gv.w + bv.w) };
    ((u16x4*)(hout + (size_t)row * 1024))[t] = o;
  } else {
    int i = (blockIdx.x - 2048) * 256 + t;
    const float* src;
    u16* dst;
    int local;
    if (i < (1 << 18)) { src = wq; dst = dq; local = i; }
    else if (i < (2 << 18)) { src = wk; dst = dk; local = i - (1 << 18); }
    else if (i < (3 << 18)) { src = wv; dst = dv; local = i - (2 << 18); }
    else if (i < (4 << 18)) { src = wo; dst = dwo; local = i - (3 << 18); }
    else if (i < (4 << 18) + (1 << 20)) { src = f1; dst = df1; local = i - (4 << 18); }
    else { src = f2; dst = df2; local = i - ((4 << 18) + (1 << 20)); }
    float4 v = ((const float4*)src)[local];
    u16x4 o = { f2bf(v.x), f2bf(v.y), f2bf(v.z), f2bf(v.w) };
    ((u16x4*)dst)[local] = o;
  }
}

// ---------------- fused: x2 = x + sum of 4 bf16 wo-partials; h2 = LN(x2) ----------
__launch_bounds__(256)
__global__ void ln2_add(const float* __restrict__ x, const u16* __restrict__ Pw,
                        size_t poff, const float* __restrict__ gam,
                        const float* __restrict__ bet, float* __restrict__ x2,
                        u16* __restrict__ out) {
  int row = blockIdx.x;
  int t = threadIdx.x;
  size_t base = (size_t)row * 256 + t;
  float4 v = ((const float4*)x)[base];
#pragma unroll
  for (int i = 0; i < 4; ++i) {
    u16x4 q = ((const u16x4*)(Pw + i * poff))[base];
    v.x += bf2f(q[0]);
    v.y += bf2f(q[1]);
    v.z += bf2f(q[2]);
    v.w += bf2f(q[3]);
  }
  ((float4*)x2)[base] = v;
  float s = v.x + v.y + v.z + v.w;
  float s2 = v.x * v.x + v.y * v.y + v.z * v.z + v.w * v.w;
  for (int off = 1; off < 64; off <<= 1) {
    s += __shfl_xor(s, off);
    s2 += __shfl_xor(s2, off);
  }
  __shared__ float red[8];
  int wv = t >> 6, ln = t & 63;
  if (ln == 0) { red[wv] = s; red[wv + 4] = s2; }
  __syncthreads();
  s = red[0] + red[1] + red[2] + red[3];
  s2 = red[4] + red[5] + red[6] + red[7];
  float mu = s * (1.f / 1024.f);
  float var = s2 * (1.f / 1024.f) - mu * mu;
  float rs = rsqrtf(var + 1e-5f);
  float4 gv = ((const float4*)gam)[t];
  float4 bv = ((const float4*)bet)[t];
  u16x4 o = { f2bf((v.x - mu) * rs * gv.x + bv.x), f2bf((v.y - mu) * rs * gv.y + bv.y),
              f2bf((v.z - mu) * rs * gv.z + bv.z), f2bf((v.w - mu) * rs * gv.w + bv.w) };
  ((u16x4*)(out + (size_t)row * 1024))[t] = o;
}

// ---------------- final: out = x2 + b2 + sum of 4 ff2 partials ----------------
__launch_bounds__(256)
__global__ void final_add(const float* __restrict__ x2, const float* __restrict__ b2,
                          const u16* __restrict__ Qp, size_t qoff,
                          float* __restrict__ out) {
  int row = blockIdx.x;
  int t = threadIdx.x;
  size_t base = (size_t)row * 256 + t;
  float4 xv = ((const float4*)x2)[base];
  float4 bv = ((const float4*)b2)[t];
  float4 o = { xv.x + bv.x, xv.y + bv.y, xv.z + bv.z, xv.w + bv.w };
#pragma unroll
  for (int i = 0; i < 4; ++i) {
    u16x4 q = ((const u16x4*)(Qp + i * qoff))[base];
    o.x += bf2f(q[0]);
    o.y += bf2f(q[1]);
    o.z += bf2f(q[2]);
    o.w += bf2f(q[3]);
  }
  ((float4*)out)[base] = o;
}

// ---------------- V transpose ----------------
__launch_bounds__(256)
__global__ void transpose_v(const u16* __restrict__ V, u16* __restrict__ Vt) {
  const int st = blockIdx.x, h = blockIdx.y;
  __shared__ u16 tile[64][72];
  const int t = threadIdx.x;
  const int r = t >> 3, c8 = t & 7;
#pragma unroll
  for (int i = 0; i < 2; ++i) {
    int row = i * 32 + r;
    *(u16x8*)&tile[row][c8 * 8] =
        *(const u16x8*)&V[(size_t)(st * 64 + row) * 1024 + h * 64 + c8 * 8];
  }
  __syncthreads();
#pragma unroll
  for (int i = 0; i < 2; ++i) {
    int d = i * 32 + r;
    u16x8 o;
#pragma unroll
    for (int jj = 0; jj < 8; ++jj) o[jj] = tile[c8 * 8 + jj][d];
    *(u16x8*)&Vt[(size_t)(h * 64 + d) * 2048 + st * 64 + c8 * 8] = o;
  }
}

// ---------------- generic bf16 GEMM + XCD-swizzle (R12) ----------------
template <int BM, int BN, int WR, int WC, int EPI, int SPLITK, int SWZ>
__launch_bounds__(256, 2)
__global__ void gemm_bt(const u16* __restrict__ A, const u16* __restrict__ B,
                        void* __restrict__ C, const float* __restrict__ bias,
                        const float* __restrict__ resid, int M, int N, int K,
                        size_t zoff) {
  constexpr int FM = BM / WR / 16;
  constexpr int FN = BN / WC / 16;
  __shared__ u16 As[BM * 32];
  __shared__ u16 Bs[BN * 32];
  int bxi = blockIdx.x, byi = blockIdx.y, bzi = blockIdx.z;
  if constexpr (SWZ == 1) {
    int bid = bxi + 8 * (byi + (int)gridDim.y * bzi);
    int xcd = bid & 7, k = bid >> 3;
    bxi = xcd;
    byi = k % (int)gridDim.y;
    bzi = k / (int)gridDim.y;
  } else if constexpr (SWZ == 2) {
    int bid = bxi + 32 * blockIdx.y;
    int xcd = bid & 7, k = bid >> 3;
    bxi = xcd * 4 + (k & 3);
    byi = k >> 2;
    bzi = 0;
  }
  const int t = threadIdx.x, lane = t & 63, w = t >> 6;
  const int wr = w / WC, wc = w % WC;
  const int g = lane >> 4, l16 = lane & 15;
  const int m0 = byi * BM, n0 = bxi * BN;
  const int ks = K / SPLITK;
  const int k0 = (SPLITK > 1) ? bzi * ks : 0;
  const size_t cbase = (SPLITK > 1) ? (size_t)bzi * zoff : 0;
  f32x4 acc[FM][FN] = {};
  const int nkt = ks >> 5;
  for (int kt = 0; kt < nkt; ++kt) {
    const u16* Ag = A + (size_t)m0 * K + k0 + kt * 32;
    const u16* Bg = B + (size_t)n0 * K + k0 + kt * 32;
#pragma unroll
    for (int i = 0; i < BM / 64; ++i) {
      int c = i * 256 + t;
      gload16(Ag + (size_t)(c >> 2) * K + (c & 3) * 8, &As[(i * 256 + w * 64) * 8]);
    }
#pragma unroll
    for (int i = 0; i < BN / 64; ++i) {
      int c = i * 256 + t;
      gload16(Bg + (size_t)(c >> 2) * K + (c & 3) * 8, &Bs[(i * 256 + w * 64) * 8]);
    }
    __syncthreads();
    bf16x8 af[FM], bfr[FN];
#pragma unroll
    for (int m = 0; m < FM; ++m)
      af[m] = *(const bf16x8*)&As[(wr * FM * 16 + m * 16 + l16) * 32 + g * 8];
#pragma unroll
    for (int n = 0; n < FN; ++n)
      bfr[n] = *(const bf16x8*)&Bs[(wc * FN * 16 + n * 16 + l16) * 32 + g * 8];
#pragma unroll
    for (int m = 0; m < FM; ++m)
#pragma unroll
      for (int n = 0; n < FN; ++n)
        acc[m][n] = __builtin_amdgcn_mfma_f32_16x16x32_bf16(af[m], bfr[n], acc[m][n], 0, 0, 0);
    __syncthreads();
  }
#pragma unroll
  for (int m = 0; m < FM; ++m)
#pragma unroll
    for (int n = 0; n < FN; ++n)
#pragma unroll
      for (int r = 0; r < 4; ++r) {
        int row = m0 + wr * FM * 16 + m * 16 + g * 4 + r;
        int col = n0 + wc * FN * 16 + n * 16 + l16;
        size_t idx = (size_t)row * N + col;
        float v = acc[m][n][r];
        if constexpr (EPI == 0) {
          ((u16*)C)[cbase + idx] = f2bf(v);
        } else if constexpr (EPI == 1) {
          v += bias[col];
          v = 0.5f * v * (1.f + erff(v * 0.70710678118f));
          ((u16*)C)[idx] = f2bf(v);
        } else if constexpr (EPI == 2) {
          ((float*)C)[idx] = v + bias[col] + resid[idx];
        } else if constexpr (EPI == 3) {
          ((float*)C)[idx] = v + resid[idx];
        } else {
          ((float*)C)[cbase + idx] = v;
        }
      }
}

// ---------------- fused QKV projection, 64x128 tiles + XCD swizzle (R12) --------------
__launch_bounds__(256, 2)
__global__ void gemm_qkv64(const u16* __restrict__ A, const u16* __restrict__ B0,
                           const u16* __restrict__ B1, const u16* __restrict__ B2,
                           u16* __restrict__ C0, u16* __restrict__ C1, u16* __restrict__ C2) {
  constexpr int FM = 4, FN = 2;
  const int K = 1024, N = 1024;
  int bid = blockIdx.x + 24 * blockIdx.y;
  int xcd = bid & 7, kk0 = bid >> 3;
  const int bxs = xcd * 3 + kk0 % 3;
  const int bys = kk0 / 3;
  const int which = bxs >> 3;
  const u16* B = which == 0 ? B0 : which == 1 ? B1 : B2;
  u16* C = which == 0 ? C0 : which == 1 ? C1 : C2;
  __shared__ u16 As[64 * 32];
  __shared__ u16 Bs[128 * 32];
  const int t = threadIdx.x, lane = t & 63, w = t >> 6;
  const int wc = w;
  const int g = lane >> 4, l16 = lane & 15;
  const int m0 = bys * 64, n0 = (bxs & 7) * 128;
  f32x4 acc[FM][FN] = {};
  for (int kt = 0; kt < 32; ++kt) {
    const u16* Ag = A + (size_t)m0 * K + kt * 32;
    const u16* Bg = B + (size_t)n0 * K + kt * 32;
    {
      int c = t;
      gload16(Ag + (size_t)(c >> 2) * K + (c & 3) * 8, &As[(w * 64) * 8]);
    }
#pragma unroll
    for (int i = 0; i < 2; ++i) {
      int c = i * 256 + t;
      gload16(Bg + (size_t)(c >> 2) * K + (c & 3) * 8, &Bs[(i * 256 + w * 64) * 8]);
    }
    __syncthreads();
    bf16x8 af[FM], bfr[FN];
#pragma unroll
    for (int m = 0; m < FM; ++m)
      af[m] = *(const bf16x8*)&As[(m * 16 + l16) * 32 + g * 8];
#pragma unroll
    for (int n = 0; n < FN; ++n)
      bfr[n] = *(const bf16x8*)&Bs[(wc * FN * 16 + n * 16 + l16) * 32 + g * 8];
#pragma unroll
    for (int m = 0; m < FM; ++m)
#pragma unroll
      for (int n = 0; n < FN; ++n)
        acc[m][n] = __builtin_amdgcn_mfma_f32_16x16x32_bf16(af[m], bfr[n], acc[m][n], 0, 0, 0);
    __syncthreads();
  }
#pragma unroll
  for (int m = 0; m < FM; ++m)
#pragma unroll
    for (int n = 0; n < FN; ++n)
#pragma unroll
      for (int r = 0; r < 4; ++r) {
        int row = m0 + m * 16 + g * 4 + r;
        int col = n0 + wc * FN * 16 + n * 16 + l16;
        C[(size_t)row * N + col] = f2bf(acc[m][n][r]);
      }
}

// ---------------- flash attention: 768 blocks (3/CU), 11 tiles each (R16) -------------
__launch_bounds__(256, 4)
__global__ void attn_fwd(const u16* __restrict__ Q, const u16* __restrict__ Kb,
                         const u16* __restrict__ Vt, const float* __restrict__ slopes,
                         u16* __restrict__ BoLo, u16* __restrict__ BoHi,
                         float* __restrict__ BlG) {
  const int p = blockIdx.x;
  const int h = blockIdx.y;
  const int z = blockIdx.z;
  const int t = threadIdx.x, lane = t & 63, w = t >> 6;
  const int g = lane >> 4, l16 = lane & 15;
  const float slope = slopes[h];
  const int TA = p + 1;
  const int qbB = 31 - p;

  __shared__ u16 Ks[2][4096];
  __shared__ u16 Vs[2][4096];
  __shared__ u16 Ps[4][16][72];

  const int r0 = w * 8 + (lane >> 3), r1 = 32 + r0;
  const int c8 = lane & 7;
  const int c0s = c8 ^ (r0 & 7), c1s = c8 ^ (r1 & 7);
  const int sw = l16 & 7;
  const u16x8 ones_u = { 0x3F80, 0x3F80, 0x3F80, 0x3F80, 0x3F80, 0x3F80, 0x3F80, 0x3F80 };
  const bf16x8 ones = __builtin_bit_cast(bf16x8, ones_u);

  auto stage = [&](int buf, int kv0) {
    gload16(Kb + (size_t)(kv0 + r0) * 1024 + h * 64 + c0s * 8, &Ks[buf][(w * 64) * 8]);
    gload16(Kb + (size_t)(kv0 + r1) * 1024 + h * 64 + c1s * 8, &Ks[buf][(256 + w * 64) * 8]);
    gload16(Vt + (size_t)(h * 64 + r0) * 2048 + kv0 + c0s * 8, &Vs[buf][(w * 64) * 8]);
    gload16(Vt + (size_t)(h * 64 + r1) * 2048 + kv0 + c1s * 8, &Vs[buf][(256 + w * 64) * 8]);
  };
  auto kvOf = [&](int idx) { return idx < TA ? idx * 64 : (idx - TA) * 64; };
  auto boPtr = [&](size_t slot) {
    return slot < 1024 ? BoLo + slot * 4096 : BoHi + (slot - 1024) * 4096;
  };

  const int myStart = z * 11;
  const int myEnd = myStart + 11;
  const size_t slotBase = (((size_t)p * 16 + h) * 3 + z) * 2;

  bool flushed[2] = { false, false };
  f32x4 o_acc[4] = {};
  f32x4 lsum = {};

  auto flush = [&](int c) {
    u16* Bo = boPtr(slotBase + c);
    float* Bl = BlG + (slotBase + c) * 64;
#pragma unroll
    for (int d = 0; d < 4; ++d)
#pragma unroll
      for (int r = 0; r < 4; ++r)
        Bo[(w * 16 + g * 4 + r) * 64 + d * 16 + l16] = f2bf(o_acc[d][r]);
    if (l16 == 0) {
#pragma unroll
      for (int r = 0; r < 4; ++r) Bl[w * 16 + g * 4 + r] = lsum[r];
    }
    flushed[c] = true;
  };

  int qb = (myStart < TA) ? p : qbB;
  int q0 = qb * 64 + w * 16;
  bf16x8 qf[2];
#pragma unroll
  for (int kk = 0; kk < 2; ++kk)
    qf[kk] = *(const bf16x8*)&Q[(size_t)(q0 + l16) * 1024 + h * 64 + kk * 32 + g * 8];

  stage(0, kvOf(myStart));
  __syncthreads();

  int cur = 0;
  for (int it = 0; it < 11; ++it) {
    const int idx = myStart + it;
    if (idx == TA && myStart < TA) {
      flush(0);
      qb = qbB;
      q0 = qb * 64 + w * 16;
#pragma unroll
      for (int kk = 0; kk < 2; ++kk)
        qf[kk] = *(const bf16x8*)&Q[(size_t)(q0 + l16) * 1024 + h * 64 + kk * 32 + g * 8];
#pragma unroll
      for (int d = 0; d < 4; ++d) o_acc[d] = f32x4{};
      lsum = f32x4{};
    }
    if (it + 1 < 11) stage(cur ^ 1, kvOf(idx + 1));
    {
      const int kv0 = kvOf(idx);
      const bool lastT = (idx == TA - 1) || (idx == 32);
      f32x4 s[4];
      __builtin_amdgcn_s_setprio(1);
#pragma unroll
      for (int n = 0; n < 4; ++n) {
        bf16x8 kf0 = *(const bf16x8*)&Ks[cur][(n * 16 + l16) * 64 + ((g ^ sw) * 8)];
        bf16x8 kf1 = *(const bf16x8*)&Ks[cur][(n * 16 + l16) * 64 + (((4 + g) ^ sw) * 8)];
        f32x4 z4 = {};
        s[n] = __builtin_amdgcn_mfma_f32_16x16x32_bf16(qf[0], kf0, z4, 0, 0, 0);
        s[n] = __builtin_amdgcn_mfma_f32_16x16x32_bf16(qf[1], kf1, s[n], 0, 0, 0);
      }
      __builtin_amdgcn_s_setprio(0);
      const float aB = -slope * (float)(kv0 + l16);
#pragma unroll
      for (int n = 0; n < 4; ++n) {
        const float aN = aB - slope * (float)(n * 16);
        const int kj = kv0 + n * 16 + l16;
        u16x4 pr;
#pragma unroll
        for (int r = 0; r < 4; ++r) {
          float val = fmaf(s[n][r], 0.125f, aN);
          if (lastT) {
            int qi = q0 + g * 4 + r;
            val = (kj <= qi) ? val : -1e30f;
          }
          pr[r] = f2bf(__expf(val));
        }
#pragma unroll
        for (int r = 0; r < 4; ++r) Ps[w][g * 4 + r][n * 16 + l16] = pr[r];
      }
      bf16x8 pf[2];
#pragma unroll
      for (int kk = 0; kk < 2; ++kk)
        pf[kk] = *(const bf16x8*)&Ps[w][l16][kk * 32 + g * 8];
      __builtin_amdgcn_s_setprio(1);
#pragma unroll
      for (int kk = 0; kk < 2; ++kk)
        lsum = __builtin_amdgcn_mfma_f32_16x16x32_bf16(pf[kk], ones, lsum, 0, 0, 0);
#pragma unroll
      for (int d = 0; d < 4; ++d) {
#pragma unroll
        for (int kk = 0; kk < 2; ++kk) {
          bf16x8 vv = *(const bf16x8*)&Vs[cur][(d * 16 + l16) * 64 + (((kk * 4 + g) ^ sw) * 8)];
          o_acc[d] = __builtin_amdgcn_mfma_f32_16x16x32_bf16(pf[kk], vv, o_acc[d], 0, 0, 0);
        }
      }
      __builtin_amdgcn_s_setprio(0);
    }
    __syncthreads();
    cur ^= 1;
  }
  flush((myEnd - 1) < TA ? 0 : 1);
#pragma unroll
  for (int c = 0; c < 2; ++c)
    if (!flushed[c]) {
      u16* Bo = boPtr(slotBase + c);
      float* Bl = BlG + (slotBase + c) * 64;
#pragma unroll
      for (int i = 0; i < 16; ++i) Bo[i * 256 + t] = 0;
      if (t < 64) Bl[t] = 0.f;
    }
}

// ---------------- merge 3 z-partials per chunk -> attnO ----------------
__launch_bounds__(256)
__global__ void merge_b(const u16* __restrict__ BoLo, const u16* __restrict__ BoHi,
                        const float* __restrict__ BlG, u16* __restrict__ O) {
  const int p = blockIdx.x, h = blockIdx.y;
  const int t = threadIdx.x;
  const int row = t >> 2, c0 = (t & 3) * 16;
  const size_t base = ((size_t)p * 16 + h) * 6;
#pragma unroll
  for (int c = 0; c < 2; ++c) {
    const int qb = c == 0 ? p : 31 - p;
    float l = 0.f;
    float acc[16];
#pragma unroll
    for (int i = 0; i < 16; ++i) acc[i] = 0.f;
#pragma unroll
    for (int z = 0; z < 3; ++z) {
      const size_t slot = base + (size_t)z * 2 + c;
      l += BlG[slot * 64 + row];
      const u16* Bo = (slot < 1024 ? BoLo + slot * 4096 : BoHi + (slot - 1024) * 4096) +
                      row * 64 + c0;
#pragma unroll
      for (int i = 0; i < 16; ++i) acc[i] += bf2f(Bo[i]);
    }
    float inv = 1.f / l;
    u16x8 o0, o1;
#pragma unroll
    for (int i = 0; i < 8; ++i) {
      o0[i] = f2bf(acc[i] * inv);
      o1[i] = f2bf(acc[8 + i] * inv);
    }
    u16* dst = O + (size_t)(qb * 64 + row) * 1024 + h * 64 + c0;
    *(u16x8*)dst = o0;
    *(u16x8*)(dst + 8) = o1;
  }
}

// ---------------- launcher ----------------
extern "C" void kernel_launch(void* const* d_in, const int* in_sizes, int n_in,
                              void* d_out, int out_size, void* d_ws, size_t ws_size,
                              hipStream_t stream) {
  const float* x = (const float*)d_in[0];
  const float* slopes = (const float*)d_in[1];
  const float* wq = (const float*)d_in[2];
  const float* wk = (const float*)d_in[3];
  const float* wv = (const float*)d_in[4];
  const float* wo = (const float*)d_in[5];
  const float* ff1w = (const float*)d_in[6];
  const float* ff1b = (const float*)d_in[7];
  const float* ff2w = (const float*)d_in[8];
  const float* ff2b = (const float*)d_in[9];
  const float* ln1g = (const float*)d_in[10];
  const float* ln1b = (const float*)d_in[11];
  const float* ln2g = (const float*)d_in[12];
  const float* ln2b = (const float*)d_in[13];
  float* out = (float*)d_out;

  if (ws_size < (size_t)(56u << 20)) return;  // need 56MB scratch

  char* ws = (char*)d_ws;
  // Region plan (time-ordered): identical to R16.
  u16* hbuf = (u16*)(ws + 0);
  u16* Qb = (u16*)(ws + (4u << 20));
  u16* Kbf = (u16*)(ws + (8u << 20));
  u16* Vbf = (u16*)(ws + (12u << 20));
  u16* Vtb = (u16*)(ws + (16u << 20));
  u16* Pw = (u16*)(ws + (4u << 20));
  u16* ffact = Qb;
  u16* BoLo = (u16*)(ws + (20u << 20));
  u16* BoHi = (u16*)(ws + (12u << 20));
  float* x2 = (float*)(ws + (20u << 20));
  float* BlG = (float*)(ws + (28u << 20));
  u16* h2 = (u16*)(ws + (28u << 20));
  u16* wqb = (u16*)(ws + (32u << 20));
  u16* wkb = (u16*)(ws + (34u << 20));
  u16* wvb = (u16*)(ws + (36u << 20));
  u16* wob = (u16*)(ws + (38u << 20));
  u16* ff1wb = (u16*)(ws + (40u << 20));
  u16* ff2wb = (u16*)(ws + (48u << 20));
  u16* attnO = hbuf;
  u16* Qp = (u16*)(ws + (32u << 20));
  const size_t q4off = (size_t)(4u << 20) / 2;
  const size_t woff = (size_t)2048 * 1024;

  prep<<<2048 + 12288, 256, 0, stream>>>(x, ln1g, ln1b, hbuf, wq, wk, wv, wo, ff1w, ff2w,
                                         wqb, wkb, wvb, wob, ff1wb, ff2wb);
  gemm_qkv64<<<dim3(24, 32), 256, 0, stream>>>(hbuf, wqb, wkb, wvb, Qb, Kbf, Vbf);
  transpose_v<<<dim3(32, 16), 256, 0, stream>>>(Vbf, Vtb);
  attn_fwd<<<dim3(16, 16, 3), 256, 0, stream>>>(Qb, Kbf, Vtb, slopes, BoLo, BoHi, BlG);
  merge_b<<<dim3(16, 16), 256, 0, stream>>>(BoLo, BoHi, BlG, attnO);
  gemm_bt<64, 128, 1, 4, 0, 4, 1><<<dim3(8, 32, 4), 256, 0, stream>>>(
      attnO, wob, Pw, nullptr, nullptr, 2048, 1024, 1024, woff);
  ln2_add<<<2048, 256, 0, stream>>>(x, Pw, woff, ln2g, ln2b, x2, h2);
  // ff1: 64x128 tiles -> 1024 blocks (4 blocks/CU; was 128x128 at 2/CU).
  // Same per-block config as the 780TF-effective ff2; GELU epilogue stays fused.
  gemm_bt<64, 128, 1, 4, 1, 1, 0><<<dim3(32, 32), 256, 0, stream>>>(
      h2, ff1wb, ffact, ff1b, nullptr, 2048, 4096, 1024, 0);
  gemm_bt<64, 128, 1, 4, 0, 4, 1><<<dim3(8, 32, 4), 256, 0, stream>>>(
      ffact, ff2wb, Qp, nullptr, nullptr, 2048, 1024, 4096, q4off);
  final_add<<<2048, 256, 0, stream>>>(x2, ff2b, Qp, q4off, out);
}